// Round 12
// baseline (232.460 us; speedup 1.0000x reference)
//
#include <hip/hip_runtime.h>
#include <hip/hip_bf16.h>
#include <cstdint>

#define B_ 2
#define T_ 2048
#define D_ 2048
#define H_ 32
#define KVH_ 8
#define HD_ 64
#define NQKV_ 3072
#define M_ 4096

typedef __attribute__((ext_vector_type(8))) __bf16 bf16x8;
typedef __attribute__((ext_vector_type(4))) float f32x4;
typedef __attribute__((ext_vector_type(4))) uint32_t u32x4;

__device__ __forceinline__ uint16_t f2bf(float f) {
  uint32_t u = __builtin_bit_cast(uint32_t, f);
  return (uint16_t)((u + 0x7FFFu + ((u >> 16) & 1u)) >> 16);
}

__device__ __forceinline__ uint32_t cvt_pk(float lo, float hi) {
  uint32_t r;
  asm("v_cvt_pk_bf16_f32 %0, %1, %2" : "=v"(r) : "v"(lo), "v"(hi));
  return r;
}

__device__ __forceinline__ void gload_lds16(const void* g, void* l) {
  __builtin_amdgcn_global_load_lds(
      (const __attribute__((address_space(1))) void*)(uintptr_t)g,
      (__attribute__((address_space(3))) void*)(uintptr_t)l, 16, 0, 0);
}

// ---------------- fp32 -> bf16 convert (vectorized x8) ----------------
__global__ void cvt_bf16_k(const float* __restrict__ in, uint16_t* __restrict__ out, int n) {
  int i = (blockIdx.x * 256 + threadIdx.x) * 8;
  if (i >= n) return;
  float4 a = *reinterpret_cast<const float4*>(in + i);
  float4 b = *reinterpret_cast<const float4*>(in + i + 4);
  uint4 v;
  v.x = (uint32_t)f2bf(a.x) | ((uint32_t)f2bf(a.y) << 16);
  v.y = (uint32_t)f2bf(a.z) | ((uint32_t)f2bf(a.w) << 16);
  v.z = (uint32_t)f2bf(b.x) | ((uint32_t)f2bf(b.y) << 16);
  v.w = (uint32_t)f2bf(b.z) | ((uint32_t)f2bf(b.w) << 16);
  *reinterpret_cast<uint4*>(out + i) = v;
}

__global__ void concat_bias_k(const float* __restrict__ bq, const float* __restrict__ bk,
                              const float* __restrict__ bv, float* __restrict__ out) {
  int i = blockIdx.x * 256 + threadIdx.x;
  if (i >= NQKV_) return;
  out[i] = (i < D_) ? bq[i] : (i < D_ + 512) ? bk[i - D_] : bv[i - D_ - 512];
}

__global__ void rope_tab_k(float* __restrict__ cosT, float* __restrict__ sinT) {
  int i = blockIdx.x * 256 + threadIdx.x;  // 2048*32
  int d = i & 31;
  int t = i >> 5;
  float inv = expf(-(float)d * (1.0f / 32.0f) * logf(10000.0f));
  float f = (float)t * inv;
  cosT[i] = cosf(f);
  sinT[i] = sinf(f);
}

// ---------------- GEMM 256x256, BK=64, 8 waves, 4-phase schedule ----------------
// T2: LDS XOR-swizzle colb ^= (row&7)<<4, applied identically to the
// pre-swizzled global_load_lds SOURCE and the ds_read address (rule #21).
// T3/T4: next K-step's 8 gload_lds front-loaded at phase 0; single vmcnt(0)
// at phase 3 (3 phases of latency cover). T5: setprio around MFMA cluster.
// Raw s_barrier + explicit lgkmcnt(0) + sched_barrier(0) (rule #18) -- no
// __syncthreads full-drain in the loop.
#define GBM 256
#define GBN 256
#define GBK 64
__global__ __launch_bounds__(512, 2)
void gemm256(const uint16_t* __restrict__ A, const uint16_t* __restrict__ Bw,
             const float* __restrict__ bias, float* __restrict__ C,
             int M, int N, int K) {
  __shared__ __align__(16) uint16_t lds[2][2][GBM * GBK];  // 128 KiB
  const int tid = threadIdx.x;
  const int lane = tid & 63;
  const int w = tid >> 6;            // 0..7
  const int wm = w >> 2, wn = w & 3; // 2 x 4 wave grid; per-wave 128x64
  const int l16 = lane & 15, lq = lane >> 4;

  int lin = blockIdx.y * gridDim.x + blockIdx.x;
  int qn = (gridDim.x * gridDim.y) >> 3;   // nwg % 8 == 0 for both calls
  int swz = (lin & 7) * qn + (lin >> 3);
  const int m0 = (swz / gridDim.x) * GBM, n0 = (swz % gridDim.x) * GBN;

  // stage one K-step (A 32KB + B 32KB): per-thread 4+4 gload_lds of 16B.
  // linear LDS dest off = w*4096 + j*1024 + lane*16; source pre-swizzled.
  auto stage = [&](int dbuf, int kt) {
    int k0 = kt * GBK;
#pragma unroll
    for (int j = 0; j < 4; ++j) {
      int off = w * 4096 + j * 1024 + lane * 16;
      int row = off >> 7;
      int colb = (off & 127) ^ ((row & 7) << 4);
      gload_lds16(A + (size_t)(m0 + row) * K + k0 + (colb >> 1),
                  (char*)&lds[dbuf][0][0] + off);
    }
#pragma unroll
    for (int j = 0; j < 4; ++j) {
      int off = w * 4096 + j * 1024 + lane * 16;
      int row = off >> 7;
      int colb = (off & 127) ^ ((row & 7) << 4);
      gload_lds16(Bw + (size_t)(n0 + row) * K + k0 + (colb >> 1),
                  (char*)&lds[dbuf][1][0] + off);
    }
  };

  f32x4 acc[8][4] = {};
  const int NT = K / GBK;

  stage(0, 0);
  asm volatile("s_waitcnt vmcnt(0)" ::: "memory");
  __builtin_amdgcn_s_barrier();

  for (int t = 0; t < NT; ++t) {
    const int cur = t & 1;
    const char* Ab = (const char*)&lds[cur][0][0];
    const char* Bb = (const char*)&lds[cur][1][0];

    // phase 0 head: issue next K-step's loads into the other dbuf
    stage(cur ^ 1, (t + 1 < NT) ? t + 1 : 0);  // tail: junk-clamped, never read

    // B fragments for the whole K-step (held across phases)
    bf16x8 bfr[4][2];
#pragma unroll
    for (int ni = 0; ni < 4; ++ni)
#pragma unroll
      for (int ks = 0; ks < 2; ++ks) {
        int R = wn * 64 + ni * 16 + l16;
        int colb = (ks * 64 + lq * 16) ^ ((R & 7) << 4);
        bfr[ni][ks] = *reinterpret_cast<const bf16x8*>(Bb + R * 128 + colb);
      }

#pragma unroll
    for (int q = 0; q < 4; ++q) {   // 4 phases: quadrant = mi pair {2q, 2q+1}
      bf16x8 afr[2][2];
#pragma unroll
      for (int mi2 = 0; mi2 < 2; ++mi2)
#pragma unroll
        for (int ks = 0; ks < 2; ++ks) {
          int R = wm * 128 + (q * 2 + mi2) * 16 + l16;
          int colb = (ks * 64 + lq * 16) ^ ((R & 7) << 4);
          afr[mi2][ks] = *reinterpret_cast<const bf16x8*>(Ab + R * 128 + colb);
        }
      if (q == 3) asm volatile("s_waitcnt vmcnt(0)" ::: "memory");  // next dbuf landed
      __builtin_amdgcn_s_barrier();
      asm volatile("s_waitcnt lgkmcnt(0)" ::: "memory");
      __builtin_amdgcn_sched_barrier(0);   // rule #18: pin MFMA below the wait
      __builtin_amdgcn_s_setprio(1);
#pragma unroll
      for (int ks = 0; ks < 2; ++ks)
#pragma unroll
        for (int mi2 = 0; mi2 < 2; ++mi2)
#pragma unroll
          for (int ni = 0; ni < 4; ++ni)
            acc[q * 2 + mi2][ni] = __builtin_amdgcn_mfma_f32_16x16x32_bf16(
                afr[mi2][ks], bfr[ni][ks], acc[q * 2 + mi2][ni], 0, 0, 0);
      __builtin_amdgcn_s_setprio(0);
      __builtin_amdgcn_s_barrier();
    }
  }

  // epilogue: bias + fp32 C
#pragma unroll
  for (int mi = 0; mi < 8; ++mi) {
    int r0 = m0 + wm * 128 + mi * 16 + lq * 4;
#pragma unroll
    for (int ni = 0; ni < 4; ++ni) {
      int c = n0 + wn * 64 + ni * 16 + l16;
      float bb = bias[c];
#pragma unroll
      for (int rr = 0; rr < 4; ++rr)
        C[(size_t)(r0 + rr) * N + c] = acc[mi][ni][rr] + bb;
    }
  }
}

// ---------------- RoPE on Q,K + pack to FRAGMENT-MAJOR bf16 layouts ----------------
__global__ void rope_qk_k(const float* __restrict__ QKV, const float* __restrict__ cosT,
                          const float* __restrict__ sinT, uint16_t* __restrict__ qb,
                          uint16_t* __restrict__ kb) {
  int tid = blockIdx.x * 256 + threadIdx.x;  // B*40*T*32
  int d = tid & 31;                           // rope pair index: (d, d+32)
  int t = (tid >> 5) & (T_ - 1);
  int rest = tid >> 16;
  int hh = rest % 40;
  int b = rest / 40;
  const float PREQ = 0.125f * 1.44269504f;
  float c = cosT[t * 32 + d];
  float s = sinT[t * 32 + d];
  size_t rowoff = (size_t)(b * T_ + t) * NQKV_;
  const int lq = d >> 3, e = d & 7;
  const int l16 = t & 15;
  const int lofs = (lq * 16 + l16) * 8 + e;
  if (hh < H_) {
    const float* q = QKV + rowoff + hh * 64;
    float x1 = q[d], x2 = q[d + 32];
    int tile = t >> 5, mf = (t >> 4) & 1;
    size_t base = ((size_t)(b * H_ + hh) * 64 + tile) * 2048;
    qb[base + (0 * 2 + mf) * 512 + lofs] = f2bf((x1 * c - x2 * s) * PREQ);  // ks=0
    qb[base + (1 * 2 + mf) * 512 + lofs] = f2bf((x2 * c + x1 * s) * PREQ);  // ks=1
  } else {
    int kh = hh - H_;
    const float* kp = QKV + rowoff + D_ + kh * 64;
    float x1 = kp[d], x2 = kp[d + 32];
    int it = t >> 6, nf = (t >> 4) & 3;
    size_t base = (size_t)(b * KVH_ + kh) * (T_ * HD_) + (size_t)it * 4096;
    kb[base + (0 * 8 + nf) * 512 + lofs] = f2bf(x1 * c - x2 * s);           // ks=0
    kb[base + (4 + nf) * 512 + lofs] = f2bf(x2 * c + x1 * s);               // ks=1
  }
}

// ---------------- V -> fragment-major bf16 (PV A-operand order) ----------------
__global__ void cvt_v_k(const float* __restrict__ QKV, uint16_t* __restrict__ vt) {
  int tid = blockIdx.x * 256 + threadIdx.x;
  int t8 = tid & 255;
  int rest = tid >> 8;
  int b = rest >> 9;
  int col = 2560 + (rest & 511);
  int d = rest & 63;
  int kvh = (rest >> 6) & 7;
  uint16_t tmp[8];
#pragma unroll
  for (int i = 0; i < 8; ++i)
    tmp[i] = f2bf(QKV[(size_t)(b * T_ + t8 * 8 + i) * NQKV_ + col]);
  uint4 v;
  v.x = (uint32_t)tmp[0] | ((uint32_t)tmp[1] << 16);
  v.y = (uint32_t)tmp[2] | ((uint32_t)tmp[3] << 16);
  v.z = (uint32_t)tmp[4] | ((uint32_t)tmp[5] << 16);
  v.w = (uint32_t)tmp[6] | ((uint32_t)tmp[7] << 16);
  int it = t8 >> 3, k2 = (t8 >> 2) & 1, lq = t8 & 3;
  int dn = d >> 4, l16 = d & 15;
  size_t base = (size_t)(b * KVH_ + kvh) * (T_ * HD_);
  *reinterpret_cast<uint4*>(vt + base + ((size_t)(it * 2 + k2) * 4 + dn) * 512 +
                            (lq * 16 + l16) * 8) = v;
}

// ---------------- flash attention (causal, GQA), swapped QK^T ----------------
__global__ __launch_bounds__(256, 2)
void flash_attn_k(const uint16_t* __restrict__ qb, const uint16_t* __restrict__ kb,
                  const uint16_t* __restrict__ vt, uint16_t* __restrict__ ob) {
  __shared__ __align__(16) uint16_t P_lds[4][32 * 72];  // per-wave 32 q x 64+pad
  const int lane = threadIdx.x & 63;
  const int w = threadIdx.x >> 6;
  const int l16 = lane & 15, lq = lane >> 4;
  const int bh = (blockIdx.x & 15) * 4 + w;
  const int rank = blockIdx.x >> 4;              // 0..63
  const int pair = rank & 31;
  const int tile = (rank & 32) ? (63 - pair) : pair;
  const int b = bh >> 5, h = bh & 31;
  const int kvh = h >> 2;
  uint16_t* P = P_lds[w];

  const uint16_t* Qp = qb + ((size_t)(b * H_ + h) * 64 + tile) * 2048;
  const uint16_t* Kp = kb + (size_t)(b * KVH_ + kvh) * (T_ * HD_);
  const uint16_t* Vp = vt + (size_t)(b * KVH_ + kvh) * (T_ * HD_);
  const int lofs = lane * 8;

  const int q0 = tile * 32;
  u32x4 ones_u = {0x3F803F80u, 0x3F803F80u, 0x3F803F80u, 0x3F803F80u};
  bf16x8 ones = __builtin_bit_cast(bf16x8, ones_u);

  bf16x8 aq[2][2];
#pragma unroll
  for (int mf = 0; mf < 2; ++mf)
#pragma unroll
    for (int ks = 0; ks < 2; ++ks)
      aq[mf][ks] = *reinterpret_cast<const bf16x8*>(Qp + (ks * 2 + mf) * 512 + lofs);

  f32x4 acc[2][4] = {};
  f32x4 acc_l[2] = {};

  const int nt = (tile >> 1) + 1;

  bf16x8 kA[2][4], kB[2][4];
#pragma unroll
  for (int ks = 0; ks < 2; ++ks)
#pragma unroll
    for (int nf = 0; nf < 4; ++nf)
      kA[ks][nf] = *reinterpret_cast<const bf16x8*>(Kp + (ks * 4 + nf) * 512 + lofs);

#define FLASH_STEP(KCUR, KNXT, IT)                                                     \
  do {                                                                                 \
    const int kv0 = (IT) * 64;                                                         \
    f32x4 sacc[4][2] = {};                                                             \
    _Pragma("unroll")                                                                  \
    for (int ks = 0; ks < 2; ++ks)                                                     \
      _Pragma("unroll")                                                                \
      for (int nf = 0; nf < 4; ++nf)                                                   \
        _Pragma("unroll")                                                              \
        for (int mf = 0; mf < 2; ++mf)                                                 \
          sacc[nf][mf] = __builtin_amdgcn_mfma_f32_16x16x32_bf16(                      \
              KCUR[ks][nf], aq[mf][ks], sacc[nf][mf], 0, 0, 0);                        \
    const int itn = ((IT) + 1 < nt) ? (IT) + 1 : (IT);                                 \
    _Pragma("unroll")                                                                  \
    for (int ks = 0; ks < 2; ++ks)                                                     \
      _Pragma("unroll")                                                                \
      for (int nf = 0; nf < 4; ++nf)                                                   \
        KNXT[ks][nf] = *reinterpret_cast<const bf16x8*>(                               \
            Kp + ((size_t)(itn * 2 + ks) * 4 + nf) * 512 + lofs);                      \
    bf16x8 vv[2][4];                                                                   \
    _Pragma("unroll")                                                                  \
    for (int k2 = 0; k2 < 2; ++k2)                                                     \
      _Pragma("unroll")                                                                \
      for (int dn = 0; dn < 4; ++dn)                                                   \
        vv[k2][dn] = *reinterpret_cast<const bf16x8*>(                                 \
            Vp + ((size_t)((IT) * 2 + k2) * 4 + dn) * 512 + lofs);                     \
    if ((IT) == nt - 1) {                                                              \
      _Pragma("unroll")                                                                \
      for (int mf = 0; mf < 2; ++mf) {                                                 \
        int qg = q0 + mf * 16 + l16;                                                   \
        _Pragma("unroll")                                                              \
        for (int nf = 0; nf < 4; ++nf)                                                 \
          _Pragma("unroll")                                                            \
          for (int r = 0; r < 4; ++r)                                                  \
            if (kv0 + nf * 16 + lq * 4 + r > qg) sacc[nf][mf][r] = -1e30f;             \
      }                                                                                \
    }                                                                                  \
    _Pragma("unroll")                                                                  \
    for (int mf = 0; mf < 2; ++mf) {                                                   \
      uint16_t* rowp = P + (mf * 16 + l16) * 72;                                       \
      _Pragma("unroll")                                                                \
      for (int nf = 0; nf < 4; ++nf) {                                                 \
        float p0 = __builtin_amdgcn_exp2f(sacc[nf][mf][0]);                            \
        float p1 = __builtin_amdgcn_exp2f(sacc[nf][mf][1]);                            \
        float p2 = __builtin_amdgcn_exp2f(sacc[nf][mf][2]);                            \
        float p3 = __builtin_amdgcn_exp2f(sacc[nf][mf][3]);                            \
        uint2 pk;                                                                      \
        pk.x = cvt_pk(p0, p1);                                                         \
        pk.y = cvt_pk(p2, p3);                                                         \
        *reinterpret_cast<uint2*>(rowp + nf * 16 + lq * 4) = pk;                       \
      }                                                                                \
    }                                                                                  \
    bf16x8 pa[2][2];                                                                   \
    _Pragma("unroll")                                                                  \
    for (int mf = 0; mf < 2; ++mf)                                                     \
      _Pragma("unroll")                                                                \
      for (int k2 = 0; k2 < 2; ++k2)                                                   \
        pa[mf][k2] = *reinterpret_cast<const bf16x8*>(                                 \
            P + (mf * 16 + l16) * 72 + k2 * 32 + lq * 8);                              \
    _Pragma("unroll")                                                                  \
    for (int k2 = 0; k2 < 2; ++k2)                                                     \
      _Pragma("unroll")                                                                \
      for (int mf = 0; mf < 2; ++mf) {                                                 \
        acc_l[mf] = __builtin_amdgcn_mfma_f32_16x16x32_bf16(ones, pa[mf][k2],          \
                                                            acc_l[mf], 0, 0, 0);      \
        _Pragma("unroll")                                                              \
        for (int dn = 0; dn < 4; ++dn)                                                 \
          acc[mf][dn] = __builtin_amdgcn_mfma_f32_16x16x32_bf16(                       \
              vv[k2][dn], pa[mf][k2], acc[mf][dn], 0, 0, 0);                           \
      }                                                                                \
  } while (0)

  {
    int it = 0;
    for (;;) {
      FLASH_STEP(kA, kB, it);
      ++it;
      if (it == nt) break;
      FLASH_STEP(kB, kA, it);
      ++it;
      if (it == nt) break;
    }
  }
#undef FLASH_STEP

#pragma unroll
  for (int mf = 0; mf < 2; ++mf) {
    float inv = 1.0f / acc_l[mf][0];
    uint16_t* rowp = P + (mf * 16 + l16) * 72;
#pragma unroll
    for (int dn = 0; dn < 4; ++dn) {
      uint2 pk;
      pk.x = cvt_pk(acc[mf][dn][0] * inv, acc[mf][dn][1] * inv);
      pk.y = cvt_pk(acc[mf][dn][2] * inv, acc[mf][dn][3] * inv);
      *reinterpret_cast<uint2*>(rowp + dn * 16 + lq * 4) = pk;
    }
  }
  {
    int orow = lane >> 1, ohalf = (lane & 1) * 32;
    uint16_t* op = ob + (size_t)(b * T_ + q0 + orow) * D_ + h * HD_ + ohalf;
    const uint16_t* lp = P + orow * 72 + ohalf;
#pragma unroll
    for (int j = 0; j < 4; ++j)
      *reinterpret_cast<uint4*>(op + j * 8) = *reinterpret_cast<const uint4*>(lp + j * 8);
  }
}

extern "C" void kernel_launch(void* const* d_in, const int* in_sizes, int n_in,
                              void* d_out, int out_size, void* d_ws, size_t ws_size,
                              hipStream_t stream) {
  const float* x  = (const float*)d_in[0];
  const float* Wq = (const float*)d_in[1];
  const float* bq = (const float*)d_in[2];
  const float* Wk = (const float*)d_in[3];
  const float* bk = (const float*)d_in[4];
  const float* Wv = (const float*)d_in[5];
  const float* bv = (const float*)d_in[6];
  const float* Wo = (const float*)d_in[7];
  const float* bo = (const float*)d_in[8];
  float* out = (float*)d_out;

  char* ws = (char*)d_ws;
  size_t off = 0;
  auto alloc = [&](size_t bytes) {
    void* p = ws + off;
    off += (bytes + 255) & ~(size_t)255;
    return p;
  };
  uint16_t* xb    = (uint16_t*)alloc((size_t)M_ * D_ * 2);
  uint16_t* wqkv  = (uint16_t*)alloc((size_t)NQKV_ * D_ * 2);
  uint16_t* wo_b  = (uint16_t*)alloc((size_t)D_ * D_ * 2);
  float*    bqkv  = (float*)alloc(NQKV_ * 4);
  float*    cosT  = (float*)alloc(T_ * 32 * 4);
  float*    sinT  = (float*)alloc(T_ * 32 * 4);
  uint16_t* q_bf  = (uint16_t*)alloc((size_t)B_ * H_ * T_ * HD_ * 2);
  uint16_t* k_bf  = (uint16_t*)alloc((size_t)B_ * KVH_ * T_ * HD_ * 2);
  uint16_t* vt_bf = (uint16_t*)alloc((size_t)B_ * KVH_ * T_ * HD_ * 2);
  float*    qkvf  = (float*)alloc((size_t)M_ * NQKV_ * 4);
  uint16_t* attn_bf = (uint16_t*)qkvf;  // reuse: QKV fp32 dead after rope/cvt_v

  cvt_bf16_k<<<4096, 256, 0, stream>>>(x, xb, M_ * D_);
  cvt_bf16_k<<<2048, 256, 0, stream>>>(Wq, wqkv, D_ * D_);
  cvt_bf16_k<<<512, 256, 0, stream>>>(Wk, wqkv + (size_t)D_ * D_, 512 * D_);
  cvt_bf16_k<<<512, 256, 0, stream>>>(Wv, wqkv + (size_t)2560 * D_, 512 * D_);
  cvt_bf16_k<<<2048, 256, 0, stream>>>(Wo, wo_b, D_ * D_);
  concat_bias_k<<<12, 256, 0, stream>>>(bq, bk, bv, bqkv);
  rope_tab_k<<<256, 256, 0, stream>>>(cosT, sinT);

  gemm256<<<dim3(NQKV_ / GBN, M_ / GBM), 512, 0, stream>>>(xb, wqkv, bqkv, qkvf, M_, NQKV_, D_);

  rope_qk_k<<<(B_ * 40 * T_ * 32) / 256, 256, 0, stream>>>(qkvf, cosT, sinT, q_bf, k_bf);
  cvt_v_k<<<(B_ * KVH_ * HD_ * (T_ / 8)) / 256, 256, 0, stream>>>(qkvf, vt_bf);

  flash_attn_k<<<1024, 256, 0, stream>>>(q_bf, k_bf, vt_bf, attn_bf);

  gemm256<<<dim3(D_ / GBN, M_ / GBM), 512, 0, stream>>>(attn_bf, wo_b, bo, out, M_, D_, D_);
}

// Round 13
// 232.360 us; speedup vs baseline: 1.0004x; 1.0004x over previous
//
#include <hip/hip_runtime.h>
#include <hip/hip_bf16.h>
#include <cstdint>

#define B_ 2
#define T_ 2048
#define D_ 2048
#define H_ 32
#define KVH_ 8
#define HD_ 64
#define NQKV_ 3072
#define M_ 4096

typedef __attribute__((ext_vector_type(8))) __bf16 bf16x8;
typedef __attribute__((ext_vector_type(4))) float f32x4;
typedef __attribute__((ext_vector_type(4))) uint32_t u32x4;

__device__ __forceinline__ uint16_t f2bf(float f) {
  uint32_t u = __builtin_bit_cast(uint32_t, f);
  return (uint16_t)((u + 0x7FFFu + ((u >> 16) & 1u)) >> 16);
}

__device__ __forceinline__ uint32_t cvt_pk(float lo, float hi) {
  uint32_t r;
  asm("v_cvt_pk_bf16_f32 %0, %1, %2" : "=v"(r) : "v"(lo), "v"(hi));
  return r;
}

__device__ __forceinline__ void gload_lds16(const void* g, void* l) {
  __builtin_amdgcn_global_load_lds(
      (const __attribute__((address_space(1))) void*)(uintptr_t)g,
      (__attribute__((address_space(3))) void*)(uintptr_t)l, 16, 0, 0);
}

// ---------------- fp32 -> bf16 convert (vectorized x8) ----------------
__global__ void cvt_bf16_k(const float* __restrict__ in, uint16_t* __restrict__ out, int n) {
  int i = (blockIdx.x * 256 + threadIdx.x) * 8;
  if (i >= n) return;
  float4 a = *reinterpret_cast<const float4*>(in + i);
  float4 b = *reinterpret_cast<const float4*>(in + i + 4);
  uint4 v;
  v.x = (uint32_t)f2bf(a.x) | ((uint32_t)f2bf(a.y) << 16);
  v.y = (uint32_t)f2bf(a.z) | ((uint32_t)f2bf(a.w) << 16);
  v.z = (uint32_t)f2bf(b.x) | ((uint32_t)f2bf(b.y) << 16);
  v.w = (uint32_t)f2bf(b.z) | ((uint32_t)f2bf(b.w) << 16);
  *reinterpret_cast<uint4*>(out + i) = v;
}

__global__ void concat_bias_k(const float* __restrict__ bq, const float* __restrict__ bk,
                              const float* __restrict__ bv, float* __restrict__ out) {
  int i = blockIdx.x * 256 + threadIdx.x;
  if (i >= NQKV_) return;
  out[i] = (i < D_) ? bq[i] : (i < D_ + 512) ? bk[i - D_] : bv[i - D_ - 512];
}

__global__ void rope_tab_k(float* __restrict__ cosT, float* __restrict__ sinT) {
  int i = blockIdx.x * 256 + threadIdx.x;  // 2048*32
  int d = i & 31;
  int t = i >> 5;
  float inv = expf(-(float)d * (1.0f / 32.0f) * logf(10000.0f));
  float f = (float)t * inv;
  cosT[i] = cosf(f);
  sinT[i] = sinf(f);
}

// ---------------- GEMM 256x256, BK=64, 8 waves, 4-phase schedule ----------------
// T2: LDS XOR-swizzle colb ^= (row&7)<<4, applied identically to the
// pre-swizzled global_load_lds SOURCE and the ds_read address (rule #21).
// T3/T4: next K-step's 8 gload_lds front-loaded at phase 0; single vmcnt(0)
// at phase 3 (3 phases of latency cover). T5: setprio around MFMA cluster.
// Raw s_barrier + explicit lgkmcnt(0) + sched_barrier(0) (rule #18) -- no
// __syncthreads full-drain in the loop.
#define GBM 256
#define GBN 256
#define GBK 64
__global__ __launch_bounds__(512, 2)
void gemm256(const uint16_t* __restrict__ A, const uint16_t* __restrict__ Bw,
             const float* __restrict__ bias, float* __restrict__ C,
             int M, int N, int K) {
  __shared__ __align__(16) uint16_t lds[2][2][GBM * GBK];  // 128 KiB
  const int tid = threadIdx.x;
  const int lane = tid & 63;
  const int w = tid >> 6;            // 0..7
  const int wm = w >> 2, wn = w & 3; // 2 x 4 wave grid; per-wave 128x64
  const int l16 = lane & 15, lq = lane >> 4;

  int lin = blockIdx.y * gridDim.x + blockIdx.x;
  int qn = (gridDim.x * gridDim.y) >> 3;   // nwg % 8 == 0 for both calls
  int swz = (lin & 7) * qn + (lin >> 3);
  const int m0 = (swz / gridDim.x) * GBM, n0 = (swz % gridDim.x) * GBN;

  // stage one K-step (A 32KB + B 32KB): per-thread 4+4 gload_lds of 16B.
  // linear LDS dest off = w*4096 + j*1024 + lane*16; source pre-swizzled.
  auto stage = [&](int dbuf, int kt) {
    int k0 = kt * GBK;
#pragma unroll
    for (int j = 0; j < 4; ++j) {
      int off = w * 4096 + j * 1024 + lane * 16;
      int row = off >> 7;
      int colb = (off & 127) ^ ((row & 7) << 4);
      gload_lds16(A + (size_t)(m0 + row) * K + k0 + (colb >> 1),
                  (char*)&lds[dbuf][0][0] + off);
    }
#pragma unroll
    for (int j = 0; j < 4; ++j) {
      int off = w * 4096 + j * 1024 + lane * 16;
      int row = off >> 7;
      int colb = (off & 127) ^ ((row & 7) << 4);
      gload_lds16(Bw + (size_t)(n0 + row) * K + k0 + (colb >> 1),
                  (char*)&lds[dbuf][1][0] + off);
    }
  };

  f32x4 acc[8][4] = {};
  const int NT = K / GBK;

  stage(0, 0);
  asm volatile("s_waitcnt vmcnt(0)" ::: "memory");
  __builtin_amdgcn_s_barrier();

  for (int t = 0; t < NT; ++t) {
    const int cur = t & 1;
    const char* Ab = (const char*)&lds[cur][0][0];
    const char* Bb = (const char*)&lds[cur][1][0];

    // phase 0 head: issue next K-step's loads into the other dbuf
    stage(cur ^ 1, (t + 1 < NT) ? t + 1 : 0);  // tail: junk-clamped, never read

    // B fragments for the whole K-step (held across phases)
    bf16x8 bfr[4][2];
#pragma unroll
    for (int ni = 0; ni < 4; ++ni)
#pragma unroll
      for (int ks = 0; ks < 2; ++ks) {
        int R = wn * 64 + ni * 16 + l16;
        int colb = (ks * 64 + lq * 16) ^ ((R & 7) << 4);
        bfr[ni][ks] = *reinterpret_cast<const bf16x8*>(Bb + R * 128 + colb);
      }

#pragma unroll
    for (int q = 0; q < 4; ++q) {   // 4 phases: quadrant = mi pair {2q, 2q+1}
      bf16x8 afr[2][2];
#pragma unroll
      for (int mi2 = 0; mi2 < 2; ++mi2)
#pragma unroll
        for (int ks = 0; ks < 2; ++ks) {
          int R = wm * 128 + (q * 2 + mi2) * 16 + l16;
          int colb = (ks * 64 + lq * 16) ^ ((R & 7) << 4);
          afr[mi2][ks] = *reinterpret_cast<const bf16x8*>(Ab + R * 128 + colb);
        }
      if (q == 3) asm volatile("s_waitcnt vmcnt(0)" ::: "memory");  // next dbuf landed
      __builtin_amdgcn_s_barrier();
      asm volatile("s_waitcnt lgkmcnt(0)" ::: "memory");
      __builtin_amdgcn_sched_barrier(0);   // rule #18: pin MFMA below the wait
      __builtin_amdgcn_s_setprio(1);
#pragma unroll
      for (int ks = 0; ks < 2; ++ks)
#pragma unroll
        for (int mi2 = 0; mi2 < 2; ++mi2)
#pragma unroll
          for (int ni = 0; ni < 4; ++ni)
            acc[q * 2 + mi2][ni] = __builtin_amdgcn_mfma_f32_16x16x32_bf16(
                afr[mi2][ks], bfr[ni][ks], acc[q * 2 + mi2][ni], 0, 0, 0);
      __builtin_amdgcn_s_setprio(0);
      __builtin_amdgcn_s_barrier();
    }
  }

  // epilogue: bias + fp32 C
#pragma unroll
  for (int mi = 0; mi < 8; ++mi) {
    int r0 = m0 + wm * 128 + mi * 16 + lq * 4;
#pragma unroll
    for (int ni = 0; ni < 4; ++ni) {
      int c = n0 + wn * 64 + ni * 16 + l16;
      float bb = bias[c];
#pragma unroll
      for (int rr = 0; rr < 4; ++rr)
        C[(size_t)(r0 + rr) * N + c] = acc[mi][ni][rr] + bb;
    }
  }
}

// ---------------- RoPE on Q,K + pack to FRAGMENT-MAJOR bf16 layouts ----------------
__global__ void rope_qk_k(const float* __restrict__ QKV, const float* __restrict__ cosT,
                          const float* __restrict__ sinT, uint16_t* __restrict__ qb,
                          uint16_t* __restrict__ kb) {
  int tid = blockIdx.x * 256 + threadIdx.x;  // B*40*T*32
  int d = tid & 31;                           // rope pair index: (d, d+32)
  int t = (tid >> 5) & (T_ - 1);
  int rest = tid >> 16;
  int hh = rest % 40;
  int b = rest / 40;
  const float PREQ = 0.125f * 1.44269504f;
  float c = cosT[t * 32 + d];
  float s = sinT[t * 32 + d];
  size_t rowoff = (size_t)(b * T_ + t) * NQKV_;
  const int lq = d >> 3, e = d & 7;
  const int l16 = t & 15;
  const int lofs = (lq * 16 + l16) * 8 + e;
  if (hh < H_) {
    const float* q = QKV + rowoff + hh * 64;
    float x1 = q[d], x2 = q[d + 32];
    int tile = t >> 5, mf = (t >> 4) & 1;
    size_t base = ((size_t)(b * H_ + hh) * 64 + tile) * 2048;
    qb[base + (0 * 2 + mf) * 512 + lofs] = f2bf((x1 * c - x2 * s) * PREQ);  // ks=0
    qb[base + (1 * 2 + mf) * 512 + lofs] = f2bf((x2 * c + x1 * s) * PREQ);  // ks=1
  } else {
    int kh = hh - H_;
    const float* kp = QKV + rowoff + D_ + kh * 64;
    float x1 = kp[d], x2 = kp[d + 32];
    int it = t >> 6, nf = (t >> 4) & 3;
    size_t base = (size_t)(b * KVH_ + kh) * (T_ * HD_) + (size_t)it * 4096;
    kb[base + (0 * 8 + nf) * 512 + lofs] = f2bf(x1 * c - x2 * s);           // ks=0
    kb[base + (4 + nf) * 512 + lofs] = f2bf(x2 * c + x1 * s);               // ks=1
  }
}

// ---------------- V -> fragment-major bf16 (PV A-operand order) ----------------
__global__ void cvt_v_k(const float* __restrict__ QKV, uint16_t* __restrict__ vt) {
  int tid = blockIdx.x * 256 + threadIdx.x;
  int t8 = tid & 255;
  int rest = tid >> 8;
  int b = rest >> 9;
  int col = 2560 + (rest & 511);
  int d = rest & 63;
  int kvh = (rest >> 6) & 7;
  uint16_t tmp[8];
#pragma unroll
  for (int i = 0; i < 8; ++i)
    tmp[i] = f2bf(QKV[(size_t)(b * T_ + t8 * 8 + i) * NQKV_ + col]);
  uint4 v;
  v.x = (uint32_t)tmp[0] | ((uint32_t)tmp[1] << 16);
  v.y = (uint32_t)tmp[2] | ((uint32_t)tmp[3] << 16);
  v.z = (uint32_t)tmp[4] | ((uint32_t)tmp[5] << 16);
  v.w = (uint32_t)tmp[6] | ((uint32_t)tmp[7] << 16);
  int it = t8 >> 3, k2 = (t8 >> 2) & 1, lq = t8 & 3;
  int dn = d >> 4, l16 = d & 15;
  size_t base = (size_t)(b * KVH_ + kvh) * (T_ * HD_);
  *reinterpret_cast<uint4*>(vt + base + ((size_t)(it * 2 + k2) * 4 + dn) * 512 +
                            (lq * 16 + l16) * 8) = v;
}

// ---------------- flash attention (causal, GQA), swapped QK^T ----------------
__global__ __launch_bounds__(256, 2)
void flash_attn_k(const uint16_t* __restrict__ qb, const uint16_t* __restrict__ kb,
                  const uint16_t* __restrict__ vt, uint16_t* __restrict__ ob) {
  __shared__ __align__(16) uint16_t P_lds[4][32 * 72];  // per-wave 32 q x 64+pad
  const int lane = threadIdx.x & 63;
  const int w = threadIdx.x >> 6;
  const int l16 = lane & 15, lq = lane >> 4;
  const int bh = (blockIdx.x & 15) * 4 + w;
  const int rank = blockIdx.x >> 4;              // 0..63
  const int pair = rank & 31;
  const int tile = (rank & 32) ? (63 - pair) : pair;
  const int b = bh >> 5, h = bh & 31;
  const int kvh = h >> 2;
  uint16_t* P = P_lds[w];

  const uint16_t* Qp = qb + ((size_t)(b * H_ + h) * 64 + tile) * 2048;
  const uint16_t* Kp = kb + (size_t)(b * KVH_ + kvh) * (T_ * HD_);
  const uint16_t* Vp = vt + (size_t)(b * KVH_ + kvh) * (T_ * HD_);
  const int lofs = lane * 8;

  const int q0 = tile * 32;
  u32x4 ones_u = {0x3F803F80u, 0x3F803F80u, 0x3F803F80u, 0x3F803F80u};
  bf16x8 ones = __builtin_bit_cast(bf16x8, ones_u);

  bf16x8 aq[2][2];
#pragma unroll
  for (int mf = 0; mf < 2; ++mf)
#pragma unroll
    for (int ks = 0; ks < 2; ++ks)
      aq[mf][ks] = *reinterpret_cast<const bf16x8*>(Qp + (ks * 2 + mf) * 512 + lofs);

  f32x4 acc[2][4] = {};
  f32x4 acc_l[2] = {};

  const int nt = (tile >> 1) + 1;

  bf16x8 kA[2][4], kB[2][4];
#pragma unroll
  for (int ks = 0; ks < 2; ++ks)
#pragma unroll
    for (int nf = 0; nf < 4; ++nf)
      kA[ks][nf] = *reinterpret_cast<const bf16x8*>(Kp + (ks * 4 + nf) * 512 + lofs);

#define FLASH_STEP(KCUR, KNXT, IT)                                                     \
  do {                                                                                 \
    const int kv0 = (IT) * 64;                                                         \
    f32x4 sacc[4][2] = {};                                                             \
    _Pragma("unroll")                                                                  \
    for (int ks = 0; ks < 2; ++ks)                                                     \
      _Pragma("unroll")                                                                \
      for (int nf = 0; nf < 4; ++nf)                                                   \
        _Pragma("unroll")                                                              \
        for (int mf = 0; mf < 2; ++mf)                                                 \
          sacc[nf][mf] = __builtin_amdgcn_mfma_f32_16x16x32_bf16(                      \
              KCUR[ks][nf], aq[mf][ks], sacc[nf][mf], 0, 0, 0);                        \
    const int itn = ((IT) + 1 < nt) ? (IT) + 1 : (IT);                                 \
    _Pragma("unroll")                                                                  \
    for (int ks = 0; ks < 2; ++ks)                                                     \
      _Pragma("unroll")                                                                \
      for (int nf = 0; nf < 4; ++nf)                                                   \
        KNXT[ks][nf] = *reinterpret_cast<const bf16x8*>(                               \
            Kp + ((size_t)(itn * 2 + ks) * 4 + nf) * 512 + lofs);                      \
    bf16x8 vv[2][4];                                                                   \
    _Pragma("unroll")                                                                  \
    for (int k2 = 0; k2 < 2; ++k2)                                                     \
      _Pragma("unroll")                                                                \
      for (int dn = 0; dn < 4; ++dn)                                                   \
        vv[k2][dn] = *reinterpret_cast<const bf16x8*>(                                 \
            Vp + ((size_t)((IT) * 2 + k2) * 4 + dn) * 512 + lofs);                     \
    if ((IT) == nt - 1) {                                                              \
      _Pragma("unroll")                                                                \
      for (int mf = 0; mf < 2; ++mf) {                                                 \
        int qg = q0 + mf * 16 + l16;                                                   \
        _Pragma("unroll")                                                              \
        for (int nf = 0; nf < 4; ++nf)                                                 \
          _Pragma("unroll")                                                            \
          for (int r = 0; r < 4; ++r)                                                  \
            if (kv0 + nf * 16 + lq * 4 + r > qg) sacc[nf][mf][r] = -1e30f;             \
      }                                                                                \
    }                                                                                  \
    _Pragma("unroll")                                                                  \
    for (int mf = 0; mf < 2; ++mf) {                                                   \
      uint16_t* rowp = P + (mf * 16 + l16) * 72;                                       \
      _Pragma("unroll")                                                                \
      for (int nf = 0; nf < 4; ++nf) {                                                 \
        float p0 = __builtin_amdgcn_exp2f(sacc[nf][mf][0]);                            \
        float p1 = __builtin_amdgcn_exp2f(sacc[nf][mf][1]);                            \
        float p2 = __builtin_amdgcn_exp2f(sacc[nf][mf][2]);                            \
        float p3 = __builtin_amdgcn_exp2f(sacc[nf][mf][3]);                            \
        uint2 pk;                                                                      \
        pk.x = cvt_pk(p0, p1);                                                         \
        pk.y = cvt_pk(p2, p3);                                                         \
        *reinterpret_cast<uint2*>(rowp + nf * 16 + lq * 4) = pk;                       \
      }                                                                                \
    }                                                                                  \
    bf16x8 pa[2][2];                                                                   \
    _Pragma("unroll")                                                                  \
    for (int mf = 0; mf < 2; ++mf)                                                     \
      _Pragma("unroll")                                                                \
      for (int k2 = 0; k2 < 2; ++k2)                                                   \
        pa[mf][k2] = *reinterpret_cast<const bf16x8*>(                                 \
            P + (mf * 16 + l16) * 72 + k2 * 32 + lq * 8);                              \
    _Pragma("unroll")                                                                  \
    for (int k2 = 0; k2 < 2; ++k2)                                                     \
      _Pragma("unroll")                                                                \
      for (int mf = 0; mf < 2; ++mf) {                                                 \
        acc_l[mf] = __builtin_amdgcn_mfma_f32_16x16x32_bf16(ones, pa[mf][k2],          \
                                                            acc_l[mf], 0, 0, 0);      \
        _Pragma("unroll")                                                              \
        for (int dn = 0; dn < 4; ++dn)                                                 \
          acc[mf][dn] = __builtin_amdgcn_mfma_f32_16x16x32_bf16(                       \
              vv[k2][dn], pa[mf][k2], acc[mf][dn], 0, 0, 0);                           \
      }                                                                                \
  } while (0)

  {
    int it = 0;
    for (;;) {
      FLASH_STEP(kA, kB, it);
      ++it;
      if (it == nt) break;
      FLASH_STEP(kB, kA, it);
      ++it;
      if (it == nt) break;
    }
  }
#undef FLASH_STEP

#pragma unroll
  for (int mf = 0; mf < 2; ++mf) {
    float inv = 1.0f / acc_l[mf][0];
    uint16_t* rowp = P + (mf * 16 + l16) * 72;
#pragma unroll
    for (int dn = 0; dn < 4; ++dn) {
      uint2 pk;
      pk.x = cvt_pk(acc[mf][dn][0] * inv, acc[mf][dn][1] * inv);
      pk.y = cvt_pk(acc[mf][dn][2] * inv, acc[mf][dn][3] * inv);
      *reinterpret_cast<uint2*>(rowp + dn * 16 + lq * 4) = pk;
    }
  }
  {
    int orow = lane >> 1, ohalf = (lane & 1) * 32;
    uint16_t* op = ob + (size_t)(b * T_ + q0 + orow) * D_ + h * HD_ + ohalf;
    const uint16_t* lp = P + orow * 72 + ohalf;
#pragma unroll
    for (int j = 0; j < 4; ++j)
      *reinterpret_cast<uint4*>(op + j * 8) = *reinterpret_cast<const uint4*>(lp + j * 8);
  }
}

extern "C" void kernel_launch(void* const* d_in, const int* in_sizes, int n_in,
                              void* d_out, int out_size, void* d_ws, size_t ws_size,
                              hipStream_t stream) {
  const float* x  = (const float*)d_in[0];
  const float* Wq = (const float*)d_in[1];
  const float* bq = (const float*)d_in[2];
  const float* Wk = (const float*)d_in[3];
  const float* bk = (const float*)d_in[4];
  const float* Wv = (const float*)d_in[5];
  const float* bv = (const float*)d_in[6];
  const float* Wo = (const float*)d_in[7];
  const float* bo = (const float*)d_in[8];
  float* out = (float*)d_out;

  char* ws = (char*)d_ws;
  size_t off = 0;
  auto alloc = [&](size_t bytes) {
    void* p = ws + off;
    off += (bytes + 255) & ~(size_t)255;
    return p;
  };
  uint16_t* xb    = (uint16_t*)alloc((size_t)M_ * D_ * 2);
  uint16_t* wqkv  = (uint16_t*)alloc((size_t)NQKV_ * D_ * 2);
  uint16_t* wo_b  = (uint16_t*)alloc((size_t)D_ * D_ * 2);
  float*    bqkv  = (float*)alloc(NQKV_ * 4);
  float*    cosT  = (float*)alloc(T_ * 32 * 4);
  float*    sinT  = (float*)alloc(T_ * 32 * 4);
  uint16_t* q_bf  = (uint16_t*)alloc((size_t)B_ * H_ * T_ * HD_ * 2);
  uint16_t* k_bf  = (uint16_t*)alloc((size_t)B_ * KVH_ * T_ * HD_ * 2);
  uint16_t* vt_bf = (uint16_t*)alloc((size_t)B_ * KVH_ * T_ * HD_ * 2);
  float*    qkvf  = (float*)alloc((size_t)M_ * NQKV_ * 4);
  uint16_t* attn_bf = (uint16_t*)qkvf;  // reuse: QKV fp32 dead after rope/cvt_v

  cvt_bf16_k<<<4096, 256, 0, stream>>>(x, xb, M_ * D_);
  cvt_bf16_k<<<2048, 256, 0, stream>>>(Wq, wqkv, D_ * D_);
  cvt_bf16_k<<<512, 256, 0, stream>>>(Wk, wqkv + (size_t)D_ * D_, 512 * D_);
  cvt_bf16_k<<<512, 256, 0, stream>>>(Wv, wqkv + (size_t)2560 * D_, 512 * D_);
  cvt_bf16_k<<<2048, 256, 0, stream>>>(Wo, wo_b, D_ * D_);
  concat_bias_k<<<12, 256, 0, stream>>>(bq, bk, bv, bqkv);
  rope_tab_k<<<256, 256, 0, stream>>>(cosT, sinT);

  gemm256<<<dim3(NQKV_ / GBN, M_ / GBM), 512, 0, stream>>>(xb, wqkv, bqkv, qkvf, M_, NQKV_, D_);

  rope_qk_k<<<(B_ * 40 * T_ * 32) / 256, 256, 0, stream>>>(qkvf, cosT, sinT, q_bf, k_bf);
  cvt_v_k<<<(B_ * KVH_ * HD_ * (T_ / 8)) / 256, 256, 0, stream>>>(qkvf, vt_bf);

  flash_attn_k<<<1024, 256, 0, stream>>>(q_bf, k_bf, vt_bf, attn_bf);

  gemm256<<<dim3(D_ / GBN, M_ / GBM), 512, 0, stream>>>(attn_bf, wo_b, bo, out, M_, D_, D_);
}

// Round 14
// 232.331 us; speedup vs baseline: 1.0006x; 1.0001x over previous
//
#include <hip/hip_runtime.h>
#include <hip/hip_bf16.h>
#include <cstdint>

#define B_ 2
#define T_ 2048
#define D_ 2048
#define H_ 32
#define KVH_ 8
#define HD_ 64
#define NQKV_ 3072
#define M_ 4096

typedef __attribute__((ext_vector_type(8))) __bf16 bf16x8;
typedef __attribute__((ext_vector_type(4))) float f32x4;
typedef __attribute__((ext_vector_type(4))) uint32_t u32x4;

__device__ __forceinline__ uint16_t f2bf(float f) {
  uint32_t u = __builtin_bit_cast(uint32_t, f);
  return (uint16_t)((u + 0x7FFFu + ((u >> 16) & 1u)) >> 16);
}

__device__ __forceinline__ uint32_t cvt_pk(float lo, float hi) {
  uint32_t r;
  asm("v_cvt_pk_bf16_f32 %0, %1, %2" : "=v"(r) : "v"(lo), "v"(hi));
  return r;
}

__device__ __forceinline__ void gload_lds16(const void* g, void* l) {
  __builtin_amdgcn_global_load_lds(
      (const __attribute__((address_space(1))) void*)(uintptr_t)g,
      (__attribute__((address_space(3))) void*)(uintptr_t)l, 16, 0, 0);
}

// ---------------- fp32 -> bf16 convert (vectorized x8) ----------------
__global__ void cvt_bf16_k(const float* __restrict__ in, uint16_t* __restrict__ out, int n) {
  int i = (blockIdx.x * 256 + threadIdx.x) * 8;
  if (i >= n) return;
  float4 a = *reinterpret_cast<const float4*>(in + i);
  float4 b = *reinterpret_cast<const float4*>(in + i + 4);
  uint4 v;
  v.x = (uint32_t)f2bf(a.x) | ((uint32_t)f2bf(a.y) << 16);
  v.y = (uint32_t)f2bf(a.z) | ((uint32_t)f2bf(a.w) << 16);
  v.z = (uint32_t)f2bf(b.x) | ((uint32_t)f2bf(b.y) << 16);
  v.w = (uint32_t)f2bf(b.z) | ((uint32_t)f2bf(b.w) << 16);
  *reinterpret_cast<uint4*>(out + i) = v;
}

__global__ void concat_bias_k(const float* __restrict__ bq, const float* __restrict__ bk,
                              const float* __restrict__ bv, float* __restrict__ out) {
  int i = blockIdx.x * 256 + threadIdx.x;
  if (i >= NQKV_) return;
  out[i] = (i < D_) ? bq[i] : (i < D_ + 512) ? bk[i - D_] : bv[i - D_ - 512];
}

__global__ void rope_tab_k(float* __restrict__ cosT, float* __restrict__ sinT) {
  int i = blockIdx.x * 256 + threadIdx.x;  // 2048*32
  int d = i & 31;
  int t = i >> 5;
  float inv = expf(-(float)d * (1.0f / 32.0f) * logf(10000.0f));
  float f = (float)t * inv;
  cosT[i] = cosf(f);
  sinT[i] = sinf(f);
}

// ---------------- GEMM 256x256, BK=64, 8 waves, 4-phase schedule ----------------
// T2: LDS XOR-swizzle colb ^= (row&7)<<4, applied identically to the
// pre-swizzled global_load_lds SOURCE and the ds_read address (rule #21).
// T3/T4: next K-step's 8 gload_lds front-loaded at phase 0; single vmcnt(0)
// at phase 3 (3 phases of latency cover). T5: setprio around MFMA cluster.
// Raw s_barrier + explicit lgkmcnt(0) + sched_barrier(0) (rule #18) -- no
// __syncthreads full-drain in the loop.
#define GBM 256
#define GBN 256
#define GBK 64
__global__ __launch_bounds__(512, 2)
void gemm256(const uint16_t* __restrict__ A, const uint16_t* __restrict__ Bw,
             const float* __restrict__ bias, float* __restrict__ C,
             int M, int N, int K) {
  __shared__ __align__(16) uint16_t lds[2][2][GBM * GBK];  // 128 KiB
  const int tid = threadIdx.x;
  const int lane = tid & 63;
  const int w = tid >> 6;            // 0..7
  const int wm = w >> 2, wn = w & 3; // 2 x 4 wave grid; per-wave 128x64
  const int l16 = lane & 15, lq = lane >> 4;

  int lin = blockIdx.y * gridDim.x + blockIdx.x;
  int qn = (gridDim.x * gridDim.y) >> 3;   // nwg % 8 == 0 for both calls
  int swz = (lin & 7) * qn + (lin >> 3);
  const int m0 = (swz / gridDim.x) * GBM, n0 = (swz % gridDim.x) * GBN;

  // stage one K-step (A 32KB + B 32KB): per-thread 4+4 gload_lds of 16B.
  // linear LDS dest off = w*4096 + j*1024 + lane*16; source pre-swizzled.
  auto stage = [&](int dbuf, int kt) {
    int k0 = kt * GBK;
#pragma unroll
    for (int j = 0; j < 4; ++j) {
      int off = w * 4096 + j * 1024 + lane * 16;
      int row = off >> 7;
      int colb = (off & 127) ^ ((row & 7) << 4);
      gload_lds16(A + (size_t)(m0 + row) * K + k0 + (colb >> 1),
                  (char*)&lds[dbuf][0][0] + off);
    }
#pragma unroll
    for (int j = 0; j < 4; ++j) {
      int off = w * 4096 + j * 1024 + lane * 16;
      int row = off >> 7;
      int colb = (off & 127) ^ ((row & 7) << 4);
      gload_lds16(Bw + (size_t)(n0 + row) * K + k0 + (colb >> 1),
                  (char*)&lds[dbuf][1][0] + off);
    }
  };

  f32x4 acc[8][4] = {};
  const int NT = K / GBK;

  stage(0, 0);
  asm volatile("s_waitcnt vmcnt(0)" ::: "memory");
  __builtin_amdgcn_s_barrier();

  for (int t = 0; t < NT; ++t) {
    const int cur = t & 1;
    const char* Ab = (const char*)&lds[cur][0][0];
    const char* Bb = (const char*)&lds[cur][1][0];

    // phase 0 head: issue next K-step's loads into the other dbuf
    stage(cur ^ 1, (t + 1 < NT) ? t + 1 : 0);  // tail: junk-clamped, never read

    // B fragments for the whole K-step (held across phases)
    bf16x8 bfr[4][2];
#pragma unroll
    for (int ni = 0; ni < 4; ++ni)
#pragma unroll
      for (int ks = 0; ks < 2; ++ks) {
        int R = wn * 64 + ni * 16 + l16;
        int colb = (ks * 64 + lq * 16) ^ ((R & 7) << 4);
        bfr[ni][ks] = *reinterpret_cast<const bf16x8*>(Bb + R * 128 + colb);
      }

#pragma unroll
    for (int q = 0; q < 4; ++q) {   // 4 phases: quadrant = mi pair {2q, 2q+1}
      bf16x8 afr[2][2];
#pragma unroll
      for (int mi2 = 0; mi2 < 2; ++mi2)
#pragma unroll
        for (int ks = 0; ks < 2; ++ks) {
          int R = wm * 128 + (q * 2 + mi2) * 16 + l16;
          int colb = (ks * 64 + lq * 16) ^ ((R & 7) << 4);
          afr[mi2][ks] = *reinterpret_cast<const bf16x8*>(Ab + R * 128 + colb);
        }
      if (q == 3) asm volatile("s_waitcnt vmcnt(0)" ::: "memory");  // next dbuf landed
      __builtin_amdgcn_s_barrier();
      asm volatile("s_waitcnt lgkmcnt(0)" ::: "memory");
      __builtin_amdgcn_sched_barrier(0);   // rule #18: pin MFMA below the wait
      __builtin_amdgcn_s_setprio(1);
#pragma unroll
      for (int ks = 0; ks < 2; ++ks)
#pragma unroll
        for (int mi2 = 0; mi2 < 2; ++mi2)
#pragma unroll
          for (int ni = 0; ni < 4; ++ni)
            acc[q * 2 + mi2][ni] = __builtin_amdgcn_mfma_f32_16x16x32_bf16(
                afr[mi2][ks], bfr[ni][ks], acc[q * 2 + mi2][ni], 0, 0, 0);
      __builtin_amdgcn_s_setprio(0);
      __builtin_amdgcn_s_barrier();
    }
  }

  // epilogue: bias + fp32 C
#pragma unroll
  for (int mi = 0; mi < 8; ++mi) {
    int r0 = m0 + wm * 128 + mi * 16 + lq * 4;
#pragma unroll
    for (int ni = 0; ni < 4; ++ni) {
      int c = n0 + wn * 64 + ni * 16 + l16;
      float bb = bias[c];
#pragma unroll
      for (int rr = 0; rr < 4; ++rr)
        C[(size_t)(r0 + rr) * N + c] = acc[mi][ni][rr] + bb;
    }
  }
}

// ---------------- RoPE on Q,K + pack to FRAGMENT-MAJOR bf16 layouts ----------------
__global__ void rope_qk_k(const float* __restrict__ QKV, const float* __restrict__ cosT,
                          const float* __restrict__ sinT, uint16_t* __restrict__ qb,
                          uint16_t* __restrict__ kb) {
  int tid = blockIdx.x * 256 + threadIdx.x;  // B*40*T*32
  int d = tid & 31;                           // rope pair index: (d, d+32)
  int t = (tid >> 5) & (T_ - 1);
  int rest = tid >> 16;
  int hh = rest % 40;
  int b = rest / 40;
  const float PREQ = 0.125f * 1.44269504f;
  float c = cosT[t * 32 + d];
  float s = sinT[t * 32 + d];
  size_t rowoff = (size_t)(b * T_ + t) * NQKV_;
  const int lq = d >> 3, e = d & 7;
  const int l16 = t & 15;
  const int lofs = (lq * 16 + l16) * 8 + e;
  if (hh < H_) {
    const float* q = QKV + rowoff + hh * 64;
    float x1 = q[d], x2 = q[d + 32];
    int tile = t >> 5, mf = (t >> 4) & 1;
    size_t base = ((size_t)(b * H_ + hh) * 64 + tile) * 2048;
    qb[base + (0 * 2 + mf) * 512 + lofs] = f2bf((x1 * c - x2 * s) * PREQ);  // ks=0
    qb[base + (1 * 2 + mf) * 512 + lofs] = f2bf((x2 * c + x1 * s) * PREQ);  // ks=1
  } else {
    int kh = hh - H_;
    const float* kp = QKV + rowoff + D_ + kh * 64;
    float x1 = kp[d], x2 = kp[d + 32];
    int it = t >> 6, nf = (t >> 4) & 3;
    size_t base = (size_t)(b * KVH_ + kh) * (T_ * HD_) + (size_t)it * 4096;
    kb[base + (0 * 8 + nf) * 512 + lofs] = f2bf(x1 * c - x2 * s);           // ks=0
    kb[base + (4 + nf) * 512 + lofs] = f2bf(x2 * c + x1 * s);               // ks=1
  }
}

// ---------------- V -> fragment-major bf16 (PV A-operand order) ----------------
__global__ void cvt_v_k(const float* __restrict__ QKV, uint16_t* __restrict__ vt) {
  int tid = blockIdx.x * 256 + threadIdx.x;
  int t8 = tid & 255;
  int rest = tid >> 8;
  int b = rest >> 9;
  int col = 2560 + (rest & 511);
  int d = rest & 63;
  int kvh = (rest >> 6) & 7;
  uint16_t tmp[8];
#pragma unroll
  for (int i = 0; i < 8; ++i)
    tmp[i] = f2bf(QKV[(size_t)(b * T_ + t8 * 8 + i) * NQKV_ + col]);
  uint4 v;
  v.x = (uint32_t)tmp[0] | ((uint32_t)tmp[1] << 16);
  v.y = (uint32_t)tmp[2] | ((uint32_t)tmp[3] << 16);
  v.z = (uint32_t)tmp[4] | ((uint32_t)tmp[5] << 16);
  v.w = (uint32_t)tmp[6] | ((uint32_t)tmp[7] << 16);
  int it = t8 >> 3, k2 = (t8 >> 2) & 1, lq = t8 & 3;
  int dn = d >> 4, l16 = d & 15;
  size_t base = (size_t)(b * KVH_ + kvh) * (T_ * HD_);
  *reinterpret_cast<uint4*>(vt + base + ((size_t)(it * 2 + k2) * 4 + dn) * 512 +
                            (lq * 16 + l16) * 8) = v;
}

// ---------------- flash attention (causal, GQA), swapped QK^T ----------------
__global__ __launch_bounds__(256, 2)
void flash_attn_k(const uint16_t* __restrict__ qb, const uint16_t* __restrict__ kb,
                  const uint16_t* __restrict__ vt, uint16_t* __restrict__ ob) {
  __shared__ __align__(16) uint16_t P_lds[4][32 * 72];  // per-wave 32 q x 64+pad
  const int lane = threadIdx.x & 63;
  const int w = threadIdx.x >> 6;
  const int l16 = lane & 15, lq = lane >> 4;
  const int bh = (blockIdx.x & 15) * 4 + w;
  const int rank = blockIdx.x >> 4;              // 0..63
  const int pair = rank & 31;
  const int tile = (rank & 32) ? (63 - pair) : pair;
  const int b = bh >> 5, h = bh & 31;
  const int kvh = h >> 2;
  uint16_t* P = P_lds[w];

  const uint16_t* Qp = qb + ((size_t)(b * H_ + h) * 64 + tile) * 2048;
  const uint16_t* Kp = kb + (size_t)(b * KVH_ + kvh) * (T_ * HD_);
  const uint16_t* Vp = vt + (size_t)(b * KVH_ + kvh) * (T_ * HD_);
  const int lofs = lane * 8;

  const int q0 = tile * 32;
  u32x4 ones_u = {0x3F803F80u, 0x3F803F80u, 0x3F803F80u, 0x3F803F80u};
  bf16x8 ones = __builtin_bit_cast(bf16x8, ones_u);

  bf16x8 aq[2][2];
#pragma unroll
  for (int mf = 0; mf < 2; ++mf)
#pragma unroll
    for (int ks = 0; ks < 2; ++ks)
      aq[mf][ks] = *reinterpret_cast<const bf16x8*>(Qp + (ks * 2 + mf) * 512 + lofs);

  f32x4 acc[2][4] = {};
  f32x4 acc_l[2] = {};

  const int nt = (tile >> 1) + 1;

  bf16x8 kA[2][4], kB[2][4];
#pragma unroll
  for (int ks = 0; ks < 2; ++ks)
#pragma unroll
    for (int nf = 0; nf < 4; ++nf)
      kA[ks][nf] = *reinterpret_cast<const bf16x8*>(Kp + (ks * 4 + nf) * 512 + lofs);

#define FLASH_STEP(KCUR, KNXT, IT)                                                     \
  do {                                                                                 \
    const int kv0 = (IT) * 64;                                                         \
    f32x4 sacc[4][2] = {};                                                             \
    _Pragma("unroll")                                                                  \
    for (int ks = 0; ks < 2; ++ks)                                                     \
      _Pragma("unroll")                                                                \
      for (int nf = 0; nf < 4; ++nf)                                                   \
        _Pragma("unroll")                                                              \
        for (int mf = 0; mf < 2; ++mf)                                                 \
          sacc[nf][mf] = __builtin_amdgcn_mfma_f32_16x16x32_bf16(                      \
              KCUR[ks][nf], aq[mf][ks], sacc[nf][mf], 0, 0, 0);                        \
    const int itn = ((IT) + 1 < nt) ? (IT) + 1 : (IT);                                 \
    _Pragma("unroll")                                                                  \
    for (int ks = 0; ks < 2; ++ks)                                                     \
      _Pragma("unroll")                                                                \
      for (int nf = 0; nf < 4; ++nf)                                                   \
        KNXT[ks][nf] = *reinterpret_cast<const bf16x8*>(                               \
            Kp + ((size_t)(itn * 2 + ks) * 4 + nf) * 512 + lofs);                      \
    bf16x8 vv[2][4];                                                                   \
    _Pragma("unroll")                                                                  \
    for (int k2 = 0; k2 < 2; ++k2)                                                     \
      _Pragma("unroll")                                                                \
      for (int dn = 0; dn < 4; ++dn)                                                   \
        vv[k2][dn] = *reinterpret_cast<const bf16x8*>(                                 \
            Vp + ((size_t)((IT) * 2 + k2) * 4 + dn) * 512 + lofs);                     \
    if ((IT) == nt - 1) {                                                              \
      _Pragma("unroll")                                                                \
      for (int mf = 0; mf < 2; ++mf) {                                                 \
        int qg = q0 + mf * 16 + l16;                                                   \
        _Pragma("unroll")                                                              \
        for (int nf = 0; nf < 4; ++nf)                                                 \
          _Pragma("unroll")                                                            \
          for (int r = 0; r < 4; ++r)                                                  \
            if (kv0 + nf * 16 + lq * 4 + r > qg) sacc[nf][mf][r] = -1e30f;             \
      }                                                                                \
    }                                                                                  \
    _Pragma("unroll")                                                                  \
    for (int mf = 0; mf < 2; ++mf) {                                                   \
      uint16_t* rowp = P + (mf * 16 + l16) * 72;                                       \
      _Pragma("unroll")                                                                \
      for (int nf = 0; nf < 4; ++nf) {                                                 \
        float p0 = __builtin_amdgcn_exp2f(sacc[nf][mf][0]);                            \
        float p1 = __builtin_amdgcn_exp2f(sacc[nf][mf][1]);                            \
        float p2 = __builtin_amdgcn_exp2f(sacc[nf][mf][2]);                            \
        float p3 = __builtin_amdgcn_exp2f(sacc[nf][mf][3]);                            \
        uint2 pk;                                                                      \
        pk.x = cvt_pk(p0, p1);                                                         \
        pk.y = cvt_pk(p2, p3);                                                         \
        *reinterpret_cast<uint2*>(rowp + nf * 16 + lq * 4) = pk;                       \
      }                                                                                \
    }                                                                                  \
    bf16x8 pa[2][2];                                                                   \
    _Pragma("unroll")                                                                  \
    for (int mf = 0; mf < 2; ++mf)                                                     \
      _Pragma("unroll")                                                                \
      for (int k2 = 0; k2 < 2; ++k2)                                                   \
        pa[mf][k2] = *reinterpret_cast<const bf16x8*>(                                 \
            P + (mf * 16 + l16) * 72 + k2 * 32 + lq * 8);                              \
    _Pragma("unroll")                                                                  \
    for (int k2 = 0; k2 < 2; ++k2)                                                     \
      _Pragma("unroll")                                                                \
      for (int mf = 0; mf < 2; ++mf) {                                                 \
        acc_l[mf] = __builtin_amdgcn_mfma_f32_16x16x32_bf16(ones, pa[mf][k2],          \
                                                            acc_l[mf], 0, 0, 0);      \
        _Pragma("unroll")                                                              \
        for (int dn = 0; dn < 4; ++dn)                                                 \
          acc[mf][dn] = __builtin_amdgcn_mfma_f32_16x16x32_bf16(                       \
              vv[k2][dn], pa[mf][k2], acc[mf][dn], 0, 0, 0);                           \
      }                                                                                \
  } while (0)

  {
    int it = 0;
    for (;;) {
      FLASH_STEP(kA, kB, it);
      ++it;
      if (it == nt) break;
      FLASH_STEP(kB, kA, it);
      ++it;
      if (it == nt) break;
    }
  }
#undef FLASH_STEP

#pragma unroll
  for (int mf = 0; mf < 2; ++mf) {
    float inv = 1.0f / acc_l[mf][0];
    uint16_t* rowp = P + (mf * 16 + l16) * 72;
#pragma unroll
    for (int dn = 0; dn < 4; ++dn) {
      uint2 pk;
      pk.x = cvt_pk(acc[mf][dn][0] * inv, acc[mf][dn][1] * inv);
      pk.y = cvt_pk(acc[mf][dn][2] * inv, acc[mf][dn][3] * inv);
      *reinterpret_cast<uint2*>(rowp + dn * 16 + lq * 4) = pk;
    }
  }
  {
    int orow = lane >> 1, ohalf = (lane & 1) * 32;
    uint16_t* op = ob + (size_t)(b * T_ + q0 + orow) * D_ + h * HD_ + ohalf;
    const uint16_t* lp = P + orow * 72 + ohalf;
#pragma unroll
    for (int j = 0; j < 4; ++j)
      *reinterpret_cast<uint4*>(op + j * 8) = *reinterpret_cast<const uint4*>(lp + j * 8);
  }
}

extern "C" void kernel_launch(void* const* d_in, const int* in_sizes, int n_in,
                              void* d_out, int out_size, void* d_ws, size_t ws_size,
                              hipStream_t stream) {
  const float* x  = (const float*)d_in[0];
  const float* Wq = (const float*)d_in[1];
  const float* bq = (const float*)d_in[2];
  const float* Wk = (const float*)d_in[3];
  const float* bk = (const float*)d_in[4];
  const float* Wv = (const float*)d_in[5];
  const float* bv = (const float*)d_in[6];
  const float* Wo = (const float*)d_in[7];
  const float* bo = (const float*)d_in[8];
  float* out = (float*)d_out;

  char* ws = (char*)d_ws;
  size_t off = 0;
  auto alloc = [&](size_t bytes) {
    void* p = ws + off;
    off += (bytes + 255) & ~(size_t)255;
    return p;
  };
  uint16_t* xb    = (uint16_t*)alloc((size_t)M_ * D_ * 2);
  uint16_t* wqkv  = (uint16_t*)alloc((size_t)NQKV_ * D_ * 2);
  uint16_t* wo_b  = (uint16_t*)alloc((size_t)D_ * D_ * 2);
  float*    bqkv  = (float*)alloc(NQKV_ * 4);
  float*    cosT  = (float*)alloc(T_ * 32 * 4);
  float*    sinT  = (float*)alloc(T_ * 32 * 4);
  uint16_t* q_bf  = (uint16_t*)alloc((size_t)B_ * H_ * T_ * HD_ * 2);
  uint16_t* k_bf  = (uint16_t*)alloc((size_t)B_ * KVH_ * T_ * HD_ * 2);
  uint16_t* vt_bf = (uint16_t*)alloc((size_t)B_ * KVH_ * T_ * HD_ * 2);
  float*    qkvf  = (float*)alloc((size_t)M_ * NQKV_ * 4);
  uint16_t* attn_bf = (uint16_t*)qkvf;  // reuse: QKV fp32 dead after rope/cvt_v

  cvt_bf16_k<<<4096, 256, 0, stream>>>(x, xb, M_ * D_);
  cvt_bf16_k<<<2048, 256, 0, stream>>>(Wq, wqkv, D_ * D_);
  cvt_bf16_k<<<512, 256, 0, stream>>>(Wk, wqkv + (size_t)D_ * D_, 512 * D_);
  cvt_bf16_k<<<512, 256, 0, stream>>>(Wv, wqkv + (size_t)2560 * D_, 512 * D_);
  cvt_bf16_k<<<2048, 256, 0, stream>>>(Wo, wo_b, D_ * D_);
  concat_bias_k<<<12, 256, 0, stream>>>(bq, bk, bv, bqkv);
  rope_tab_k<<<256, 256, 0, stream>>>(cosT, sinT);

  gemm256<<<dim3(NQKV_ / GBN, M_ / GBM), 512, 0, stream>>>(xb, wqkv, bqkv, qkvf, M_, NQKV_, D_);

  rope_qk_k<<<(B_ * 40 * T_ * 32) / 256, 256, 0, stream>>>(qkvf, cosT, sinT, q_bf, k_bf);
  cvt_v_k<<<(B_ * KVH_ * HD_ * (T_ / 8)) / 256, 256, 0, stream>>>(qkvf, vt_bf);

  flash_attn_k<<<1024, 256, 0, stream>>>(q_bf, k_bf, vt_bf, attn_bf);

  gemm256<<<dim3(D_ / GBN, M_ / GBM), 512, 0, stream>>>(attn_bf, wo_b, bo, out, M_, D_, D_);
}

// Round 15
// 232.135 us; speedup vs baseline: 1.0014x; 1.0008x over previous
//
#include <hip/hip_runtime.h>
#include <hip/hip_bf16.h>
#include <cstdint>

#define B_ 2
#define T_ 2048
#define D_ 2048
#define H_ 32
#define KVH_ 8
#define HD_ 64
#define NQKV_ 3072
#define M_ 4096

typedef __attribute__((ext_vector_type(8))) __bf16 bf16x8;
typedef __attribute__((ext_vector_type(4))) float f32x4;
typedef __attribute__((ext_vector_type(4))) uint32_t u32x4;

__device__ __forceinline__ uint16_t f2bf(float f) {
  uint32_t u = __builtin_bit_cast(uint32_t, f);
  return (uint16_t)((u + 0x7FFFu + ((u >> 16) & 1u)) >> 16);
}

__device__ __forceinline__ uint32_t cvt_pk(float lo, float hi) {
  uint32_t r;
  asm("v_cvt_pk_bf16_f32 %0, %1, %2" : "=v"(r) : "v"(lo), "v"(hi));
  return r;
}

__device__ __forceinline__ void gload_lds16(const void* g, void* l) {
  __builtin_amdgcn_global_load_lds(
      (const __attribute__((address_space(1))) void*)(uintptr_t)g,
      (__attribute__((address_space(3))) void*)(uintptr_t)l, 16, 0, 0);
}

// ---------------- fp32 -> bf16 convert (vectorized x8) ----------------
__global__ void cvt_bf16_k(const float* __restrict__ in, uint16_t* __restrict__ out, int n) {
  int i = (blockIdx.x * 256 + threadIdx.x) * 8;
  if (i >= n) return;
  float4 a = *reinterpret_cast<const float4*>(in + i);
  float4 b = *reinterpret_cast<const float4*>(in + i + 4);
  uint4 v;
  v.x = (uint32_t)f2bf(a.x) | ((uint32_t)f2bf(a.y) << 16);
  v.y = (uint32_t)f2bf(a.z) | ((uint32_t)f2bf(a.w) << 16);
  v.z = (uint32_t)f2bf(b.x) | ((uint32_t)f2bf(b.y) << 16);
  v.w = (uint32_t)f2bf(b.z) | ((uint32_t)f2bf(b.w) << 16);
  *reinterpret_cast<uint4*>(out + i) = v;
}

__global__ void concat_bias_k(const float* __restrict__ bq, const float* __restrict__ bk,
                              const float* __restrict__ bv, float* __restrict__ out) {
  int i = blockIdx.x * 256 + threadIdx.x;
  if (i >= NQKV_) return;
  out[i] = (i < D_) ? bq[i] : (i < D_ + 512) ? bk[i - D_] : bv[i - D_ - 512];
}

__global__ void rope_tab_k(float* __restrict__ cosT, float* __restrict__ sinT) {
  int i = blockIdx.x * 256 + threadIdx.x;  // 2048*32
  int d = i & 31;
  int t = i >> 5;
  float inv = expf(-(float)d * (1.0f / 32.0f) * logf(10000.0f));
  float f = (float)t * inv;
  cosT[i] = cosf(f);
  sinT[i] = sinf(f);
}

// ---------------- GEMM 256x256, BK=64, 8 waves, 4-phase schedule ----------------
// T2: LDS XOR-swizzle colb ^= (row&7)<<4, applied identically to the
// pre-swizzled global_load_lds SOURCE and the ds_read address (rule #21).
// T3/T4: next K-step's 8 gload_lds front-loaded at phase 0; single vmcnt(0)
// at phase 3 (3 phases of latency cover). T5: setprio around MFMA cluster.
// Raw s_barrier + explicit lgkmcnt(0) + sched_barrier(0) (rule #18) -- no
// __syncthreads full-drain in the loop.
#define GBM 256
#define GBN 256
#define GBK 64
__global__ __launch_bounds__(512, 2)
void gemm256(const uint16_t* __restrict__ A, const uint16_t* __restrict__ Bw,
             const float* __restrict__ bias, float* __restrict__ C,
             int M, int N, int K) {
  __shared__ __align__(16) uint16_t lds[2][2][GBM * GBK];  // 128 KiB
  const int tid = threadIdx.x;
  const int lane = tid & 63;
  const int w = tid >> 6;            // 0..7
  const int wm = w >> 2, wn = w & 3; // 2 x 4 wave grid; per-wave 128x64
  const int l16 = lane & 15, lq = lane >> 4;

  int lin = blockIdx.y * gridDim.x + blockIdx.x;
  int qn = (gridDim.x * gridDim.y) >> 3;   // nwg % 8 == 0 for both calls
  int swz = (lin & 7) * qn + (lin >> 3);
  const int m0 = (swz / gridDim.x) * GBM, n0 = (swz % gridDim.x) * GBN;

  // stage one K-step (A 32KB + B 32KB): per-thread 4+4 gload_lds of 16B.
  // linear LDS dest off = w*4096 + j*1024 + lane*16; source pre-swizzled.
  auto stage = [&](int dbuf, int kt) {
    int k0 = kt * GBK;
#pragma unroll
    for (int j = 0; j < 4; ++j) {
      int off = w * 4096 + j * 1024 + lane * 16;
      int row = off >> 7;
      int colb = (off & 127) ^ ((row & 7) << 4);
      gload_lds16(A + (size_t)(m0 + row) * K + k0 + (colb >> 1),
                  (char*)&lds[dbuf][0][0] + off);
    }
#pragma unroll
    for (int j = 0; j < 4; ++j) {
      int off = w * 4096 + j * 1024 + lane * 16;
      int row = off >> 7;
      int colb = (off & 127) ^ ((row & 7) << 4);
      gload_lds16(Bw + (size_t)(n0 + row) * K + k0 + (colb >> 1),
                  (char*)&lds[dbuf][1][0] + off);
    }
  };

  f32x4 acc[8][4] = {};
  const int NT = K / GBK;

  stage(0, 0);
  asm volatile("s_waitcnt vmcnt(0)" ::: "memory");
  __builtin_amdgcn_s_barrier();

  for (int t = 0; t < NT; ++t) {
    const int cur = t & 1;
    const char* Ab = (const char*)&lds[cur][0][0];
    const char* Bb = (const char*)&lds[cur][1][0];

    // phase 0 head: issue next K-step's loads into the other dbuf
    stage(cur ^ 1, (t + 1 < NT) ? t + 1 : 0);  // tail: junk-clamped, never read

    // B fragments for the whole K-step (held across phases)
    bf16x8 bfr[4][2];
#pragma unroll
    for (int ni = 0; ni < 4; ++ni)
#pragma unroll
      for (int ks = 0; ks < 2; ++ks) {
        int R = wn * 64 + ni * 16 + l16;
        int colb = (ks * 64 + lq * 16) ^ ((R & 7) << 4);
        bfr[ni][ks] = *reinterpret_cast<const bf16x8*>(Bb + R * 128 + colb);
      }

#pragma unroll
    for (int q = 0; q < 4; ++q) {   // 4 phases: quadrant = mi pair {2q, 2q+1}
      bf16x8 afr[2][2];
#pragma unroll
      for (int mi2 = 0; mi2 < 2; ++mi2)
#pragma unroll
        for (int ks = 0; ks < 2; ++ks) {
          int R = wm * 128 + (q * 2 + mi2) * 16 + l16;
          int colb = (ks * 64 + lq * 16) ^ ((R & 7) << 4);
          afr[mi2][ks] = *reinterpret_cast<const bf16x8*>(Ab + R * 128 + colb);
        }
      if (q == 3) asm volatile("s_waitcnt vmcnt(0)" ::: "memory");  // next dbuf landed
      __builtin_amdgcn_s_barrier();
      asm volatile("s_waitcnt lgkmcnt(0)" ::: "memory");
      __builtin_amdgcn_sched_barrier(0);   // rule #18: pin MFMA below the wait
      __builtin_amdgcn_s_setprio(1);
#pragma unroll
      for (int ks = 0; ks < 2; ++ks)
#pragma unroll
        for (int mi2 = 0; mi2 < 2; ++mi2)
#pragma unroll
          for (int ni = 0; ni < 4; ++ni)
            acc[q * 2 + mi2][ni] = __builtin_amdgcn_mfma_f32_16x16x32_bf16(
                afr[mi2][ks], bfr[ni][ks], acc[q * 2 + mi2][ni], 0, 0, 0);
      __builtin_amdgcn_s_setprio(0);
      __builtin_amdgcn_s_barrier();
    }
  }

  // epilogue: bias + fp32 C
#pragma unroll
  for (int mi = 0; mi < 8; ++mi) {
    int r0 = m0 + wm * 128 + mi * 16 + lq * 4;
#pragma unroll
    for (int ni = 0; ni < 4; ++ni) {
      int c = n0 + wn * 64 + ni * 16 + l16;
      float bb = bias[c];
#pragma unroll
      for (int rr = 0; rr < 4; ++rr)
        C[(size_t)(r0 + rr) * N + c] = acc[mi][ni][rr] + bb;
    }
  }
}

// ---------------- RoPE on Q,K + pack to FRAGMENT-MAJOR bf16 layouts ----------------
__global__ void rope_qk_k(const float* __restrict__ QKV, const float* __restrict__ cosT,
                          const float* __restrict__ sinT, uint16_t* __restrict__ qb,
                          uint16_t* __restrict__ kb) {
  int tid = blockIdx.x * 256 + threadIdx.x;  // B*40*T*32
  int d = tid & 31;                           // rope pair index: (d, d+32)
  int t = (tid >> 5) & (T_ - 1);
  int rest = tid >> 16;
  int hh = rest % 40;
  int b = rest / 40;
  const float PREQ = 0.125f * 1.44269504f;
  float c = cosT[t * 32 + d];
  float s = sinT[t * 32 + d];
  size_t rowoff = (size_t)(b * T_ + t) * NQKV_;
  const int lq = d >> 3, e = d & 7;
  const int l16 = t & 15;
  const int lofs = (lq * 16 + l16) * 8 + e;
  if (hh < H_) {
    const float* q = QKV + rowoff + hh * 64;
    float x1 = q[d], x2 = q[d + 32];
    int tile = t >> 5, mf = (t >> 4) & 1;
    size_t base = ((size_t)(b * H_ + hh) * 64 + tile) * 2048;
    qb[base + (0 * 2 + mf) * 512 + lofs] = f2bf((x1 * c - x2 * s) * PREQ);  // ks=0
    qb[base + (1 * 2 + mf) * 512 + lofs] = f2bf((x2 * c + x1 * s) * PREQ);  // ks=1
  } else {
    int kh = hh - H_;
    const float* kp = QKV + rowoff + D_ + kh * 64;
    float x1 = kp[d], x2 = kp[d + 32];
    int it = t >> 6, nf = (t >> 4) & 3;
    size_t base = (size_t)(b * KVH_ + kh) * (T_ * HD_) + (size_t)it * 4096;
    kb[base + (0 * 8 + nf) * 512 + lofs] = f2bf(x1 * c - x2 * s);           // ks=0
    kb[base + (4 + nf) * 512 + lofs] = f2bf(x2 * c + x1 * s);               // ks=1
  }
}

// ---------------- V -> fragment-major bf16 (PV A-operand order) ----------------
__global__ void cvt_v_k(const float* __restrict__ QKV, uint16_t* __restrict__ vt) {
  int tid = blockIdx.x * 256 + threadIdx.x;
  int t8 = tid & 255;
  int rest = tid >> 8;
  int b = rest >> 9;
  int col = 2560 + (rest & 511);
  int d = rest & 63;
  int kvh = (rest >> 6) & 7;
  uint16_t tmp[8];
#pragma unroll
  for (int i = 0; i < 8; ++i)
    tmp[i] = f2bf(QKV[(size_t)(b * T_ + t8 * 8 + i) * NQKV_ + col]);
  uint4 v;
  v.x = (uint32_t)tmp[0] | ((uint32_t)tmp[1] << 16);
  v.y = (uint32_t)tmp[2] | ((uint32_t)tmp[3] << 16);
  v.z = (uint32_t)tmp[4] | ((uint32_t)tmp[5] << 16);
  v.w = (uint32_t)tmp[6] | ((uint32_t)tmp[7] << 16);
  int it = t8 >> 3, k2 = (t8 >> 2) & 1, lq = t8 & 3;
  int dn = d >> 4, l16 = d & 15;
  size_t base = (size_t)(b * KVH_ + kvh) * (T_ * HD_);
  *reinterpret_cast<uint4*>(vt + base + ((size_t)(it * 2 + k2) * 4 + dn) * 512 +
                            (lq * 16 + l16) * 8) = v;
}

// ---------------- flash attention (causal, GQA), swapped QK^T ----------------
__global__ __launch_bounds__(256, 2)
void flash_attn_k(const uint16_t* __restrict__ qb, const uint16_t* __restrict__ kb,
                  const uint16_t* __restrict__ vt, uint16_t* __restrict__ ob) {
  __shared__ __align__(16) uint16_t P_lds[4][32 * 72];  // per-wave 32 q x 64+pad
  const int lane = threadIdx.x & 63;
  const int w = threadIdx.x >> 6;
  const int l16 = lane & 15, lq = lane >> 4;
  const int bh = (blockIdx.x & 15) * 4 + w;
  const int rank = blockIdx.x >> 4;              // 0..63
  const int pair = rank & 31;
  const int tile = (rank & 32) ? (63 - pair) : pair;
  const int b = bh >> 5, h = bh & 31;
  const int kvh = h >> 2;
  uint16_t* P = P_lds[w];

  const uint16_t* Qp = qb + ((size_t)(b * H_ + h) * 64 + tile) * 2048;
  const uint16_t* Kp = kb + (size_t)(b * KVH_ + kvh) * (T_ * HD_);
  const uint16_t* Vp = vt + (size_t)(b * KVH_ + kvh) * (T_ * HD_);
  const int lofs = lane * 8;

  const int q0 = tile * 32;
  u32x4 ones_u = {0x3F803F80u, 0x3F803F80u, 0x3F803F80u, 0x3F803F80u};
  bf16x8 ones = __builtin_bit_cast(bf16x8, ones_u);

  bf16x8 aq[2][2];
#pragma unroll
  for (int mf = 0; mf < 2; ++mf)
#pragma unroll
    for (int ks = 0; ks < 2; ++ks)
      aq[mf][ks] = *reinterpret_cast<const bf16x8*>(Qp + (ks * 2 + mf) * 512 + lofs);

  f32x4 acc[2][4] = {};
  f32x4 acc_l[2] = {};

  const int nt = (tile >> 1) + 1;

  bf16x8 kA[2][4], kB[2][4];
#pragma unroll
  for (int ks = 0; ks < 2; ++ks)
#pragma unroll
    for (int nf = 0; nf < 4; ++nf)
      kA[ks][nf] = *reinterpret_cast<const bf16x8*>(Kp + (ks * 4 + nf) * 512 + lofs);

#define FLASH_STEP(KCUR, KNXT, IT)                                                     \
  do {                                                                                 \
    const int kv0 = (IT) * 64;                                                         \
    f32x4 sacc[4][2] = {};                                                             \
    _Pragma("unroll")                                                                  \
    for (int ks = 0; ks < 2; ++ks)                                                     \
      _Pragma("unroll")                                                                \
      for (int nf = 0; nf < 4; ++nf)                                                   \
        _Pragma("unroll")                                                              \
        for (int mf = 0; mf < 2; ++mf)                                                 \
          sacc[nf][mf] = __builtin_amdgcn_mfma_f32_16x16x32_bf16(                      \
              KCUR[ks][nf], aq[mf][ks], sacc[nf][mf], 0, 0, 0);                        \
    const int itn = ((IT) + 1 < nt) ? (IT) + 1 : (IT);                                 \
    _Pragma("unroll")                                                                  \
    for (int ks = 0; ks < 2; ++ks)                                                     \
      _Pragma("unroll")                                                                \
      for (int nf = 0; nf < 4; ++nf)                                                   \
        KNXT[ks][nf] = *reinterpret_cast<const bf16x8*>(                               \
            Kp + ((size_t)(itn * 2 + ks) * 4 + nf) * 512 + lofs);                      \
    bf16x8 vv[2][4];                                                                   \
    _Pragma("unroll")                                                                  \
    for (int k2 = 0; k2 < 2; ++k2)                                                     \
      _Pragma("unroll")                                                                \
      for (int dn = 0; dn < 4; ++dn)                                                   \
        vv[k2][dn] = *reinterpret_cast<const bf16x8*>(                                 \
            Vp + ((size_t)((IT) * 2 + k2) * 4 + dn) * 512 + lofs);                     \
    if ((IT) == nt - 1) {                                                              \
      _Pragma("unroll")                                                                \
      for (int mf = 0; mf < 2; ++mf) {                                                 \
        int qg = q0 + mf * 16 + l16;                                                   \
        _Pragma("unroll")                                                              \
        for (int nf = 0; nf < 4; ++nf)                                                 \
          _Pragma("unroll")                                                            \
          for (int r = 0; r < 4; ++r)                                                  \
            if (kv0 + nf * 16 + lq * 4 + r > qg) sacc[nf][mf][r] = -1e30f;             \
      }                                                                                \
    }                                                                                  \
    _Pragma("unroll")                                                                  \
    for (int mf = 0; mf < 2; ++mf) {                                                   \
      uint16_t* rowp = P + (mf * 16 + l16) * 72;                                       \
      _Pragma("unroll")                                                                \
      for (int nf = 0; nf < 4; ++nf) {                                                 \
        float p0 = __builtin_amdgcn_exp2f(sacc[nf][mf][0]);                            \
        float p1 = __builtin_amdgcn_exp2f(sacc[nf][mf][1]);                            \
        float p2 = __builtin_amdgcn_exp2f(sacc[nf][mf][2]);                            \
        float p3 = __builtin_amdgcn_exp2f(sacc[nf][mf][3]);                            \
        uint2 pk;                                                                      \
        pk.x = cvt_pk(p0, p1);                                                         \
        pk.y = cvt_pk(p2, p3);                                                         \
        *reinterpret_cast<uint2*>(rowp + nf * 16 + lq * 4) = pk;                       \
      }                                                                                \
    }                                                                                  \
    bf16x8 pa[2][2];                                                                   \
    _Pragma("unroll")                                                                  \
    for (int mf = 0; mf < 2; ++mf)                                                     \
      _Pragma("unroll")                                                                \
      for (int k2 = 0; k2 < 2; ++k2)                                                   \
        pa[mf][k2] = *reinterpret_cast<const bf16x8*>(                                 \
            P + (mf * 16 + l16) * 72 + k2 * 32 + lq * 8);                              \
    _Pragma("unroll")                                                                  \
    for (int k2 = 0; k2 < 2; ++k2)                                                     \
      _Pragma("unroll")                                                                \
      for (int mf = 0; mf < 2; ++mf) {                                                 \
        acc_l[mf] = __builtin_amdgcn_mfma_f32_16x16x32_bf16(ones, pa[mf][k2],          \
                                                            acc_l[mf], 0, 0, 0);      \
        _Pragma("unroll")                                                              \
        for (int dn = 0; dn < 4; ++dn)                                                 \
          acc[mf][dn] = __builtin_amdgcn_mfma_f32_16x16x32_bf16(                       \
              vv[k2][dn], pa[mf][k2], acc[mf][dn], 0, 0, 0);                           \
      }                                                                                \
  } while (0)

  {
    int it = 0;
    for (;;) {
      FLASH_STEP(kA, kB, it);
      ++it;
      if (it == nt) break;
      FLASH_STEP(kB, kA, it);
      ++it;
      if (it == nt) break;
    }
  }
#undef FLASH_STEP

#pragma unroll
  for (int mf = 0; mf < 2; ++mf) {
    float inv = 1.0f / acc_l[mf][0];
    uint16_t* rowp = P + (mf * 16 + l16) * 72;
#pragma unroll
    for (int dn = 0; dn < 4; ++dn) {
      uint2 pk;
      pk.x = cvt_pk(acc[mf][dn][0] * inv, acc[mf][dn][1] * inv);
      pk.y = cvt_pk(acc[mf][dn][2] * inv, acc[mf][dn][3] * inv);
      *reinterpret_cast<uint2*>(rowp + dn * 16 + lq * 4) = pk;
    }
  }
  {
    int orow = lane >> 1, ohalf = (lane & 1) * 32;
    uint16_t* op = ob + (size_t)(b * T_ + q0 + orow) * D_ + h * HD_ + ohalf;
    const uint16_t* lp = P + orow * 72 + ohalf;
#pragma unroll
    for (int j = 0; j < 4; ++j)
      *reinterpret_cast<uint4*>(op + j * 8) = *reinterpret_cast<const uint4*>(lp + j * 8);
  }
}

extern "C" void kernel_launch(void* const* d_in, const int* in_sizes, int n_in,
                              void* d_out, int out_size, void* d_ws, size_t ws_size,
                              hipStream_t stream) {
  const float* x  = (const float*)d_in[0];
  const float* Wq = (const float*)d_in[1];
  const float* bq = (const float*)d_in[2];
  const float* Wk = (const float*)d_in[3];
  const float* bk = (const float*)d_in[4];
  const float* Wv = (const float*)d_in[5];
  const float* bv = (const float*)d_in[6];
  const float* Wo = (const float*)d_in[7];
  const float* bo = (const float*)d_in[8];
  float* out = (float*)d_out;

  char* ws = (char*)d_ws;
  size_t off = 0;
  auto alloc = [&](size_t bytes) {
    void* p = ws + off;
    off += (bytes + 255) & ~(size_t)255;
    return p;
  };
  uint16_t* xb    = (uint16_t*)alloc((size_t)M_ * D_ * 2);
  uint16_t* wqkv  = (uint16_t*)alloc((size_t)NQKV_ * D_ * 2);
  uint16_t* wo_b  = (uint16_t*)alloc((size_t)D_ * D_ * 2);
  float*    bqkv  = (float*)alloc(NQKV_ * 4);
  float*    cosT  = (float*)alloc(T_ * 32 * 4);
  float*    sinT  = (float*)alloc(T_ * 32 * 4);
  uint16_t* q_bf  = (uint16_t*)alloc((size_t)B_ * H_ * T_ * HD_ * 2);
  uint16_t* k_bf  = (uint16_t*)alloc((size_t)B_ * KVH_ * T_ * HD_ * 2);
  uint16_t* vt_bf = (uint16_t*)alloc((size_t)B_ * KVH_ * T_ * HD_ * 2);
  float*    qkvf  = (float*)alloc((size_t)M_ * NQKV_ * 4);
  uint16_t* attn_bf = (uint16_t*)qkvf;  // reuse: QKV fp32 dead after rope/cvt_v

  cvt_bf16_k<<<4096, 256, 0, stream>>>(x, xb, M_ * D_);
  cvt_bf16_k<<<2048, 256, 0, stream>>>(Wq, wqkv, D_ * D_);
  cvt_bf16_k<<<512, 256, 0, stream>>>(Wk, wqkv + (size_t)D_ * D_, 512 * D_);
  cvt_bf16_k<<<512, 256, 0, stream>>>(Wv, wqkv + (size_t)2560 * D_, 512 * D_);
  cvt_bf16_k<<<2048, 256, 0, stream>>>(Wo, wo_b, D_ * D_);
  concat_bias_k<<<12, 256, 0, stream>>>(bq, bk, bv, bqkv);
  rope_tab_k<<<256, 256, 0, stream>>>(cosT, sinT);

  gemm256<<<dim3(NQKV_ / GBN, M_ / GBM), 512, 0, stream>>>(xb, wqkv, bqkv, qkvf, M_, NQKV_, D_);

  rope_qk_k<<<(B_ * 40 * T_ * 32) / 256, 256, 0, stream>>>(qkvf, cosT, sinT, q_bf, k_bf);
  cvt_v_k<<<(B_ * KVH_ * HD_ * (T_ / 8)) / 256, 256, 0, stream>>>(qkvf, vt_bf);

  flash_attn_k<<<1024, 256, 0, stream>>>(q_bf, k_bf, vt_bf, attn_bf);

  gemm256<<<dim3(D_ / GBN, M_ / GBM), 512, 0, stream>>>(attn_bf, wo_b, bo, out, M_, D_, D_);
}

// Round 16
// 206.036 us; speedup vs baseline: 1.1282x; 1.1267x over previous
//
#include <hip/hip_runtime.h>
#include <hip/hip_bf16.h>
#include <cstdint>

#define B_ 2
#define T_ 2048
#define D_ 2048
#define H_ 32
#define KVH_ 8
#define HD_ 64
#define NQKV_ 3072
#define M_ 4096

typedef __attribute__((ext_vector_type(8))) __bf16 bf16x8;
typedef __attribute__((ext_vector_type(4))) float f32x4;
typedef __attribute__((ext_vector_type(4))) uint32_t u32x4;

__device__ __forceinline__ uint16_t f2bf(float f) {
  uint32_t u = __builtin_bit_cast(uint32_t, f);
  return (uint16_t)((u + 0x7FFFu + ((u >> 16) & 1u)) >> 16);
}

__device__ __forceinline__ uint32_t cvt_pk(float lo, float hi) {
  uint32_t r;
  asm("v_cvt_pk_bf16_f32 %0, %1, %2" : "=v"(r) : "v"(lo), "v"(hi));
  return r;
}

__device__ __forceinline__ void gload_lds16(const void* g, void* l) {
  __builtin_amdgcn_global_load_lds(
      (const __attribute__((address_space(1))) void*)(uintptr_t)g,
      (__attribute__((address_space(3))) void*)(uintptr_t)l, 16, 0, 0);
}

// ---------------- fp32 -> bf16 convert (vectorized x8) ----------------
__global__ void cvt_bf16_k(const float* __restrict__ in, uint16_t* __restrict__ out, int n) {
  int i = (blockIdx.x * 256 + threadIdx.x) * 8;
  if (i >= n) return;
  float4 a = *reinterpret_cast<const float4*>(in + i);
  float4 b = *reinterpret_cast<const float4*>(in + i + 4);
  uint4 v;
  v.x = (uint32_t)f2bf(a.x) | ((uint32_t)f2bf(a.y) << 16);
  v.y = (uint32_t)f2bf(a.z) | ((uint32_t)f2bf(a.w) << 16);
  v.z = (uint32_t)f2bf(b.x) | ((uint32_t)f2bf(b.y) << 16);
  v.w = (uint32_t)f2bf(b.z) | ((uint32_t)f2bf(b.w) << 16);
  *reinterpret_cast<uint4*>(out + i) = v;
}

__global__ void concat_bias_k(const float* __restrict__ bq, const float* __restrict__ bk,
                              const float* __restrict__ bv, float* __restrict__ out) {
  int i = blockIdx.x * 256 + threadIdx.x;
  if (i >= NQKV_) return;
  out[i] = (i < D_) ? bq[i] : (i < D_ + 512) ? bk[i - D_] : bv[i - D_ - 512];
}

__global__ void rope_tab_k(float* __restrict__ cosT, float* __restrict__ sinT) {
  int i = blockIdx.x * 256 + threadIdx.x;  // 2048*32
  int d = i & 31;
  int t = i >> 5;
  float inv = expf(-(float)d * (1.0f / 32.0f) * logf(10000.0f));
  float f = (float)t * inv;
  cosT[i] = cosf(f);
  sinT[i] = sinf(f);
}

// ---------------- GEMM: C[m][n] = sum_k A[m][k]*Bw[n][k] + bias[n] ----------------
// Proven r11 128x128 structure (888 TF here). One change: launch_bounds(256,3)
// -> 3 blocks/CU (VGPR 60 measured, LDS 32KB: no spill risk) to fill the
// 2-barrier-per-K-step stall with a third resident block.
#define BM 128
#define BN 128
#define BK 64
__global__ __launch_bounds__(256, 3)
void gemm_bf16(const uint16_t* __restrict__ A, const uint16_t* __restrict__ Bw,
               const float* __restrict__ bias, float* __restrict__ C,
               int M, int N, int K) {
  __shared__ __align__(16) uint16_t As[BM * BK];
  __shared__ __align__(16) uint16_t Bs[BN * BK];
  const int tid = threadIdx.x;
  const int lane = tid & 63;
  const int w = tid >> 6;
  const int wm = w >> 1, wn = w & 1;
  const int l16 = lane & 15, lq = lane >> 4;

  int lin = blockIdx.y * gridDim.x + blockIdx.x;
  int qn = (gridDim.x * gridDim.y) >> 3;   // nwg % 8 == 0 for both calls
  int swz = (lin & 7) * qn + (lin >> 3);
  const int m0 = (swz / gridDim.x) * BM, n0 = (swz % gridDim.x) * BN;

  f32x4 acc[4][4] = {};

  for (int k0 = 0; k0 < K; k0 += BK) {
#pragma unroll
    for (int r = 0; r < 4; ++r) {
      int idx = r * 256 + tid;
      int row = idx >> 3;
      int c8 = (idx & 7) ^ (row & 7);
      gload_lds16(A + (size_t)(m0 + row) * K + k0 + c8 * 8, &As[idx * 8]);
    }
#pragma unroll
    for (int r = 0; r < 4; ++r) {
      int idx = r * 256 + tid;
      int row = idx >> 3;
      int c8 = (idx & 7) ^ (row & 7);
      gload_lds16(Bw + (size_t)(n0 + row) * K + k0 + c8 * 8, &Bs[idx * 8]);
    }
    __syncthreads();
#pragma unroll
    for (int ks = 0; ks < 2; ++ks) {
      bf16x8 av[4], bv[4];
      int k8 = ks * 4 + lq;
#pragma unroll
      for (int mi = 0; mi < 4; ++mi) {
        int row = wm * 64 + mi * 16 + l16;
        av[mi] = *reinterpret_cast<const bf16x8*>(&As[row * BK + ((k8 ^ (row & 7)) * 8)]);
      }
#pragma unroll
      for (int ni = 0; ni < 4; ++ni) {
        int row = wn * 64 + ni * 16 + l16;
        bv[ni] = *reinterpret_cast<const bf16x8*>(&Bs[row * BK + ((k8 ^ (row & 7)) * 8)]);
      }
#pragma unroll
      for (int mi = 0; mi < 4; ++mi)
#pragma unroll
        for (int ni = 0; ni < 4; ++ni)
          acc[mi][ni] = __builtin_amdgcn_mfma_f32_16x16x32_bf16(av[mi], bv[ni], acc[mi][ni], 0, 0, 0);
    }
    __syncthreads();
  }

#pragma unroll
  for (int mi = 0; mi < 4; ++mi) {
    int r0 = m0 + wm * 64 + mi * 16 + lq * 4;
#pragma unroll
    for (int ni = 0; ni < 4; ++ni) {
      int c = n0 + wn * 64 + ni * 16 + l16;
      float bb = bias[c];
#pragma unroll
      for (int rr = 0; rr < 4; ++rr)
        C[(size_t)(r0 + rr) * N + c] = acc[mi][ni][rr] + bb;
    }
  }
}

// ---------------- RoPE on Q,K + pack to FRAGMENT-MAJOR bf16 layouts ----------------
// Fragment-major: each 16x32 MFMA fragment's 64 lanes x 16B stored contiguously
// (1KB/fragment) so the flash kernel's fragment loads are single coalesced
// transactions. Q frag id (per b,h): (tile*2+ks)*2+mf; K frag id (per b,kvh):
// (it*2+ks)*4+nf. Lane = lq*16+l16, element offset = lane*8+e (uint16).
// Q is pre-scaled by 0.125*log2(e) (exp2-domain softmax fold).
__global__ void rope_qk_k(const float* __restrict__ QKV, const float* __restrict__ cosT,
                          const float* __restrict__ sinT, uint16_t* __restrict__ qb,
                          uint16_t* __restrict__ kb) {
  int tid = blockIdx.x * 256 + threadIdx.x;  // B*40*T*32
  int d = tid & 31;                           // rope pair index: (d, d+32)
  int t = (tid >> 5) & (T_ - 1);
  int rest = tid >> 16;
  int hh = rest % 40;
  int b = rest / 40;
  const float PREQ = 0.125f * 1.44269504f;
  float c = cosT[t * 32 + d];
  float s = sinT[t * 32 + d];
  size_t rowoff = (size_t)(b * T_ + t) * NQKV_;
  const int lq = d >> 3, e = d & 7;
  const int l16 = t & 15;
  const int lofs = (lq * 16 + l16) * 8 + e;
  if (hh < H_) {
    const float* q = QKV + rowoff + hh * 64;
    float x1 = q[d], x2 = q[d + 32];
    int tile = t >> 5, mf = (t >> 4) & 1;
    size_t base = ((size_t)(b * H_ + hh) * 64 + tile) * 2048;
    qb[base + (0 * 2 + mf) * 512 + lofs] = f2bf((x1 * c - x2 * s) * PREQ);  // ks=0
    qb[base + (1 * 2 + mf) * 512 + lofs] = f2bf((x2 * c + x1 * s) * PREQ);  // ks=1
  } else {
    int kh = hh - H_;
    const float* kp = QKV + rowoff + D_ + kh * 64;
    float x1 = kp[d], x2 = kp[d + 32];
    int it = t >> 6, nf = (t >> 4) & 3;
    size_t base = (size_t)(b * KVH_ + kh) * (T_ * HD_) + (size_t)it * 4096;
    kb[base + (0 * 8 + nf) * 512 + lofs] = f2bf(x1 * c - x2 * s);           // ks=0
    kb[base + (4 + nf) * 512 + lofs] = f2bf(x2 * c + x1 * s);               // ks=1
  }
}

// ---------------- V -> fragment-major bf16 (PV A-operand order) ----------------
// V frag id (per b,kvh): (it*2+k2)*4+dn; lane(l16=d&15, lq=(t>>3)&3), e=t&7.
__global__ void cvt_v_k(const float* __restrict__ QKV, uint16_t* __restrict__ vt) {
  int tid = blockIdx.x * 256 + threadIdx.x;
  int t8 = tid & 255;
  int rest = tid >> 8;
  int b = rest >> 9;
  int col = 2560 + (rest & 511);
  int d = rest & 63;
  int kvh = (rest >> 6) & 7;
  uint16_t tmp[8];
#pragma unroll
  for (int i = 0; i < 8; ++i)
    tmp[i] = f2bf(QKV[(size_t)(b * T_ + t8 * 8 + i) * NQKV_ + col]);
  uint4 v;
  v.x = (uint32_t)tmp[0] | ((uint32_t)tmp[1] << 16);
  v.y = (uint32_t)tmp[2] | ((uint32_t)tmp[3] << 16);
  v.z = (uint32_t)tmp[4] | ((uint32_t)tmp[5] << 16);
  v.w = (uint32_t)tmp[6] | ((uint32_t)tmp[7] << 16);
  int it = t8 >> 3, k2 = (t8 >> 2) & 1, lq = t8 & 3;
  int dn = d >> 4, l16 = d & 15;
  size_t base = (size_t)(b * KVH_ + kvh) * (T_ * HD_);
  *reinterpret_cast<uint4*>(vt + base + ((size_t)(it * 2 + k2) * 4 + dn) * 512 +
                            (lq * 16 + l16) * 8) = v;
}

// ---------------- flash attention (causal, GQA), swapped QK^T ----------------
// Fragment-major Q/K/V loads (single coalesced 1KB transaction per fragment),
// no row-max (exp2 unnormalized, O = PV/l cancels scale), l via ones-MFMA,
// K register double-buffer. Proven r11 structure.
__global__ __launch_bounds__(256, 2)
void flash_attn_k(const uint16_t* __restrict__ qb, const uint16_t* __restrict__ kb,
                  const uint16_t* __restrict__ vt, uint16_t* __restrict__ ob) {
  __shared__ __align__(16) uint16_t P_lds[4][32 * 72];  // per-wave 32 q x 64+pad
  const int lane = threadIdx.x & 63;
  const int w = threadIdx.x >> 6;
  const int l16 = lane & 15, lq = lane >> 4;
  const int bh = (blockIdx.x & 15) * 4 + w;
  const int rank = blockIdx.x >> 4;              // 0..63
  const int pair = rank & 31;
  const int tile = (rank & 32) ? (63 - pair) : pair;
  const int b = bh >> 5, h = bh & 31;
  const int kvh = h >> 2;
  uint16_t* P = P_lds[w];

  const uint16_t* Qp = qb + ((size_t)(b * H_ + h) * 64 + tile) * 2048;
  const uint16_t* Kp = kb + (size_t)(b * KVH_ + kvh) * (T_ * HD_);
  const uint16_t* Vp = vt + (size_t)(b * KVH_ + kvh) * (T_ * HD_);
  const int lofs = lane * 8;

  const int q0 = tile * 32;
  u32x4 ones_u = {0x3F803F80u, 0x3F803F80u, 0x3F803F80u, 0x3F803F80u};
  bf16x8 ones = __builtin_bit_cast(bf16x8, ones_u);

  bf16x8 aq[2][2];
#pragma unroll
  for (int mf = 0; mf < 2; ++mf)
#pragma unroll
    for (int ks = 0; ks < 2; ++ks)
      aq[mf][ks] = *reinterpret_cast<const bf16x8*>(Qp + (ks * 2 + mf) * 512 + lofs);

  f32x4 acc[2][4] = {};
  f32x4 acc_l[2] = {};

  const int nt = (tile >> 1) + 1;

  bf16x8 kA[2][4], kB[2][4];
#pragma unroll
  for (int ks = 0; ks < 2; ++ks)
#pragma unroll
    for (int nf = 0; nf < 4; ++nf)
      kA[ks][nf] = *reinterpret_cast<const bf16x8*>(Kp + (ks * 4 + nf) * 512 + lofs);

#define FLASH_STEP(KCUR, KNXT, IT)                                                     \
  do {                                                                                 \
    const int kv0 = (IT) * 64;                                                         \
    f32x4 sacc[4][2] = {};                                                             \
    _Pragma("unroll")                                                                  \
    for (int ks = 0; ks < 2; ++ks)                                                     \
      _Pragma("unroll")                                                                \
      for (int nf = 0; nf < 4; ++nf)                                                   \
        _Pragma("unroll")                                                              \
        for (int mf = 0; mf < 2; ++mf)                                                 \
          sacc[nf][mf] = __builtin_amdgcn_mfma_f32_16x16x32_bf16(                      \
              KCUR[ks][nf], aq[mf][ks], sacc[nf][mf], 0, 0, 0);                        \
    const int itn = ((IT) + 1 < nt) ? (IT) + 1 : (IT);                                 \
    _Pragma("unroll")                                                                  \
    for (int ks = 0; ks < 2; ++ks)                                                     \
      _Pragma("unroll")                                                                \
      for (int nf = 0; nf < 4; ++nf)                                                   \
        KNXT[ks][nf] = *reinterpret_cast<const bf16x8*>(                               \
            Kp + ((size_t)(itn * 2 + ks) * 4 + nf) * 512 + lofs);                      \
    bf16x8 vv[2][4];                                                                   \
    _Pragma("unroll")                                                                  \
    for (int k2 = 0; k2 < 2; ++k2)                                                     \
      _Pragma("unroll")                                                                \
      for (int dn = 0; dn < 4; ++dn)                                                   \
        vv[k2][dn] = *reinterpret_cast<const bf16x8*>(                                 \
            Vp + ((size_t)((IT) * 2 + k2) * 4 + dn) * 512 + lofs);                     \
    if ((IT) == nt - 1) {                                                              \
      _Pragma("unroll")                                                                \
      for (int mf = 0; mf < 2; ++mf) {                                                 \
        int qg = q0 + mf * 16 + l16;                                                   \
        _Pragma("unroll")                                                              \
        for (int nf = 0; nf < 4; ++nf)                                                 \
          _Pragma("unroll")                                                            \
          for (int r = 0; r < 4; ++r)                                                  \
            if (kv0 + nf * 16 + lq * 4 + r > qg) sacc[nf][mf][r] = -1e30f;             \
      }                                                                                \
    }                                                                                  \
    _Pragma("unroll")                                                                  \
    for (int mf = 0; mf < 2; ++mf) {                                                   \
      uint16_t* rowp = P + (mf * 16 + l16) * 72;                                       \
      _Pragma("unroll")                                                                \
      for (int nf = 0; nf < 4; ++nf) {                                                 \
        float p0 = __builtin_amdgcn_exp2f(sacc[nf][mf][0]);                            \
        float p1 = __builtin_amdgcn_exp2f(sacc[nf][mf][1]);                            \
        float p2 = __builtin_amdgcn_exp2f(sacc[nf][mf][2]);                            \
        float p3 = __builtin_amdgcn_exp2f(sacc[nf][mf][3]);                            \
        uint2 pk;                                                                      \
        pk.x = cvt_pk(p0, p1);                                                         \
        pk.y = cvt_pk(p2, p3);                                                         \
        *reinterpret_cast<uint2*>(rowp + nf * 16 + lq * 4) = pk;                       \
      }                                                                                \
    }                                                                                  \
    bf16x8 pa[2][2];                                                                   \
    _Pragma("unroll")                                                                  \
    for (int mf = 0; mf < 2; ++mf)                                                     \
      _Pragma("unroll")                                                                \
      for (int k2 = 0; k2 < 2; ++k2)                                                   \
        pa[mf][k2] = *reinterpret_cast<const bf16x8*>(                                 \
            P + (mf * 16 + l16) * 72 + k2 * 32 + lq * 8);                              \
    _Pragma("unroll")                                                                  \
    for (int k2 = 0; k2 < 2; ++k2)                                                     \
      _Pragma("unroll")                                                                \
      for (int mf = 0; mf < 2; ++mf) {                                                 \
        acc_l[mf] = __builtin_amdgcn_mfma_f32_16x16x32_bf16(ones, pa[mf][k2],          \
                                                            acc_l[mf], 0, 0, 0);      \
        _Pragma("unroll")                                                              \
        for (int dn = 0; dn < 4; ++dn)                                                 \
          acc[mf][dn] = __builtin_amdgcn_mfma_f32_16x16x32_bf16(                       \
              vv[k2][dn], pa[mf][k2], acc[mf][dn], 0, 0, 0);                           \
      }                                                                                \
  } while (0)

  {
    int it = 0;
    for (;;) {
      FLASH_STEP(kA, kB, it);
      ++it;
      if (it == nt) break;
      FLASH_STEP(kB, kA, it);
      ++it;
      if (it == nt) break;
    }
  }
#undef FLASH_STEP

#pragma unroll
  for (int mf = 0; mf < 2; ++mf) {
    float inv = 1.0f / acc_l[mf][0];
    uint16_t* rowp = P + (mf * 16 + l16) * 72;
#pragma unroll
    for (int dn = 0; dn < 4; ++dn) {
      uint2 pk;
      pk.x = cvt_pk(acc[mf][dn][0] * inv, acc[mf][dn][1] * inv);
      pk.y = cvt_pk(acc[mf][dn][2] * inv, acc[mf][dn][3] * inv);
      *reinterpret_cast<uint2*>(rowp + dn * 16 + lq * 4) = pk;
    }
  }
  {
    int orow = lane >> 1, ohalf = (lane & 1) * 32;
    uint16_t* op = ob + (size_t)(b * T_ + q0 + orow) * D_ + h * HD_ + ohalf;
    const uint16_t* lp = P + orow * 72 + ohalf;
#pragma unroll
    for (int j = 0; j < 4; ++j)
      *reinterpret_cast<uint4*>(op + j * 8) = *reinterpret_cast<const uint4*>(lp + j * 8);
  }
}

extern "C" void kernel_launch(void* const* d_in, const int* in_sizes, int n_in,
                              void* d_out, int out_size, void* d_ws, size_t ws_size,
                              hipStream_t stream) {
  const float* x  = (const float*)d_in[0];
  const float* Wq = (const float*)d_in[1];
  const float* bq = (const float*)d_in[2];
  const float* Wk = (const float*)d_in[3];
  const float* bk = (const float*)d_in[4];
  const float* Wv = (const float*)d_in[5];
  const float* bv = (const float*)d_in[6];
  const float* Wo = (const float*)d_in[7];
  const float* bo = (const float*)d_in[8];
  float* out = (float*)d_out;

  char* ws = (char*)d_ws;
  size_t off = 0;
  auto alloc = [&](size_t bytes) {
    void* p = ws + off;
    off += (bytes + 255) & ~(size_t)255;
    return p;
  };
  uint16_t* xb    = (uint16_t*)alloc((size_t)M_ * D_ * 2);
  uint16_t* wqkv  = (uint16_t*)alloc((size_t)NQKV_ * D_ * 2);
  uint16_t* wo_b  = (uint16_t*)alloc((size_t)D_ * D_ * 2);
  float*    bqkv  = (float*)alloc(NQKV_ * 4);
  float*    cosT  = (float*)alloc(T_ * 32 * 4);
  float*    sinT  = (float*)alloc(T_ * 32 * 4);
  uint16_t* q_bf  = (uint16_t*)alloc((size_t)B_ * H_ * T_ * HD_ * 2);
  uint16_t* k_bf  = (uint16_t*)alloc((size_t)B_ * KVH_ * T_ * HD_ * 2);
  uint16_t* vt_bf = (uint16_t*)alloc((size_t)B_ * KVH_ * T_ * HD_ * 2);
  float*    qkvf  = (float*)alloc((size_t)M_ * NQKV_ * 4);
  uint16_t* attn_bf = (uint16_t*)qkvf;  // reuse: QKV fp32 dead after rope/cvt_v

  cvt_bf16_k<<<4096, 256, 0, stream>>>(x, xb, M_ * D_);
  cvt_bf16_k<<<2048, 256, 0, stream>>>(Wq, wqkv, D_ * D_);
  cvt_bf16_k<<<512, 256, 0, stream>>>(Wk, wqkv + (size_t)D_ * D_, 512 * D_);
  cvt_bf16_k<<<512, 256, 0, stream>>>(Wv, wqkv + (size_t)2560 * D_, 512 * D_);
  cvt_bf16_k<<<2048, 256, 0, stream>>>(Wo, wo_b, D_ * D_);
  concat_bias_k<<<12, 256, 0, stream>>>(bq, bk, bv, bqkv);
  rope_tab_k<<<256, 256, 0, stream>>>(cosT, sinT);

  gemm_bf16<<<dim3(NQKV_ / BN, M_ / BM), 256, 0, stream>>>(xb, wqkv, bqkv, qkvf, M_, NQKV_, D_);

  rope_qk_k<<<(B_ * 40 * T_ * 32) / 256, 256, 0, stream>>>(qkvf, cosT, sinT, q_bf, k_bf);
  cvt_v_k<<<(B_ * KVH_ * HD_ * (T_ / 8)) / 256, 256, 0, stream>>>(qkvf, vt_bf);

  flash_attn_k<<<1024, 256, 0, stream>>>(q_bf, k_bf, vt_bf, attn_bf);

  gemm_bf16<<<dim3(D_ / BN, M_ / BM), 256, 0, stream>>>(attn_bf, wo_b, bo, out, M_, D_, D_);
}

// Round 17
// 188.987 us; speedup vs baseline: 1.2300x; 1.0902x over previous
//
#include <hip/hip_runtime.h>
#include <hip/hip_bf16.h>
#include <cstdint>

#define B_ 2
#define T_ 2048
#define D_ 2048
#define H_ 32
#define KVH_ 8
#define HD_ 64
#define NQKV_ 3072
#define M_ 4096

typedef __attribute__((ext_vector_type(8))) __bf16 bf16x8;
typedef __attribute__((ext_vector_type(4))) float f32x4;
typedef __attribute__((ext_vector_type(4))) uint32_t u32x4;

__device__ __forceinline__ uint16_t f2bf(float f) {
  uint32_t u = __builtin_bit_cast(uint32_t, f);
  return (uint16_t)((u + 0x7FFFu + ((u >> 16) & 1u)) >> 16);
}

__device__ __forceinline__ float bf2f(uint16_t u) {
  return __builtin_bit_cast(float, (uint32_t)u << 16);
}

__device__ __forceinline__ uint32_t cvt_pk(float lo, float hi) {
  uint32_t r;
  asm("v_cvt_pk_bf16_f32 %0, %1, %2" : "=v"(r) : "v"(lo), "v"(hi));
  return r;
}

__device__ __forceinline__ void gload_lds16(const void* g, void* l) {
  __builtin_amdgcn_global_load_lds(
      (const __attribute__((address_space(1))) void*)(uintptr_t)g,
      (__attribute__((address_space(3))) void*)(uintptr_t)l, 16, 0, 0);
}

// ---------------- fp32 -> bf16 convert (vectorized x8) ----------------
__global__ void cvt_bf16_k(const float* __restrict__ in, uint16_t* __restrict__ out, int n) {
  int i = (blockIdx.x * 256 + threadIdx.x) * 8;
  if (i >= n) return;
  float4 a = *reinterpret_cast<const float4*>(in + i);
  float4 b = *reinterpret_cast<const float4*>(in + i + 4);
  uint4 v;
  v.x = (uint32_t)f2bf(a.x) | ((uint32_t)f2bf(a.y) << 16);
  v.y = (uint32_t)f2bf(a.z) | ((uint32_t)f2bf(a.w) << 16);
  v.z = (uint32_t)f2bf(b.x) | ((uint32_t)f2bf(b.y) << 16);
  v.w = (uint32_t)f2bf(b.z) | ((uint32_t)f2bf(b.w) << 16);
  *reinterpret_cast<uint4*>(out + i) = v;
}

__global__ void concat_bias_k(const float* __restrict__ bq, const float* __restrict__ bk,
                              const float* __restrict__ bv, float* __restrict__ out) {
  int i = blockIdx.x * 256 + threadIdx.x;
  if (i >= NQKV_) return;
  out[i] = (i < D_) ? bq[i] : (i < D_ + 512) ? bk[i - D_] : bv[i - D_ - 512];
}

__global__ void rope_tab_k(float* __restrict__ cosT, float* __restrict__ sinT) {
  int i = blockIdx.x * 256 + threadIdx.x;  // 2048*32
  int d = i & 31;
  int t = i >> 5;
  float inv = expf(-(float)d * (1.0f / 32.0f) * logf(10000.0f));
  float f = (float)t * inv;
  cosT[i] = cosf(f);
  sinT[i] = sinf(f);
}

// ---------------- GEMM: C[m][n] = sum_k A[m][k]*Bw[n][k] + bias[n] ----------------
// Proven r11 128x128 structure (~888 TF here). OUTBF16: write bf16 (QKV GEMM)
// to halve the intermediate's write+read traffic; else fp32 (O-proj -> d_out).
#define BM 128
#define BN 128
#define BK 64
template <bool OUTBF16>
__global__ __launch_bounds__(256, 3)
void gemm_bf16(const uint16_t* __restrict__ A, const uint16_t* __restrict__ Bw,
               const float* __restrict__ bias, void* __restrict__ Cv,
               int M, int N, int K) {
  __shared__ __align__(16) uint16_t As[BM * BK];
  __shared__ __align__(16) uint16_t Bs[BN * BK];
  const int tid = threadIdx.x;
  const int lane = tid & 63;
  const int w = tid >> 6;
  const int wm = w >> 1, wn = w & 1;
  const int l16 = lane & 15, lq = lane >> 4;

  int lin = blockIdx.y * gridDim.x + blockIdx.x;
  int qn = (gridDim.x * gridDim.y) >> 3;   // nwg % 8 == 0 for both calls
  int swz = (lin & 7) * qn + (lin >> 3);
  const int m0 = (swz / gridDim.x) * BM, n0 = (swz % gridDim.x) * BN;

  f32x4 acc[4][4] = {};

  for (int k0 = 0; k0 < K; k0 += BK) {
#pragma unroll
    for (int r = 0; r < 4; ++r) {
      int idx = r * 256 + tid;
      int row = idx >> 3;
      int c8 = (idx & 7) ^ (row & 7);
      gload_lds16(A + (size_t)(m0 + row) * K + k0 + c8 * 8, &As[idx * 8]);
    }
#pragma unroll
    for (int r = 0; r < 4; ++r) {
      int idx = r * 256 + tid;
      int row = idx >> 3;
      int c8 = (idx & 7) ^ (row & 7);
      gload_lds16(Bw + (size_t)(n0 + row) * K + k0 + c8 * 8, &Bs[idx * 8]);
    }
    __syncthreads();
#pragma unroll
    for (int ks = 0; ks < 2; ++ks) {
      bf16x8 av[4], bv[4];
      int k8 = ks * 4 + lq;
#pragma unroll
      for (int mi = 0; mi < 4; ++mi) {
        int row = wm * 64 + mi * 16 + l16;
        av[mi] = *reinterpret_cast<const bf16x8*>(&As[row * BK + ((k8 ^ (row & 7)) * 8)]);
      }
#pragma unroll
      for (int ni = 0; ni < 4; ++ni) {
        int row = wn * 64 + ni * 16 + l16;
        bv[ni] = *reinterpret_cast<const bf16x8*>(&Bs[row * BK + ((k8 ^ (row & 7)) * 8)]);
      }
#pragma unroll
      for (int mi = 0; mi < 4; ++mi)
#pragma unroll
        for (int ni = 0; ni < 4; ++ni)
          acc[mi][ni] = __builtin_amdgcn_mfma_f32_16x16x32_bf16(av[mi], bv[ni], acc[mi][ni], 0, 0, 0);
    }
    __syncthreads();
  }

#pragma unroll
  for (int mi = 0; mi < 4; ++mi) {
    int r0 = m0 + wm * 64 + mi * 16 + lq * 4;
#pragma unroll
    for (int ni = 0; ni < 4; ++ni) {
      int c = n0 + wn * 64 + ni * 16 + l16;
      float bb = bias[c];
#pragma unroll
      for (int rr = 0; rr < 4; ++rr) {
        float v = acc[mi][ni][rr] + bb;
        if constexpr (OUTBF16)
          ((uint16_t*)Cv)[(size_t)(r0 + rr) * N + c] = f2bf(v);
        else
          ((float*)Cv)[(size_t)(r0 + rr) * N + c] = v;
      }
    }
  }
}

// ---------------- RoPE on Q,K (bf16 in) + pack to FRAGMENT-MAJOR bf16 ----------------
// Fragment-major: each 16x32 MFMA fragment's 64 lanes x 16B stored contiguously
// (1KB/fragment). Q frag id (per b,h): (tile*2+ks)*2+mf; K frag id (per b,kvh):
// (it*2+ks)*4+nf. Lane = lq*16+l16, element offset = lane*8+e (uint16).
// Q is pre-scaled by 0.125*log2(e) (exp2-domain softmax fold).
__global__ void rope_qk_k(const uint16_t* __restrict__ QKV, const float* __restrict__ cosT,
                          const float* __restrict__ sinT, uint16_t* __restrict__ qb,
                          uint16_t* __restrict__ kb) {
  int tid = blockIdx.x * 256 + threadIdx.x;  // B*40*T*32
  int d = tid & 31;                           // rope pair index: (d, d+32)
  int t = (tid >> 5) & (T_ - 1);
  int rest = tid >> 16;
  int hh = rest % 40;
  int b = rest / 40;
  const float PREQ = 0.125f * 1.44269504f;
  float c = cosT[t * 32 + d];
  float s = sinT[t * 32 + d];
  size_t rowoff = (size_t)(b * T_ + t) * NQKV_;
  const int lq = d >> 3, e = d & 7;
  const int l16 = t & 15;
  const int lofs = (lq * 16 + l16) * 8 + e;
  if (hh < H_) {
    const uint16_t* q = QKV + rowoff + hh * 64;
    float x1 = bf2f(q[d]), x2 = bf2f(q[d + 32]);
    int tile = t >> 5, mf = (t >> 4) & 1;
    size_t base = ((size_t)(b * H_ + hh) * 64 + tile) * 2048;
    qb[base + (0 * 2 + mf) * 512 + lofs] = f2bf((x1 * c - x2 * s) * PREQ);  // ks=0
    qb[base + (1 * 2 + mf) * 512 + lofs] = f2bf((x2 * c + x1 * s) * PREQ);  // ks=1
  } else {
    int kh = hh - H_;
    const uint16_t* kp = QKV + rowoff + D_ + kh * 64;
    float x1 = bf2f(kp[d]), x2 = bf2f(kp[d + 32]);
    int it = t >> 6, nf = (t >> 4) & 3;
    size_t base = (size_t)(b * KVH_ + kh) * (T_ * HD_) + (size_t)it * 4096;
    kb[base + (0 * 8 + nf) * 512 + lofs] = f2bf(x1 * c - x2 * s);           // ks=0
    kb[base + (4 + nf) * 512 + lofs] = f2bf(x2 * c + x1 * s);               // ks=1
  }
}

// ---------------- V -> fragment-major bf16 via LDS transpose ----------------
// Block = one 64t x 64d V tile. Reads fully row-coalesced (uint4), transposes
// through [64][72] LDS (2-way conflicts only), writes fragment-major uint4.
// Replaces the old column-gather (12KB-stride, ~16x cache-line overfetch).
__global__ void cvt_v_k(const uint16_t* __restrict__ QKV, uint16_t* __restrict__ vt) {
  __shared__ uint16_t tile[64][72];
  int blk = blockIdx.x;              // b*256 + kvh*32 + it
  int it = blk & 31;
  int kvh = (blk >> 5) & 7;
  int b = blk >> 8;
  int tid = threadIdx.x;
  int t0 = it * 64;

  {  // read: thread = (row r, 16-col group)
    int r = tid >> 2;
    int cg = (tid & 3) * 16;
    const uint16_t* src = QKV + (size_t)(b * T_ + t0 + r) * NQKV_ + 2560 + kvh * 64 + cg;
    uint4 v0 = *reinterpret_cast<const uint4*>(src);
    uint4 v1 = *reinterpret_cast<const uint4*>(src + 8);
    *reinterpret_cast<uint4*>(&tile[r][cg]) = v0;
    *reinterpret_cast<uint4*>(&tile[r][cg + 8]) = v1;
  }
  __syncthreads();

  // write: thread = (d = tid&63, two t-octets); frag id (it*2+k2)*4+dn,
  // lane(l16 = d&15, lq = (t>>3)&3), elem e = t&7.
  int d = tid & 63;
  int wv = tid >> 6;  // 0..3
  int dn = d >> 4, l16 = d & 15;
  size_t base = (size_t)(b * KVH_ + kvh) * (T_ * HD_);
#pragma unroll
  for (int j = 0; j < 2; ++j) {
    int oct = wv * 2 + j;            // t_local = oct*8 .. +7
    int k2 = oct >> 2, lq = oct & 3;
    uint16_t tmp[8];
#pragma unroll
    for (int e = 0; e < 8; ++e) tmp[e] = tile[oct * 8 + e][d];
    uint4 v;
    v.x = (uint32_t)tmp[0] | ((uint32_t)tmp[1] << 16);
    v.y = (uint32_t)tmp[2] | ((uint32_t)tmp[3] << 16);
    v.z = (uint32_t)tmp[4] | ((uint32_t)tmp[5] << 16);
    v.w = (uint32_t)tmp[6] | ((uint32_t)tmp[7] << 16);
    *reinterpret_cast<uint4*>(vt + base + ((size_t)(it * 2 + k2) * 4 + dn) * 512 +
                              (lq * 16 + l16) * 8) = v;
  }
}

// ---------------- flash attention (causal, GQA), swapped QK^T ----------------
// Fragment-major Q/K/V loads (single coalesced 1KB transaction per fragment),
// no row-max (exp2 unnormalized, O = PV/l cancels scale), l via ones-MFMA,
// K register double-buffer. Proven r11 structure.
__global__ __launch_bounds__(256, 2)
void flash_attn_k(const uint16_t* __restrict__ qb, const uint16_t* __restrict__ kb,
                  const uint16_t* __restrict__ vt, uint16_t* __restrict__ ob) {
  __shared__ __align__(16) uint16_t P_lds[4][32 * 72];  // per-wave 32 q x 64+pad
  const int lane = threadIdx.x & 63;
  const int w = threadIdx.x >> 6;
  const int l16 = lane & 15, lq = lane >> 4;
  const int bh = (blockIdx.x & 15) * 4 + w;
  const int rank = blockIdx.x >> 4;              // 0..63
  const int pair = rank & 31;
  const int tile = (rank & 32) ? (63 - pair) : pair;
  const int b = bh >> 5, h = bh & 31;
  const int kvh = h >> 2;
  uint16_t* P = P_lds[w];

  const uint16_t* Qp = qb + ((size_t)(b * H_ + h) * 64 + tile) * 2048;
  const uint16_t* Kp = kb + (size_t)(b * KVH_ + kvh) * (T_ * HD_);
  const uint16_t* Vp = vt + (size_t)(b * KVH_ + kvh) * (T_ * HD_);
  const int lofs = lane * 8;

  const int q0 = tile * 32;
  u32x4 ones_u = {0x3F803F80u, 0x3F803F80u, 0x3F803F80u, 0x3F803F80u};
  bf16x8 ones = __builtin_bit_cast(bf16x8, ones_u);

  bf16x8 aq[2][2];
#pragma unroll
  for (int mf = 0; mf < 2; ++mf)
#pragma unroll
    for (int ks = 0; ks < 2; ++ks)
      aq[mf][ks] = *reinterpret_cast<const bf16x8*>(Qp + (ks * 2 + mf) * 512 + lofs);

  f32x4 acc[2][4] = {};
  f32x4 acc_l[2] = {};

  const int nt = (tile >> 1) + 1;

  bf16x8 kA[2][4], kB[2][4];
#pragma unroll
  for (int ks = 0; ks < 2; ++ks)
#pragma unroll
    for (int nf = 0; nf < 4; ++nf)
      kA[ks][nf] = *reinterpret_cast<const bf16x8*>(Kp + (ks * 4 + nf) * 512 + lofs);

#define FLASH_STEP(KCUR, KNXT, IT)                                                     \
  do {                                                                                 \
    const int kv0 = (IT) * 64;                                                         \
    f32x4 sacc[4][2] = {};                                                             \
    _Pragma("unroll")                                                                  \
    for (int ks = 0; ks < 2; ++ks)                                                     \
      _Pragma("unroll")                                                                \
      for (int nf = 0; nf < 4; ++nf)                                                   \
        _Pragma("unroll")                                                              \
        for (int mf = 0; mf < 2; ++mf)                                                 \
          sacc[nf][mf] = __builtin_amdgcn_mfma_f32_16x16x32_bf16(                      \
              KCUR[ks][nf], aq[mf][ks], sacc[nf][mf], 0, 0, 0);                        \
    const int itn = ((IT) + 1 < nt) ? (IT) + 1 : (IT);                                 \
    _Pragma("unroll")                                                                  \
    for (int ks = 0; ks < 2; ++ks)                                                     \
      _Pragma("unroll")                                                                \
      for (int nf = 0; nf < 4; ++nf)                                                   \
        KNXT[ks][nf] = *reinterpret_cast<const bf16x8*>(                               \
            Kp + ((size_t)(itn * 2 + ks) * 4 + nf) * 512 + lofs);                      \
    bf16x8 vv[2][4];                                                                   \
    _Pragma("unroll")                                                                  \
    for (int k2 = 0; k2 < 2; ++k2)                                                     \
      _Pragma("unroll")                                                                \
      for (int dn = 0; dn < 4; ++dn)                                                   \
        vv[k2][dn] = *reinterpret_cast<const bf16x8*>(                                 \
            Vp + ((size_t)((IT) * 2 + k2) * 4 + dn) * 512 + lofs);                     \
    if ((IT) == nt - 1) {                                                              \
      _Pragma("unroll")                                                                \
      for (int mf = 0; mf < 2; ++mf) {                                                 \
        int qg = q0 + mf * 16 + l16;                                                   \
        _Pragma("unroll")                                                              \
        for (int nf = 0; nf < 4; ++nf)                                                 \
          _Pragma("unroll")                                                            \
          for (int r = 0; r < 4; ++r)                                                  \
            if (kv0 + nf * 16 + lq * 4 + r > qg) sacc[nf][mf][r] = -1e30f;             \
      }                                                                                \
    }                                                                                  \
    _Pragma("unroll")                                                                  \
    for (int mf = 0; mf < 2; ++mf) {                                                   \
      uint16_t* rowp = P + (mf * 16 + l16) * 72;                                       \
      _Pragma("unroll")                                                                \
      for (int nf = 0; nf < 4; ++nf) {                                                 \
        float p0 = __builtin_amdgcn_exp2f(sacc[nf][mf][0]);                            \
        float p1 = __builtin_amdgcn_exp2f(sacc[nf][mf][1]);                            \
        float p2 = __builtin_amdgcn_exp2f(sacc[nf][mf][2]);                            \
        float p3 = __builtin_amdgcn_exp2f(sacc[nf][mf][3]);                            \
        uint2 pk;                                                                      \
        pk.x = cvt_pk(p0, p1);                                                         \
        pk.y = cvt_pk(p2, p3);                                                         \
        *reinterpret_cast<uint2*>(rowp + nf * 16 + lq * 4) = pk;                       \
      }                                                                                \
    }                                                                                  \
    bf16x8 pa[2][2];                                                                   \
    _Pragma("unroll")                                                                  \
    for (int mf = 0; mf < 2; ++mf)                                                     \
      _Pragma("unroll")                                                                \
      for (int k2 = 0; k2 < 2; ++k2)                                                   \
        pa[mf][k2] = *reinterpret_cast<const bf16x8*>(                                 \
            P + (mf * 16 + l16) * 72 + k2 * 32 + lq * 8);                              \
    _Pragma("unroll")                                                                  \
    for (int k2 = 0; k2 < 2; ++k2)                                                     \
      _Pragma("unroll")                                                                \
      for (int mf = 0; mf < 2; ++mf) {                                                 \
        acc_l[mf] = __builtin_amdgcn_mfma_f32_16x16x32_bf16(ones, pa[mf][k2],          \
                                                            acc_l[mf], 0, 0, 0);      \
        _Pragma("unroll")                                                              \
        for (int dn = 0; dn < 4; ++dn)                                                 \
          acc[mf][dn] = __builtin_amdgcn_mfma_f32_16x16x32_bf16(                       \
              vv[k2][dn], pa[mf][k2], acc[mf][dn], 0, 0, 0);                           \
      }                                                                                \
  } while (0)

  {
    int it = 0;
    for (;;) {
      FLASH_STEP(kA, kB, it);
      ++it;
      if (it == nt) break;
      FLASH_STEP(kB, kA, it);
      ++it;
      if (it == nt) break;
    }
  }
#undef FLASH_STEP

#pragma unroll
  for (int mf = 0; mf < 2; ++mf) {
    float inv = 1.0f / acc_l[mf][0];
    uint16_t* rowp = P + (mf * 16 + l16) * 72;
#pragma unroll
    for (int dn = 0; dn < 4; ++dn) {
      uint2 pk;
      pk.x = cvt_pk(acc[mf][dn][0] * inv, acc[mf][dn][1] * inv);
      pk.y = cvt_pk(acc[mf][dn][2] * inv, acc[mf][dn][3] * inv);
      *reinterpret_cast<uint2*>(rowp + dn * 16 + lq * 4) = pk;
    }
  }
  {
    int orow = lane >> 1, ohalf = (lane & 1) * 32;
    uint16_t* op = ob + (size_t)(b * T_ + q0 + orow) * D_ + h * HD_ + ohalf;
    const uint16_t* lp = P + orow * 72 + ohalf;
#pragma unroll
    for (int j = 0; j < 4; ++j)
      *reinterpret_cast<uint4*>(op + j * 8) = *reinterpret_cast<const uint4*>(lp + j * 8);
  }
}

extern "C" void kernel_launch(void* const* d_in, const int* in_sizes, int n_in,
                              void* d_out, int out_size, void* d_ws, size_t ws_size,
                              hipStream_t stream) {
  const float* x  = (const float*)d_in[0];
  const float* Wq = (const float*)d_in[1];
  const float* bq = (const float*)d_in[2];
  const float* Wk = (const float*)d_in[3];
  const float* bk = (const float*)d_in[4];
  const float* Wv = (const float*)d_in[5];
  const float* bv = (const float*)d_in[6];
  const float* Wo = (const float*)d_in[7];
  const float* bo = (const float*)d_in[8];
  float* out = (float*)d_out;

  char* ws = (char*)d_ws;
  size_t off = 0;
  auto alloc = [&](size_t bytes) {
    void* p = ws + off;
    off += (bytes + 255) & ~(size_t)255;
    return p;
  };
  uint16_t* xb    = (uint16_t*)alloc((size_t)M_ * D_ * 2);
  uint16_t* wqkv  = (uint16_t*)alloc((size_t)NQKV_ * D_ * 2);
  uint16_t* wo_b  = (uint16_t*)alloc((size_t)D_ * D_ * 2);
  float*    bqkv  = (float*)alloc(NQKV_ * 4);
  float*    cosT  = (float*)alloc(T_ * 32 * 4);
  float*    sinT  = (float*)alloc(T_ * 32 * 4);
  uint16_t* q_bf  = (uint16_t*)alloc((size_t)B_ * H_ * T_ * HD_ * 2);
  uint16_t* k_bf  = (uint16_t*)alloc((size_t)B_ * KVH_ * T_ * HD_ * 2);
  uint16_t* vt_bf = (uint16_t*)alloc((size_t)B_ * KVH_ * T_ * HD_ * 2);
  uint16_t* qkv_bf = (uint16_t*)alloc((size_t)M_ * NQKV_ * 2);   // 25.2 MB bf16
  uint16_t* attn_bf = qkv_bf;  // reuse: qkv dead after rope/cvt_v (16.8 <= 25.2 MB)

  cvt_bf16_k<<<4096, 256, 0, stream>>>(x, xb, M_ * D_);
  cvt_bf16_k<<<2048, 256, 0, stream>>>(Wq, wqkv, D_ * D_);
  cvt_bf16_k<<<512, 256, 0, stream>>>(Wk, wqkv + (size_t)D_ * D_, 512 * D_);
  cvt_bf16_k<<<512, 256, 0, stream>>>(Wv, wqkv + (size_t)2560 * D_, 512 * D_);
  cvt_bf16_k<<<2048, 256, 0, stream>>>(Wo, wo_b, D_ * D_);
  concat_bias_k<<<12, 256, 0, stream>>>(bq, bk, bv, bqkv);
  rope_tab_k<<<256, 256, 0, stream>>>(cosT, sinT);

  gemm_bf16<true><<<dim3(NQKV_ / BN, M_ / BM), 256, 0, stream>>>(
      xb, wqkv, bqkv, qkv_bf, M_, NQKV_, D_);

  rope_qk_k<<<(B_ * 40 * T_ * 32) / 256, 256, 0, stream>>>(qkv_bf, cosT, sinT, q_bf, k_bf);
  cvt_v_k<<<B_ * KVH_ * (T_ / 64), 256, 0, stream>>>(qkv_bf, vt_bf);

  flash_attn_k<<<1024, 256, 0, stream>>>(q_bf, k_bf, vt_bf, attn_bf);

  gemm_bf16<false><<<dim3(D_ / BN, M_ / BM), 256, 0, stream>>>(
      attn_bf, wo_b, bo, out, M_, D_, D_);
}

// Round 18
// 179.704 us; speedup vs baseline: 1.2936x; 1.0517x over previous
//
#include <hip/hip_runtime.h>
#include <hip/hip_bf16.h>
#include <cstdint>

#define B_ 2
#define T_ 2048
#define D_ 2048
#define H_ 32
#define KVH_ 8
#define HD_ 64
#define NQKV_ 3072
#define M_ 4096

typedef __attribute__((ext_vector_type(8))) __bf16 bf16x8;
typedef __attribute__((ext_vector_type(4))) float f32x4;
typedef __attribute__((ext_vector_type(4))) uint32_t u32x4;

__device__ __forceinline__ uint16_t f2bf(float f) {
  uint32_t u = __builtin_bit_cast(uint32_t, f);
  return (uint16_t)((u + 0x7FFFu + ((u >> 16) & 1u)) >> 16);
}

__device__ __forceinline__ float bf2f(uint16_t u) {
  return __builtin_bit_cast(float, (uint32_t)u << 16);
}

__device__ __forceinline__ uint32_t cvt_pk(float lo, float hi) {
  uint32_t r;
  asm("v_cvt_pk_bf16_f32 %0, %1, %2" : "=v"(r) : "v"(lo), "v"(hi));
  return r;
}

__device__ __forceinline__ void gload_lds16(const void* g, void* l) {
  __builtin_amdgcn_global_load_lds(
      (const __attribute__((address_space(1))) void*)(uintptr_t)g,
      (__attribute__((address_space(3))) void*)(uintptr_t)l, 16, 0, 0);
}

// ---------------- fp32 -> bf16 convert (vectorized x8) ----------------
__global__ void cvt_bf16_k(const float* __restrict__ in, uint16_t* __restrict__ out, int n) {
  int i = (blockIdx.x * 256 + threadIdx.x) * 8;
  if (i >= n) return;
  float4 a = *reinterpret_cast<const float4*>(in + i);
  float4 b = *reinterpret_cast<const float4*>(in + i + 4);
  uint4 v;
  v.x = (uint32_t)f2bf(a.x) | ((uint32_t)f2bf(a.y) << 16);
  v.y = (uint32_t)f2bf(a.z) | ((uint32_t)f2bf(a.w) << 16);
  v.z = (uint32_t)f2bf(b.x) | ((uint32_t)f2bf(b.y) << 16);
  v.w = (uint32_t)f2bf(b.z) | ((uint32_t)f2bf(b.w) << 16);
  *reinterpret_cast<uint4*>(out + i) = v;
}

__global__ void concat_bias_k(const float* __restrict__ bq, const float* __restrict__ bk,
                              const float* __restrict__ bv, float* __restrict__ out) {
  int i = blockIdx.x * 256 + threadIdx.x;
  if (i >= NQKV_) return;
  out[i] = (i < D_) ? bq[i] : (i < D_ + 512) ? bk[i - D_] : bv[i - D_ - 512];
}

__global__ void rope_tab_k(float* __restrict__ cosT, float* __restrict__ sinT) {
  int i = blockIdx.x * 256 + threadIdx.x;  // 2048*32
  int d = i & 31;
  int t = i >> 5;
  float inv = expf(-(float)d * (1.0f / 32.0f) * logf(10000.0f));
  float f = (float)t * inv;
  cosT[i] = cosf(f);
  sinT[i] = sinf(f);
}

// ---------------- GEMM: C[m][n] = sum_k A[m][k]*Bw[n][k] + bias[n] ----------------
// Proven r11 128x128 structure (~920 TF here). MODE 0: fp32 C (O-proj).
// MODE 1: fused QKV epilogue -- each wave's 64-col span is exactly ONE head;
// the rope pair (d, d+32) is acc[mi][ni] / acc[mi][ni+2] of the SAME wave.
// Q -> rope*PREQ -> fragment-major qb; K -> rope -> fragment-major kb;
// V -> bias+bf16 -> compact vst [B][T][512]. Index math = old rope_qk_k.
#define BM 128
#define BN 128
#define BK 64
template <int MODE>
__global__ __launch_bounds__(256, 3)
void gemm_bf16(const uint16_t* __restrict__ A, const uint16_t* __restrict__ Bw,
               const float* __restrict__ bias, void* __restrict__ Cv,
               int M, int N, int K,
               const float* __restrict__ cosT, const float* __restrict__ sinT,
               uint16_t* __restrict__ qb, uint16_t* __restrict__ kb,
               uint16_t* __restrict__ vst) {
  __shared__ __align__(16) uint16_t As[BM * BK];
  __shared__ __align__(16) uint16_t Bs[BN * BK];
  const int tid = threadIdx.x;
  const int lane = tid & 63;
  const int w = tid >> 6;
  const int wm = w >> 1, wn = w & 1;
  const int l16 = lane & 15, lq = lane >> 4;

  int lin = blockIdx.y * gridDim.x + blockIdx.x;
  int qn = (gridDim.x * gridDim.y) >> 3;   // nwg % 8 == 0 for both calls
  int swz = (lin & 7) * qn + (lin >> 3);
  const int m0 = (swz / gridDim.x) * BM, n0 = (swz % gridDim.x) * BN;

  f32x4 acc[4][4] = {};

  for (int k0 = 0; k0 < K; k0 += BK) {
#pragma unroll
    for (int r = 0; r < 4; ++r) {
      int idx = r * 256 + tid;
      int row = idx >> 3;
      int c8 = (idx & 7) ^ (row & 7);
      gload_lds16(A + (size_t)(m0 + row) * K + k0 + c8 * 8, &As[idx * 8]);
    }
#pragma unroll
    for (int r = 0; r < 4; ++r) {
      int idx = r * 256 + tid;
      int row = idx >> 3;
      int c8 = (idx & 7) ^ (row & 7);
      gload_lds16(Bw + (size_t)(n0 + row) * K + k0 + c8 * 8, &Bs[idx * 8]);
    }
    __syncthreads();
#pragma unroll
    for (int ks = 0; ks < 2; ++ks) {
      bf16x8 av[4], bv[4];
      int k8 = ks * 4 + lq;
#pragma unroll
      for (int mi = 0; mi < 4; ++mi) {
        int row = wm * 64 + mi * 16 + l16;
        av[mi] = *reinterpret_cast<const bf16x8*>(&As[row * BK + ((k8 ^ (row & 7)) * 8)]);
      }
#pragma unroll
      for (int ni = 0; ni < 4; ++ni) {
        int row = wn * 64 + ni * 16 + l16;
        bv[ni] = *reinterpret_cast<const bf16x8*>(&Bs[row * BK + ((k8 ^ (row & 7)) * 8)]);
      }
#pragma unroll
      for (int mi = 0; mi < 4; ++mi)
#pragma unroll
        for (int ni = 0; ni < 4; ++ni)
          acc[mi][ni] = __builtin_amdgcn_mfma_f32_16x16x32_bf16(av[mi], bv[ni], acc[mi][ni], 0, 0, 0);
    }
    __syncthreads();
  }

  if constexpr (MODE == 0) {
#pragma unroll
    for (int mi = 0; mi < 4; ++mi) {
      int r0 = m0 + wm * 64 + mi * 16 + lq * 4;
#pragma unroll
      for (int ni = 0; ni < 4; ++ni) {
        int c = n0 + wn * 64 + ni * 16 + l16;
        float bb = bias[c];
#pragma unroll
        for (int rr = 0; rr < 4; ++rr)
          ((float*)Cv)[(size_t)(r0 + rr) * N + c] = acc[mi][ni][rr] + bb;
      }
    }
  } else {
    const int head = (n0 + wn * 64) >> 6;
    if (head < H_) {
      // Q: rope + PREQ prescale -> fragment-major (frag (ks*2+mf), per b,h,tile)
      const float PREQ = 0.125f * 1.44269504f;
#pragma unroll
      for (int mi = 0; mi < 4; ++mi) {
#pragma unroll
        for (int ni = 0; ni < 2; ++ni) {
          int d = ni * 16 + l16;
          int cg = head * 64 + d;
          float b1 = bias[cg], b2 = bias[cg + 32];
#pragma unroll
          for (int rr = 0; rr < 4; ++rr) {
            int t = m0 + wm * 64 + mi * 16 + lq * 4 + rr;
            int bb = t >> 11, tloc = t & 2047;
            float x1 = acc[mi][ni][rr] + b1;
            float x2 = acc[mi][ni + 2][rr] + b2;
            float cc = cosT[tloc * 32 + d], ss = sinT[tloc * 32 + d];
            int tile = tloc >> 5, mf = (tloc >> 4) & 1, l16f = tloc & 15;
            size_t base = ((size_t)(bb * H_ + head) * 64 + tile) * 2048;
            int lofs = ((d >> 3) * 16 + l16f) * 8 + (d & 7);
            qb[base + mf * 512 + lofs] = f2bf((x1 * cc - x2 * ss) * PREQ);       // ks=0
            qb[base + (2 + mf) * 512 + lofs] = f2bf((x2 * cc + x1 * ss) * PREQ); // ks=1
          }
        }
      }
    } else if (head < H_ + KVH_) {
      // K: rope -> fragment-major (frag (ks*4+nf), per b,kvh,it)
      int kh = head - H_;
#pragma unroll
      for (int mi = 0; mi < 4; ++mi) {
#pragma unroll
        for (int ni = 0; ni < 2; ++ni) {
          int d = ni * 16 + l16;
          int cg = head * 64 + d;
          float b1 = bias[cg], b2 = bias[cg + 32];
#pragma unroll
          for (int rr = 0; rr < 4; ++rr) {
            int t = m0 + wm * 64 + mi * 16 + lq * 4 + rr;
            int bb = t >> 11, tloc = t & 2047;
            float x1 = acc[mi][ni][rr] + b1;
            float x2 = acc[mi][ni + 2][rr] + b2;
            float cc = cosT[tloc * 32 + d], ss = sinT[tloc * 32 + d];
            int it = tloc >> 6, nf = (tloc >> 4) & 3, l16f = tloc & 15;
            size_t base = (size_t)(bb * KVH_ + kh) * (T_ * HD_) + (size_t)it * 4096;
            int lofs = ((d >> 3) * 16 + l16f) * 8 + (d & 7);
            kb[base + nf * 512 + lofs] = f2bf(x1 * cc - x2 * ss);         // ks=0
            kb[base + (4 + nf) * 512 + lofs] = f2bf(x2 * cc + x1 * ss);   // ks=1
          }
        }
      }
    } else {
      // V: bias + bf16 -> compact [B][T][512] staging (cvt_v transposes)
      int vh = head - H_ - KVH_;
#pragma unroll
      for (int mi = 0; mi < 4; ++mi) {
#pragma unroll
        for (int ni = 0; ni < 4; ++ni) {
          int d = ni * 16 + l16;
          float b1 = bias[head * 64 + d];
#pragma unroll
          for (int rr = 0; rr < 4; ++rr) {
            int t = m0 + wm * 64 + mi * 16 + lq * 4 + rr;
            int bb = t >> 11, tloc = t & 2047;
            vst[((size_t)bb * T_ + tloc) * 512 + vh * 64 + d] =
                f2bf(acc[mi][ni][rr] + b1);
          }
        }
      }
    }
  }
}

// ---------------- V (compact [B][T][512]) -> fragment-major bf16 via LDS ----------------
// Block = one 64t x 64d V tile. Reads row-coalesced (uint4), transposes
// through [64][72] LDS (2-way conflicts only), writes fragment-major uint4.
__global__ void cvt_v_k(const uint16_t* __restrict__ vst, uint16_t* __restrict__ vt) {
  __shared__ uint16_t tile[64][72];
  int blk = blockIdx.x;              // b*256 + kvh*32 + it
  int it = blk & 31;
  int kvh = (blk >> 5) & 7;
  int b = blk >> 8;
  int tid = threadIdx.x;
  int t0 = it * 64;

  {  // read: thread = (row r, 16-col group)
    int r = tid >> 2;
    int cg = (tid & 3) * 16;
    const uint16_t* src = vst + ((size_t)(b * T_ + t0 + r)) * 512 + kvh * 64 + cg;
    uint4 v0 = *reinterpret_cast<const uint4*>(src);
    uint4 v1 = *reinterpret_cast<const uint4*>(src + 8);
    *reinterpret_cast<uint4*>(&tile[r][cg]) = v0;
    *reinterpret_cast<uint4*>(&tile[r][cg + 8]) = v1;
  }
  __syncthreads();

  int d = tid & 63;
  int wv = tid >> 6;  // 0..3
  int dn = d >> 4, l16 = d & 15;
  size_t base = (size_t)(b * KVH_ + kvh) * (T_ * HD_);
#pragma unroll
  for (int j = 0; j < 2; ++j) {
    int oct = wv * 2 + j;            // t_local = oct*8 .. +7
    int k2 = oct >> 2, lq = oct & 3;
    uint16_t tmp[8];
#pragma unroll
    for (int e = 0; e < 8; ++e) tmp[e] = tile[oct * 8 + e][d];
    uint4 v;
    v.x = (uint32_t)tmp[0] | ((uint32_t)tmp[1] << 16);
    v.y = (uint32_t)tmp[2] | ((uint32_t)tmp[3] << 16);
    v.z = (uint32_t)tmp[4] | ((uint32_t)tmp[5] << 16);
    v.w = (uint32_t)tmp[6] | ((uint32_t)tmp[7] << 16);
    *reinterpret_cast<uint4*>(vt + base + ((size_t)(it * 2 + k2) * 4 + dn) * 512 +
                              (lq * 16 + l16) * 8) = v;
  }
}

// ---------------- flash attention (causal, GQA), swapped QK^T ----------------
// Fragment-major Q/K/V loads (single coalesced 1KB transaction per fragment),
// no row-max (exp2 unnormalized, O = PV/l cancels scale), l via ones-MFMA,
// K register double-buffer. Proven r11 structure.
__global__ __launch_bounds__(256, 2)
void flash_attn_k(const uint16_t* __restrict__ qb, const uint16_t* __restrict__ kb,
                  const uint16_t* __restrict__ vt, uint16_t* __restrict__ ob) {
  __shared__ __align__(16) uint16_t P_lds[4][32 * 72];  // per-wave 32 q x 64+pad
  const int lane = threadIdx.x & 63;
  const int w = threadIdx.x >> 6;
  const int l16 = lane & 15, lq = lane >> 4;
  const int bh = (blockIdx.x & 15) * 4 + w;
  const int rank = blockIdx.x >> 4;              // 0..63
  const int pair = rank & 31;
  const int tile = (rank & 32) ? (63 - pair) : pair;
  const int b = bh >> 5, h = bh & 31;
  const int kvh = h >> 2;
  uint16_t* P = P_lds[w];

  const uint16_t* Qp = qb + ((size_t)(b * H_ + h) * 64 + tile) * 2048;
  const uint16_t* Kp = kb + (size_t)(b * KVH_ + kvh) * (T_ * HD_);
  const uint16_t* Vp = vt + (size_t)(b * KVH_ + kvh) * (T_ * HD_);
  const int lofs = lane * 8;

  const int q0 = tile * 32;
  u32x4 ones_u = {0x3F803F80u, 0x3F803F80u, 0x3F803F80u, 0x3F803F80u};
  bf16x8 ones = __builtin_bit_cast(bf16x8, ones_u);

  bf16x8 aq[2][2];
#pragma unroll
  for (int mf = 0; mf < 2; ++mf)
#pragma unroll
    for (int ks = 0; ks < 2; ++ks)
      aq[mf][ks] = *reinterpret_cast<const bf16x8*>(Qp + (ks * 2 + mf) * 512 + lofs);

  f32x4 acc[2][4] = {};
  f32x4 acc_l[2] = {};

  const int nt = (tile >> 1) + 1;

  bf16x8 kA[2][4], kB[2][4];
#pragma unroll
  for (int ks = 0; ks < 2; ++ks)
#pragma unroll
    for (int nf = 0; nf < 4; ++nf)
      kA[ks][nf] = *reinterpret_cast<const bf16x8*>(Kp + (ks * 4 + nf) * 512 + lofs);

#define FLASH_STEP(KCUR, KNXT, IT)                                                     \
  do {                                                                                 \
    const int kv0 = (IT) * 64;                                                         \
    f32x4 sacc[4][2] = {};                                                             \
    _Pragma("unroll")                                                                  \
    for (int ks = 0; ks < 2; ++ks)                                                     \
      _Pragma("unroll")                                                                \
      for (int nf = 0; nf < 4; ++nf)                                                   \
        _Pragma("unroll")                                                              \
        for (int mf = 0; mf < 2; ++mf)                                                 \
          sacc[nf][mf] = __builtin_amdgcn_mfma_f32_16x16x32_bf16(                      \
              KCUR[ks][nf], aq[mf][ks], sacc[nf][mf], 0, 0, 0);                        \
    const int itn = ((IT) + 1 < nt) ? (IT) + 1 : (IT);                                 \
    _Pragma("unroll")                                                                  \
    for (int ks = 0; ks < 2; ++ks)                                                     \
      _Pragma("unroll")                                                                \
      for (int nf = 0; nf < 4; ++nf)                                                   \
        KNXT[ks][nf] = *reinterpret_cast<const bf16x8*>(                               \
            Kp + ((size_t)(itn * 2 + ks) * 4 + nf) * 512 + lofs);                      \
    bf16x8 vv[2][4];                                                                   \
    _Pragma("unroll")                                                                  \
    for (int k2 = 0; k2 < 2; ++k2)                                                     \
      _Pragma("unroll")                                                                \
      for (int dn = 0; dn < 4; ++dn)                                                   \
        vv[k2][dn] = *reinterpret_cast<const bf16x8*>(                                 \
            Vp + ((size_t)((IT) * 2 + k2) * 4 + dn) * 512 + lofs);                     \
    if ((IT) == nt - 1) {                                                              \
      _Pragma("unroll")                                                                \
      for (int mf = 0; mf < 2; ++mf) {                                                 \
        int qg = q0 + mf * 16 + l16;                                                   \
        _Pragma("unroll")                                                              \
        for (int nf = 0; nf < 4; ++nf)                                                 \
          _Pragma("unroll")                                                            \
          for (int r = 0; r < 4; ++r)                                                  \
            if (kv0 + nf * 16 + lq * 4 + r > qg) sacc[nf][mf][r] = -1e30f;             \
      }                                                                                \
    }                                                                                  \
    _Pragma("unroll")                                                                  \
    for (int mf = 0; mf < 2; ++mf) {                                                   \
      uint16_t* rowp = P + (mf * 16 + l16) * 72;                                       \
      _Pragma("unroll")                                                                \
      for (int nf = 0; nf < 4; ++nf) {                                                 \
        float p0 = __builtin_amdgcn_exp2f(sacc[nf][mf][0]);                            \
        float p1 = __builtin_amdgcn_exp2f(sacc[nf][mf][1]);                            \
        float p2 = __builtin_amdgcn_exp2f(sacc[nf][mf][2]);                            \
        float p3 = __builtin_amdgcn_exp2f(sacc[nf][mf][3]);                            \
        uint2 pk;                                                                      \
        pk.x = cvt_pk(p0, p1);                                                         \
        pk.y = cvt_pk(p2, p3);                                                         \
        *reinterpret_cast<uint2*>(rowp + nf * 16 + lq * 4) = pk;                       \
      }                                                                                \
    }                                                                                  \
    bf16x8 pa[2][2];                                                                   \
    _Pragma("unroll")                                                                  \
    for (int mf = 0; mf < 2; ++mf)                                                     \
      _Pragma("unroll")                                                                \
      for (int k2 = 0; k2 < 2; ++k2)                                                   \
        pa[mf][k2] = *reinterpret_cast<const bf16x8*>(                                 \
            P + (mf * 16 + l16) * 72 + k2 * 32 + lq * 8);                              \
    _Pragma("unroll")                                                                  \
    for (int k2 = 0; k2 < 2; ++k2)                                                     \
      _Pragma("unroll")                                                                \
      for (int mf = 0; mf < 2; ++mf) {                                                 \
        acc_l[mf] = __builtin_amdgcn_mfma_f32_16x16x32_bf16(ones, pa[mf][k2],          \
                                                            acc_l[mf], 0, 0, 0);      \
        _Pragma("unroll")                                                              \
        for (int dn = 0; dn < 4; ++dn)                                                 \
          acc[mf][dn] = __builtin_amdgcn_mfma_f32_16x16x32_bf16(                       \
              vv[k2][dn], pa[mf][k2], acc[mf][dn], 0, 0, 0);                           \
      }                                                                                \
  } while (0)

  {
    int it = 0;
    for (;;) {
      FLASH_STEP(kA, kB, it);
      ++it;
      if (it == nt) break;
      FLASH_STEP(kB, kA, it);
      ++it;
      if (it == nt) break;
    }
  }
#undef FLASH_STEP

#pragma unroll
  for (int mf = 0; mf < 2; ++mf) {
    float inv = 1.0f / acc_l[mf][0];
    uint16_t* rowp = P + (mf * 16 + l16) * 72;
#pragma unroll
    for (int dn = 0; dn < 4; ++dn) {
      uint2 pk;
      pk.x = cvt_pk(acc[mf][dn][0] * inv, acc[mf][dn][1] * inv);
      pk.y = cvt_pk(acc[mf][dn][2] * inv, acc[mf][dn][3] * inv);
      *reinterpret_cast<uint2*>(rowp + dn * 16 + lq * 4) = pk;
    }
  }
  {
    int orow = lane >> 1, ohalf = (lane & 1) * 32;
    uint16_t* op = ob + (size_t)(b * T_ + q0 + orow) * D_ + h * HD_ + ohalf;
    const uint16_t* lp = P + orow * 72 + ohalf;
#pragma unroll
    for (int j = 0; j < 4; ++j)
      *reinterpret_cast<uint4*>(op + j * 8) = *reinterpret_cast<const uint4*>(lp + j * 8);
  }
}

extern "C" void kernel_launch(void* const* d_in, const int* in_sizes, int n_in,
                              void* d_out, int out_size, void* d_ws, size_t ws_size,
                              hipStream_t stream) {
  const float* x  = (const float*)d_in[0];
  const float* Wq = (const float*)d_in[1];
  const float* bq = (const float*)d_in[2];
  const float* Wk = (const float*)d_in[3];
  const float* bk = (const float*)d_in[4];
  const float* Wv = (const float*)d_in[5];
  const float* bv = (const float*)d_in[6];
  const float* Wo = (const float*)d_in[7];
  const float* bo = (const float*)d_in[8];
  float* out = (float*)d_out;

  char* ws = (char*)d_ws;
  size_t off = 0;
  auto alloc = [&](size_t bytes) {
    void* p = ws + off;
    off += (bytes + 255) & ~(size_t)255;
    return p;
  };
  uint16_t* xb    = (uint16_t*)alloc((size_t)M_ * D_ * 2);
  uint16_t* wqkv  = (uint16_t*)alloc((size_t)NQKV_ * D_ * 2);
  uint16_t* wo_b  = (uint16_t*)alloc((size_t)D_ * D_ * 2);
  float*    bqkv  = (float*)alloc(NQKV_ * 4);
  float*    cosT  = (float*)alloc(T_ * 32 * 4);
  float*    sinT  = (float*)alloc(T_ * 32 * 4);
  uint16_t* q_bf  = (uint16_t*)alloc((size_t)B_ * H_ * T_ * HD_ * 2);
  uint16_t* k_bf  = (uint16_t*)alloc((size_t)B_ * KVH_ * T_ * HD_ * 2);
  uint16_t* vt_bf = (uint16_t*)alloc((size_t)B_ * KVH_ * T_ * HD_ * 2);
  uint16_t* vst   = (uint16_t*)alloc((size_t)B_ * T_ * 512 * 2);   // 4.2 MB
  uint16_t* attn_bf = (uint16_t*)alloc((size_t)B_ * T_ * D_ * 2);  // 16.8 MB

  cvt_bf16_k<<<4096, 256, 0, stream>>>(x, xb, M_ * D_);
  cvt_bf16_k<<<2048, 256, 0, stream>>>(Wq, wqkv, D_ * D_);
  cvt_bf16_k<<<512, 256, 0, stream>>>(Wk, wqkv + (size_t)D_ * D_, 512 * D_);
  cvt_bf16_k<<<512, 256, 0, stream>>>(Wv, wqkv + (size_t)2560 * D_, 512 * D_);
  cvt_bf16_k<<<2048, 256, 0, stream>>>(Wo, wo_b, D_ * D_);
  concat_bias_k<<<12, 256, 0, stream>>>(bq, bk, bv, bqkv);
  rope_tab_k<<<256, 256, 0, stream>>>(cosT, sinT);

  gemm_bf16<1><<<dim3(NQKV_ / BN, M_ / BM), 256, 0, stream>>>(
      xb, wqkv, bqkv, nullptr, M_, NQKV_, D_, cosT, sinT, q_bf, k_bf, vst);

  cvt_v_k<<<B_ * KVH_ * (T_ / 64), 256, 0, stream>>>(vst, vt_bf);

  flash_attn_k<<<1024, 256, 0, stream>>>(q_bf, k_bf, vt_bf, attn_bf);

  gemm_bf16<0><<<dim3(D_ / BN, M_ / BM), 256, 0, stream>>>(
      attn_bf, wo_b, bo, out, M_, D_, D_, nullptr, nullptr, nullptr, nullptr, nullptr);
}

// Round 19
// 169.041 us; speedup vs baseline: 1.3752x; 1.0631x over previous
//
#include <hip/hip_runtime.h>
#include <hip/hip_bf16.h>
#include <cstdint>

#define B_ 2
#define T_ 2048
#define D_ 2048
#define H_ 32
#define KVH_ 8
#define HD_ 64
#define NQKV_ 3072
#define M_ 4096

typedef __attribute__((ext_vector_type(8))) __bf16 bf16x8;
typedef __attribute__((ext_vector_type(4))) float f32x4;
typedef __attribute__((ext_vector_type(4))) uint32_t u32x4;

__device__ __forceinline__ uint16_t f2bf(float f) {
  uint32_t u = __builtin_bit_cast(uint32_t, f);
  return (uint16_t)((u + 0x7FFFu + ((u >> 16) & 1u)) >> 16);
}

__device__ __forceinline__ float bf2f(uint16_t u) {
  return __builtin_bit_cast(float, (uint32_t)u << 16);
}

__device__ __forceinline__ uint32_t cvt_pk(float lo, float hi) {
  uint32_t r;
  asm("v_cvt_pk_bf16_f32 %0, %1, %2" : "=v"(r) : "v"(lo), "v"(hi));
  return r;
}

__device__ __forceinline__ void gload_lds16(const void* g, void* l) {
  __builtin_amdgcn_global_load_lds(
      (const __attribute__((address_space(1))) void*)(uintptr_t)g,
      (__attribute__((address_space(3))) void*)(uintptr_t)l, 16, 0, 0);
}

// ---------------- fp32 -> bf16 convert (x input, vectorized x8) ----------------
__global__ void cvt_bf16_k(const float* __restrict__ in, uint16_t* __restrict__ out, int n) {
  int i = (blockIdx.x * 256 + threadIdx.x) * 8;
  if (i >= n) return;
  float4 a = *reinterpret_cast<const float4*>(in + i);
  float4 b = *reinterpret_cast<const float4*>(in + i + 4);
  uint4 v;
  v.x = (uint32_t)f2bf(a.x) | ((uint32_t)f2bf(a.y) << 16);
  v.y = (uint32_t)f2bf(a.z) | ((uint32_t)f2bf(a.w) << 16);
  v.z = (uint32_t)f2bf(b.x) | ((uint32_t)f2bf(b.y) << 16);
  v.w = (uint32_t)f2bf(b.z) | ((uint32_t)f2bf(b.w) << 16);
  *reinterpret_cast<uint4*>(out + i) = v;
}

// ---------------- consolidated prologue: W converts + rope tables + bias ----------------
// blocks [0,2048) Wq | [2048,2560) Wk | [2560,3072) Wv | [3072,5120) Wo |
// [5120,5376) rope tables | [5376,5388) bias concat.
__global__ void prep_k(const float* __restrict__ Wq, const float* __restrict__ Wk,
                       const float* __restrict__ Wv, const float* __restrict__ Wo,
                       const float* __restrict__ bq, const float* __restrict__ bk,
                       const float* __restrict__ bv,
                       uint16_t* __restrict__ wqkv, uint16_t* __restrict__ wo_b,
                       float* __restrict__ bqkv, float* __restrict__ cosT,
                       float* __restrict__ sinT) {
  int blk = blockIdx.x;
  if (blk < 5120) {
    const float* src;
    uint16_t* dst;
    int off;
    if (blk < 2048) { src = Wq; dst = wqkv; off = blk; }
    else if (blk < 2560) { src = Wk; dst = wqkv + (size_t)D_ * D_; off = blk - 2048; }
    else if (blk < 3072) { src = Wv; dst = wqkv + (size_t)2560 * D_; off = blk - 2560; }
    else { src = Wo; dst = wo_b; off = blk - 3072; }
    int i = (off * 256 + threadIdx.x) * 8;
    float4 a = *reinterpret_cast<const float4*>(src + i);
    float4 b = *reinterpret_cast<const float4*>(src + i + 4);
    uint4 v;
    v.x = (uint32_t)f2bf(a.x) | ((uint32_t)f2bf(a.y) << 16);
    v.y = (uint32_t)f2bf(a.z) | ((uint32_t)f2bf(a.w) << 16);
    v.z = (uint32_t)f2bf(b.x) | ((uint32_t)f2bf(b.y) << 16);
    v.w = (uint32_t)f2bf(b.z) | ((uint32_t)f2bf(b.w) << 16);
    *reinterpret_cast<uint4*>(dst + i) = v;
  } else if (blk < 5376) {
    int i = (blk - 5120) * 256 + threadIdx.x;  // 0..65535
    int d = i & 31;
    int t = i >> 5;
    float inv = expf(-(float)d * (1.0f / 32.0f) * logf(10000.0f));
    float f = (float)t * inv;
    cosT[i] = cosf(f);
    sinT[i] = sinf(f);
  } else {
    int i = (blk - 5376) * 256 + threadIdx.x;
    if (i < NQKV_)
      bqkv[i] = (i < D_) ? bq[i] : (i < D_ + 512) ? bk[i - D_] : bv[i - D_ - 512];
  }
}

// ---------------- GEMM: C[m][n] = sum_k A[m][k]*Bw[n][k] + bias[n] ----------------
// Proven r11 128x128 structure (~920 TF here). MODE 0: fp32 C (O-proj).
// MODE 1: fused QKV epilogue -- each wave's 64-col span is exactly ONE head;
// the rope pair (d, d+32) is acc[mi][ni] / acc[mi][ni+2] of the SAME wave.
#define BM 128
#define BN 128
#define BK 64
template <int MODE>
__global__ __launch_bounds__(256, 3)
void gemm_bf16(const uint16_t* __restrict__ A, const uint16_t* __restrict__ Bw,
               const float* __restrict__ bias, void* __restrict__ Cv,
               int M, int N, int K,
               const float* __restrict__ cosT, const float* __restrict__ sinT,
               uint16_t* __restrict__ qb, uint16_t* __restrict__ kb,
               uint16_t* __restrict__ vst) {
  __shared__ __align__(16) uint16_t As[BM * BK];
  __shared__ __align__(16) uint16_t Bs[BN * BK];
  const int tid = threadIdx.x;
  const int lane = tid & 63;
  const int w = tid >> 6;
  const int wm = w >> 1, wn = w & 1;
  const int l16 = lane & 15, lq = lane >> 4;

  int lin = blockIdx.y * gridDim.x + blockIdx.x;
  int qn = (gridDim.x * gridDim.y) >> 3;   // nwg % 8 == 0 for both calls
  int swz = (lin & 7) * qn + (lin >> 3);
  const int m0 = (swz / gridDim.x) * BM, n0 = (swz % gridDim.x) * BN;

  f32x4 acc[4][4] = {};

  for (int k0 = 0; k0 < K; k0 += BK) {
#pragma unroll
    for (int r = 0; r < 4; ++r) {
      int idx = r * 256 + tid;
      int row = idx >> 3;
      int c8 = (idx & 7) ^ (row & 7);
      gload_lds16(A + (size_t)(m0 + row) * K + k0 + c8 * 8, &As[idx * 8]);
    }
#pragma unroll
    for (int r = 0; r < 4; ++r) {
      int idx = r * 256 + tid;
      int row = idx >> 3;
      int c8 = (idx & 7) ^ (row & 7);
      gload_lds16(Bw + (size_t)(n0 + row) * K + k0 + c8 * 8, &Bs[idx * 8]);
    }
    __syncthreads();
#pragma unroll
    for (int ks = 0; ks < 2; ++ks) {
      bf16x8 av[4], bv[4];
      int k8 = ks * 4 + lq;
#pragma unroll
      for (int mi = 0; mi < 4; ++mi) {
        int row = wm * 64 + mi * 16 + l16;
        av[mi] = *reinterpret_cast<const bf16x8*>(&As[row * BK + ((k8 ^ (row & 7)) * 8)]);
      }
#pragma unroll
      for (int ni = 0; ni < 4; ++ni) {
        int row = wn * 64 + ni * 16 + l16;
        bv[ni] = *reinterpret_cast<const bf16x8*>(&Bs[row * BK + ((k8 ^ (row & 7)) * 8)]);
      }
#pragma unroll
      for (int mi = 0; mi < 4; ++mi)
#pragma unroll
        for (int ni = 0; ni < 4; ++ni)
          acc[mi][ni] = __builtin_amdgcn_mfma_f32_16x16x32_bf16(av[mi], bv[ni], acc[mi][ni], 0, 0, 0);
    }
    __syncthreads();
  }

  if constexpr (MODE == 0) {
#pragma unroll
    for (int mi = 0; mi < 4; ++mi) {
      int r0 = m0 + wm * 64 + mi * 16 + lq * 4;
#pragma unroll
      for (int ni = 0; ni < 4; ++ni) {
        int c = n0 + wn * 64 + ni * 16 + l16;
        float bb = bias[c];
#pragma unroll
        for (int rr = 0; rr < 4; ++rr)
          ((float*)Cv)[(size_t)(r0 + rr) * N + c] = acc[mi][ni][rr] + bb;
      }
    }
  } else {
    const int head = (n0 + wn * 64) >> 6;
    if (head < H_) {
      const float PREQ = 0.125f * 1.44269504f;
#pragma unroll
      for (int mi = 0; mi < 4; ++mi) {
#pragma unroll
        for (int ni = 0; ni < 2; ++ni) {
          int d = ni * 16 + l16;
          int cg = head * 64 + d;
          float b1 = bias[cg], b2 = bias[cg + 32];
#pragma unroll
          for (int rr = 0; rr < 4; ++rr) {
            int t = m0 + wm * 64 + mi * 16 + lq * 4 + rr;
            int bb = t >> 11, tloc = t & 2047;
            float x1 = acc[mi][ni][rr] + b1;
            float x2 = acc[mi][ni + 2][rr] + b2;
            float cc = cosT[tloc * 32 + d], ss = sinT[tloc * 32 + d];
            int tile = tloc >> 5, mf = (tloc >> 4) & 1, l16f = tloc & 15;
            size_t base = ((size_t)(bb * H_ + head) * 64 + tile) * 2048;
            int lofs = ((d >> 3) * 16 + l16f) * 8 + (d & 7);
            qb[base + mf * 512 + lofs] = f2bf((x1 * cc - x2 * ss) * PREQ);       // ks=0
            qb[base + (2 + mf) * 512 + lofs] = f2bf((x2 * cc + x1 * ss) * PREQ); // ks=1
          }
        }
      }
    } else if (head < H_ + KVH_) {
      int kh = head - H_;
#pragma unroll
      for (int mi = 0; mi < 4; ++mi) {
#pragma unroll
        for (int ni = 0; ni < 2; ++ni) {
          int d = ni * 16 + l16;
          int cg = head * 64 + d;
          float b1 = bias[cg], b2 = bias[cg + 32];
#pragma unroll
          for (int rr = 0; rr < 4; ++rr) {
            int t = m0 + wm * 64 + mi * 16 + lq * 4 + rr;
            int bb = t >> 11, tloc = t & 2047;
            float x1 = acc[mi][ni][rr] + b1;
            float x2 = acc[mi][ni + 2][rr] + b2;
            float cc = cosT[tloc * 32 + d], ss = sinT[tloc * 32 + d];
            int it = tloc >> 6, nf = (tloc >> 4) & 3, l16f = tloc & 15;
            size_t base = (size_t)(bb * KVH_ + kh) * (T_ * HD_) + (size_t)it * 4096;
            int lofs = ((d >> 3) * 16 + l16f) * 8 + (d & 7);
            kb[base + nf * 512 + lofs] = f2bf(x1 * cc - x2 * ss);         // ks=0
            kb[base + (4 + nf) * 512 + lofs] = f2bf(x2 * cc + x1 * ss);   // ks=1
          }
        }
      }
    } else {
      int vh = head - H_ - KVH_;
#pragma unroll
      for (int mi = 0; mi < 4; ++mi) {
#pragma unroll
        for (int ni = 0; ni < 4; ++ni) {
          int d = ni * 16 + l16;
          float b1 = bias[head * 64 + d];
#pragma unroll
          for (int rr = 0; rr < 4; ++rr) {
            int t = m0 + wm * 64 + mi * 16 + lq * 4 + rr;
            int bb = t >> 11, tloc = t & 2047;
            vst[((size_t)bb * T_ + tloc) * 512 + vh * 64 + d] =
                f2bf(acc[mi][ni][rr] + b1);
          }
        }
      }
    }
  }
}

// ---------------- V (compact [B][T][512]) -> fragment-major bf16 via LDS ----------------
__global__ void cvt_v_k(const uint16_t* __restrict__ vst, uint16_t* __restrict__ vt) {
  __shared__ uint16_t tile[64][72];
  int blk = blockIdx.x;              // b*256 + kvh*32 + it
  int it = blk & 31;
  int kvh = (blk >> 5) & 7;
  int b = blk >> 8;
  int tid = threadIdx.x;
  int t0 = it * 64;

  {
    int r = tid >> 2;
    int cg = (tid & 3) * 16;
    const uint16_t* src = vst + ((size_t)(b * T_ + t0 + r)) * 512 + kvh * 64 + cg;
    uint4 v0 = *reinterpret_cast<const uint4*>(src);
    uint4 v1 = *reinterpret_cast<const uint4*>(src + 8);
    *reinterpret_cast<uint4*>(&tile[r][cg]) = v0;
    *reinterpret_cast<uint4*>(&tile[r][cg + 8]) = v1;
  }
  __syncthreads();

  int d = tid & 63;
  int wv = tid >> 6;
  int dn = d >> 4, l16 = d & 15;
  size_t base = (size_t)(b * KVH_ + kvh) * (T_ * HD_);
#pragma unroll
  for (int j = 0; j < 2; ++j) {
    int oct = wv * 2 + j;
    int k2 = oct >> 2, lq = oct & 3;
    uint16_t tmp[8];
#pragma unroll
    for (int e = 0; e < 8; ++e) tmp[e] = tile[oct * 8 + e][d];
    uint4 v;
    v.x = (uint32_t)tmp[0] | ((uint32_t)tmp[1] << 16);
    v.y = (uint32_t)tmp[2] | ((uint32_t)tmp[3] << 16);
    v.z = (uint32_t)tmp[4] | ((uint32_t)tmp[5] << 16);
    v.w = (uint32_t)tmp[6] | ((uint32_t)tmp[7] << 16);
    *reinterpret_cast<uint4*>(vt + base + ((size_t)(it * 2 + k2) * 4 + dn) * 512 +
                              (lq * 16 + l16) * 8) = v;
  }
}

// ---------------- flash attention (causal, GQA), swapped QK^T ----------------
__global__ __launch_bounds__(256, 2)
void flash_attn_k(const uint16_t* __restrict__ qb, const uint16_t* __restrict__ kb,
                  const uint16_t* __restrict__ vt, uint16_t* __restrict__ ob) {
  __shared__ __align__(16) uint16_t P_lds[4][32 * 72];
  const int lane = threadIdx.x & 63;
  const int w = threadIdx.x >> 6;
  const int l16 = lane & 15, lq = lane >> 4;
  const int bh = (blockIdx.x & 15) * 4 + w;
  const int rank = blockIdx.x >> 4;
  const int pair = rank & 31;
  const int tile = (rank & 32) ? (63 - pair) : pair;
  const int b = bh >> 5, h = bh & 31;
  const int kvh = h >> 2;
  uint16_t* P = P_lds[w];

  const uint16_t* Qp = qb + ((size_t)(b * H_ + h) * 64 + tile) * 2048;
  const uint16_t* Kp = kb + (size_t)(b * KVH_ + kvh) * (T_ * HD_);
  const uint16_t* Vp = vt + (size_t)(b * KVH_ + kvh) * (T_ * HD_);
  const int lofs = lane * 8;

  const int q0 = tile * 32;
  u32x4 ones_u = {0x3F803F80u, 0x3F803F80u, 0x3F803F80u, 0x3F803F80u};
  bf16x8 ones = __builtin_bit_cast(bf16x8, ones_u);

  bf16x8 aq[2][2];
#pragma unroll
  for (int mf = 0; mf < 2; ++mf)
#pragma unroll
    for (int ks = 0; ks < 2; ++ks)
      aq[mf][ks] = *reinterpret_cast<const bf16x8*>(Qp + (ks * 2 + mf) * 512 + lofs);

  f32x4 acc[2][4] = {};
  f32x4 acc_l[2] = {};

  const int nt = (tile >> 1) + 1;

  bf16x8 kA[2][4], kB[2][4];
#pragma unroll
  for (int ks = 0; ks < 2; ++ks)
#pragma unroll
    for (int nf = 0; nf < 4; ++nf)
      kA[ks][nf] = *reinterpret_cast<const bf16x8*>(Kp + (ks * 4 + nf) * 512 + lofs);

#define FLASH_STEP(KCUR, KNXT, IT)                                                     \
  do {                                                                                 \
    const int kv0 = (IT) * 64;                                                         \
    f32x4 sacc[4][2] = {};                                                             \
    _Pragma("unroll")                                                                  \
    for (int ks = 0; ks < 2; ++ks)                                                     \
      _Pragma("unroll")                                                                \
      for (int nf = 0; nf < 4; ++nf)                                                   \
        _Pragma("unroll")                                                              \
        for (int mf = 0; mf < 2; ++mf)                                                 \
          sacc[nf][mf] = __builtin_amdgcn_mfma_f32_16x16x32_bf16(                      \
              KCUR[ks][nf], aq[mf][ks], sacc[nf][mf], 0, 0, 0);                        \
    const int itn = ((IT) + 1 < nt) ? (IT) + 1 : (IT);                                 \
    _Pragma("unroll")                                                                  \
    for (int ks = 0; ks < 2; ++ks)                                                     \
      _Pragma("unroll")                                                                \
      for (int nf = 0; nf < 4; ++nf)                                                   \
        KNXT[ks][nf] = *reinterpret_cast<const bf16x8*>(                               \
            Kp + ((size_t)(itn * 2 + ks) * 4 + nf) * 512 + lofs);                      \
    bf16x8 vv[2][4];                                                                   \
    _Pragma("unroll")                                                                  \
    for (int k2 = 0; k2 < 2; ++k2)                                                     \
      _Pragma("unroll")                                                                \
      for (int dn = 0; dn < 4; ++dn)                                                   \
        vv[k2][dn] = *reinterpret_cast<const bf16x8*>(                                 \
            Vp + ((size_t)((IT) * 2 + k2) * 4 + dn) * 512 + lofs);                     \
    if ((IT) == nt - 1) {                                                              \
      _Pragma("unroll")                                                                \
      for (int mf = 0; mf < 2; ++mf) {                                                 \
        int qg = q0 + mf * 16 + l16;                                                   \
        _Pragma("unroll")                                                              \
        for (int nf = 0; nf < 4; ++nf)                                                 \
          _Pragma("unroll")                                                            \
          for (int r = 0; r < 4; ++r)                                                  \
            if (kv0 + nf * 16 + lq * 4 + r > qg) sacc[nf][mf][r] = -1e30f;             \
      }                                                                                \
    }                                                                                  \
    _Pragma("unroll")                                                                  \
    for (int mf = 0; mf < 2; ++mf) {                                                   \
      uint16_t* rowp = P + (mf * 16 + l16) * 72;                                       \
      _Pragma("unroll")                                                                \
      for (int nf = 0; nf < 4; ++nf) {                                                 \
        float p0 = __builtin_amdgcn_exp2f(sacc[nf][mf][0]);                            \
        float p1 = __builtin_amdgcn_exp2f(sacc[nf][mf][1]);                            \
        float p2 = __builtin_amdgcn_exp2f(sacc[nf][mf][2]);                            \
        float p3 = __builtin_amdgcn_exp2f(sacc[nf][mf][3]);                            \
        uint2 pk;                                                                      \
        pk.x = cvt_pk(p0, p1);                                                         \
        pk.y = cvt_pk(p2, p3);                                                         \
        *reinterpret_cast<uint2*>(rowp + nf * 16 + lq * 4) = pk;                       \
      }                                                                                \
    }                                                                                  \
    bf16x8 pa[2][2];                                                                   \
    _Pragma("unroll")                                                                  \
    for (int mf = 0; mf < 2; ++mf)                                                     \
      _Pragma("unroll")                                                                \
      for (int k2 = 0; k2 < 2; ++k2)                                                   \
        pa[mf][k2] = *reinterpret_cast<const bf16x8*>(                                 \
            P + (mf * 16 + l16) * 72 + k2 * 32 + lq * 8);                              \
    _Pragma("unroll")                                                                  \
    for (int k2 = 0; k2 < 2; ++k2)                                                     \
      _Pragma("unroll")                                                                \
      for (int mf = 0; mf < 2; ++mf) {                                                 \
        acc_l[mf] = __builtin_amdgcn_mfma_f32_16x16x32_bf16(ones, pa[mf][k2],          \
                                                            acc_l[mf], 0, 0, 0);      \
        _Pragma("unroll")                                                              \
        for (int dn = 0; dn < 4; ++dn)                                                 \
          acc[mf][dn] = __builtin_amdgcn_mfma_f32_16x16x32_bf16(                       \
              vv[k2][dn], pa[mf][k2], acc[mf][dn], 0, 0, 0);                           \
      }                                                                                \
  } while (0)

  {
    int it = 0;
    for (;;) {
      FLASH_STEP(kA, kB, it);
      ++it;
      if (it == nt) break;
      FLASH_STEP(kB, kA, it);
      ++it;
      if (it == nt) break;
    }
  }
#undef FLASH_STEP

#pragma unroll
  for (int mf = 0; mf < 2; ++mf) {
    float inv = 1.0f / acc_l[mf][0];
    uint16_t* rowp = P + (mf * 16 + l16) * 72;
#pragma unroll
    for (int dn = 0; dn < 4; ++dn) {
      uint2 pk;
      pk.x = cvt_pk(acc[mf][dn][0] * inv, acc[mf][dn][1] * inv);
      pk.y = cvt_pk(acc[mf][dn][2] * inv, acc[mf][dn][3] * inv);
      *reinterpret_cast<uint2*>(rowp + dn * 16 + lq * 4) = pk;
    }
  }
  {
    int orow = lane >> 1, ohalf = (lane & 1) * 32;
    uint16_t* op = ob + (size_t)(b * T_ + q0 + orow) * D_ + h * HD_ + ohalf;
    const uint16_t* lp = P + orow * 72 + ohalf;
#pragma unroll
    for (int j = 0; j < 4; ++j)
      *reinterpret_cast<uint4*>(op + j * 8) = *reinterpret_cast<const uint4*>(lp + j * 8);
  }
}

extern "C" void kernel_launch(void* const* d_in, const int* in_sizes, int n_in,
                              void* d_out, int out_size, void* d_ws, size_t ws_size,
                              hipStream_t stream) {
  const float* x  = (const float*)d_in[0];
  const float* Wq = (const float*)d_in[1];
  const float* bq = (const float*)d_in[2];
  const float* Wk = (const float*)d_in[3];
  const float* bk = (const float*)d_in[4];
  const float* Wv = (const float*)d_in[5];
  const float* bv = (const float*)d_in[6];
  const float* Wo = (const float*)d_in[7];
  const float* bo = (const float*)d_in[8];
  float* out = (float*)d_out;

  char* ws = (char*)d_ws;
  size_t off = 0;
  auto alloc = [&](size_t bytes) {
    void* p = ws + off;
    off += (bytes + 255) & ~(size_t)255;
    return p;
  };
  uint16_t* xb    = (uint16_t*)alloc((size_t)M_ * D_ * 2);
  uint16_t* wqkv  = (uint16_t*)alloc((size_t)NQKV_ * D_ * 2);
  uint16_t* wo_b  = (uint16_t*)alloc((size_t)D_ * D_ * 2);
  float*    bqkv  = (float*)alloc(NQKV_ * 4);
  float*    cosT  = (float*)alloc(T_ * 32 * 4);
  float*    sinT  = (float*)alloc(T_ * 32 * 4);
  uint16_t* q_bf  = (uint16_t*)alloc((size_t)B_ * H_ * T_ * HD_ * 2);
  uint16_t* k_bf  = (uint16_t*)alloc((size_t)B_ * KVH_ * T_ * HD_ * 2);
  uint16_t* vt_bf = (uint16_t*)alloc((size_t)B_ * KVH_ * T_ * HD_ * 2);
  uint16_t* vst   = (uint16_t*)alloc((size_t)B_ * T_ * 512 * 2);   // 4.2 MB
  uint16_t* attn_bf = (uint16_t*)alloc((size_t)B_ * T_ * D_ * 2);  // 16.8 MB

  cvt_bf16_k<<<4096, 256, 0, stream>>>(x, xb, M_ * D_);
  prep_k<<<5388, 256, 0, stream>>>(Wq, Wk, Wv, Wo, bq, bk, bv,
                                   wqkv, wo_b, bqkv, cosT, sinT);

  gemm_bf16<1><<<dim3(NQKV_ / BN, M_ / BM), 256, 0, stream>>>(
      xb, wqkv, bqkv, nullptr, M_, NQKV_, D_, cosT, sinT, q_bf, k_bf, vst);

  cvt_v_k<<<B_ * KVH_ * (T_ / 64), 256, 0, stream>>>(vst, vt_bf);

  flash_attn_k<<<1024, 256, 0, stream>>>(q_bf, k_bf, vt_bf, attn_bf);

  gemm_bf16<0><<<dim3(D_ / BN, M_ / BM), 256, 0, stream>>>(
      attn_bf, wo_b, bo, out, M_, D_, D_, nullptr, nullptr, nullptr, nullptr, nullptr);
}

// Round 20
// 167.260 us; speedup vs baseline: 1.3898x; 1.0106x over previous
//
#include <hip/hip_runtime.h>
#include <hip/hip_bf16.h>
#include <cstdint>

#define B_ 2
#define T_ 2048
#define D_ 2048
#define H_ 32
#define KVH_ 8
#define HD_ 64
#define NQKV_ 3072
#define M_ 4096

typedef __attribute__((ext_vector_type(8))) __bf16 bf16x8;
typedef __attribute__((ext_vector_type(4))) float f32x4;
typedef __attribute__((ext_vector_type(4))) uint32_t u32x4;

__device__ __forceinline__ uint16_t f2bf(float f) {
  uint32_t u = __builtin_bit_cast(uint32_t, f);
  return (uint16_t)((u + 0x7FFFu + ((u >> 16) & 1u)) >> 16);
}

__device__ __forceinline__ float bf2f(uint16_t u) {
  return __builtin_bit_cast(float, (uint32_t)u << 16);
}

__device__ __forceinline__ uint32_t cvt_pk(float lo, float hi) {
  uint32_t r;
  asm("v_cvt_pk_bf16_f32 %0, %1, %2" : "=v"(r) : "v"(lo), "v"(hi));
  return r;
}

__device__ __forceinline__ void gload_lds16(const void* g, void* l) {
  __builtin_amdgcn_global_load_lds(
      (const __attribute__((address_space(1))) void*)(uintptr_t)g,
      (__attribute__((address_space(3))) void*)(uintptr_t)l, 16, 0, 0);
}

// ---------------- single consolidated prologue ----------------
// blocks [0,2048) Wq | [2048,2560) Wk | [2560,3072) Wv | [3072,5120) Wo |
// [5120,5376) rope tables | [5376,5388) bias concat | [5388,9484) x convert.
__global__ void prep_k(const float* __restrict__ x, const float* __restrict__ Wq,
                       const float* __restrict__ Wk, const float* __restrict__ Wv,
                       const float* __restrict__ Wo, const float* __restrict__ bq,
                       const float* __restrict__ bk, const float* __restrict__ bv,
                       uint16_t* __restrict__ xb, uint16_t* __restrict__ wqkv,
                       uint16_t* __restrict__ wo_b, float* __restrict__ bqkv,
                       float* __restrict__ cosT, float* __restrict__ sinT) {
  int blk = blockIdx.x;
  if (blk < 5120 || blk >= 5388) {
    const float* src;
    uint16_t* dst;
    int off;
    if (blk >= 5388) { src = x; dst = xb; off = blk - 5388; }
    else if (blk < 2048) { src = Wq; dst = wqkv; off = blk; }
    else if (blk < 2560) { src = Wk; dst = wqkv + (size_t)D_ * D_; off = blk - 2048; }
    else if (blk < 3072) { src = Wv; dst = wqkv + (size_t)2560 * D_; off = blk - 2560; }
    else { src = Wo; dst = wo_b; off = blk - 3072; }
    int i = (off * 256 + threadIdx.x) * 8;
    float4 a = *reinterpret_cast<const float4*>(src + i);
    float4 b = *reinterpret_cast<const float4*>(src + i + 4);
    uint4 v;
    v.x = (uint32_t)f2bf(a.x) | ((uint32_t)f2bf(a.y) << 16);
    v.y = (uint32_t)f2bf(a.z) | ((uint32_t)f2bf(a.w) << 16);
    v.z = (uint32_t)f2bf(b.x) | ((uint32_t)f2bf(b.y) << 16);
    v.w = (uint32_t)f2bf(b.z) | ((uint32_t)f2bf(b.w) << 16);
    *reinterpret_cast<uint4*>(dst + i) = v;
  } else if (blk < 5376) {
    int i = (blk - 5120) * 256 + threadIdx.x;  // 0..65535
    int d = i & 31;
    int t = i >> 5;
    float inv = expf(-(float)d * (1.0f / 32.0f) * logf(10000.0f));
    float f = (float)t * inv;
    cosT[i] = cosf(f);
    sinT[i] = sinf(f);
  } else {
    int i = (blk - 5376) * 256 + threadIdx.x;
    if (i < NQKV_)
      bqkv[i] = (i < D_) ? bq[i] : (i < D_ + 512) ? bk[i - D_] : bv[i - D_ - 512];
  }
}

// ---------------- GEMM: C[m][n] = sum_k A[m][k]*Bw[n][k] + bias[n] ----------------
// Proven r11 128x128 structure (~920 TF here). MODE 0: fp32 C (O-proj).
// MODE 1: fused QKV epilogue -- each wave's 64-col span is exactly ONE head;
// the rope pair (d, d+32) is acc[mi][ni] / acc[mi][ni+2] of the SAME wave.
#define BM 128
#define BN 128
#define BK 64
template <int MODE>
__global__ __launch_bounds__(256, 3)
void gemm_bf16(const uint16_t* __restrict__ A, const uint16_t* __restrict__ Bw,
               const float* __restrict__ bias, void* __restrict__ Cv,
               int M, int N, int K,
               const float* __restrict__ cosT, const float* __restrict__ sinT,
               uint16_t* __restrict__ qb, uint16_t* __restrict__ kb,
               uint16_t* __restrict__ vst) {
  __shared__ __align__(16) uint16_t As[BM * BK];
  __shared__ __align__(16) uint16_t Bs[BN * BK];
  const int tid = threadIdx.x;
  const int lane = tid & 63;
  const int w = tid >> 6;
  const int wm = w >> 1, wn = w & 1;
  const int l16 = lane & 15, lq = lane >> 4;

  int lin = blockIdx.y * gridDim.x + blockIdx.x;
  int qn = (gridDim.x * gridDim.y) >> 3;   // nwg % 8 == 0 for both calls
  int swz = (lin & 7) * qn + (lin >> 3);
  const int m0 = (swz / gridDim.x) * BM, n0 = (swz % gridDim.x) * BN;

  f32x4 acc[4][4] = {};

  for (int k0 = 0; k0 < K; k0 += BK) {
#pragma unroll
    for (int r = 0; r < 4; ++r) {
      int idx = r * 256 + tid;
      int row = idx >> 3;
      int c8 = (idx & 7) ^ (row & 7);
      gload_lds16(A + (size_t)(m0 + row) * K + k0 + c8 * 8, &As[idx * 8]);
    }
#pragma unroll
    for (int r = 0; r < 4; ++r) {
      int idx = r * 256 + tid;
      int row = idx >> 3;
      int c8 = (idx & 7) ^ (row & 7);
      gload_lds16(Bw + (size_t)(n0 + row) * K + k0 + c8 * 8, &Bs[idx * 8]);
    }
    __syncthreads();
#pragma unroll
    for (int ks = 0; ks < 2; ++ks) {
      bf16x8 av[4], bv[4];
      int k8 = ks * 4 + lq;
#pragma unroll
      for (int mi = 0; mi < 4; ++mi) {
        int row = wm * 64 + mi * 16 + l16;
        av[mi] = *reinterpret_cast<const bf16x8*>(&As[row * BK + ((k8 ^ (row & 7)) * 8)]);
      }
#pragma unroll
      for (int ni = 0; ni < 4; ++ni) {
        int row = wn * 64 + ni * 16 + l16;
        bv[ni] = *reinterpret_cast<const bf16x8*>(&Bs[row * BK + ((k8 ^ (row & 7)) * 8)]);
      }
#pragma unroll
      for (int mi = 0; mi < 4; ++mi)
#pragma unroll
        for (int ni = 0; ni < 4; ++ni)
          acc[mi][ni] = __builtin_amdgcn_mfma_f32_16x16x32_bf16(av[mi], bv[ni], acc[mi][ni], 0, 0, 0);
    }
    __syncthreads();
  }

  if constexpr (MODE == 0) {
#pragma unroll
    for (int mi = 0; mi < 4; ++mi) {
      int r0 = m0 + wm * 64 + mi * 16 + lq * 4;
#pragma unroll
      for (int ni = 0; ni < 4; ++ni) {
        int c = n0 + wn * 64 + ni * 16 + l16;
        float bb = bias[c];
#pragma unroll
        for (int rr = 0; rr < 4; ++rr)
          ((float*)Cv)[(size_t)(r0 + rr) * N + c] = acc[mi][ni][rr] + bb;
      }
    }
  } else {
    const int head = (n0 + wn * 64) >> 6;
    if (head < H_) {
      const float PREQ = 0.125f * 1.44269504f;
#pragma unroll
      for (int mi = 0; mi < 4; ++mi) {
#pragma unroll
        for (int ni = 0; ni < 2; ++ni) {
          int d = ni * 16 + l16;
          int cg = head * 64 + d;
          float b1 = bias[cg], b2 = bias[cg + 32];
#pragma unroll
          for (int rr = 0; rr < 4; ++rr) {
            int t = m0 + wm * 64 + mi * 16 + lq * 4 + rr;
            int bb = t >> 11, tloc = t & 2047;
            float x1 = acc[mi][ni][rr] + b1;
            float x2 = acc[mi][ni + 2][rr] + b2;
            float cc = cosT[tloc * 32 + d], ss = sinT[tloc * 32 + d];
            int tile = tloc >> 5, mf = (tloc >> 4) & 1, l16f = tloc & 15;
            size_t base = ((size_t)(bb * H_ + head) * 64 + tile) * 2048;
            int lofs = ((d >> 3) * 16 + l16f) * 8 + (d & 7);
            qb[base + mf * 512 + lofs] = f2bf((x1 * cc - x2 * ss) * PREQ);       // ks=0
            qb[base + (2 + mf) * 512 + lofs] = f2bf((x2 * cc + x1 * ss) * PREQ); // ks=1
          }
        }
      }
    } else if (head < H_ + KVH_) {
      int kh = head - H_;
#pragma unroll
      for (int mi = 0; mi < 4; ++mi) {
#pragma unroll
        for (int ni = 0; ni < 2; ++ni) {
          int d = ni * 16 + l16;
          int cg = head * 64 + d;
          float b1 = bias[cg], b2 = bias[cg + 32];
#pragma unroll
          for (int rr = 0; rr < 4; ++rr) {
            int t = m0 + wm * 64 + mi * 16 + lq * 4 + rr;
            int bb = t >> 11, tloc = t & 2047;
            float x1 = acc[mi][ni][rr] + b1;
            float x2 = acc[mi][ni + 2][rr] + b2;
            float cc = cosT[tloc * 32 + d], ss = sinT[tloc * 32 + d];
            int it = tloc >> 6, nf = (tloc >> 4) & 3, l16f = tloc & 15;
            size_t base = (size_t)(bb * KVH_ + kh) * (T_ * HD_) + (size_t)it * 4096;
            int lofs = ((d >> 3) * 16 + l16f) * 8 + (d & 7);
            kb[base + nf * 512 + lofs] = f2bf(x1 * cc - x2 * ss);         // ks=0
            kb[base + (4 + nf) * 512 + lofs] = f2bf(x2 * cc + x1 * ss);   // ks=1
          }
        }
      }
    } else {
      int vh = head - H_ - KVH_;
#pragma unroll
      for (int mi = 0; mi < 4; ++mi) {
#pragma unroll
        for (int ni = 0; ni < 4; ++ni) {
          int d = ni * 16 + l16;
          float b1 = bias[head * 64 + d];
#pragma unroll
          for (int rr = 0; rr < 4; ++rr) {
            int t = m0 + wm * 64 + mi * 16 + lq * 4 + rr;
            int bb = t >> 11, tloc = t & 2047;
            vst[((size_t)bb * T_ + tloc) * 512 + vh * 64 + d] =
                f2bf(acc[mi][ni][rr] + b1);
          }
        }
      }
    }
  }
}

// ---------------- V (compact [B][T][512]) -> fragment-major bf16 via LDS ----------------
__global__ void cvt_v_k(const uint16_t* __restrict__ vst, uint16_t* __restrict__ vt) {
  __shared__ uint16_t tile[64][72];
  int blk = blockIdx.x;              // b*256 + kvh*32 + it
  int it = blk & 31;
  int kvh = (blk >> 5) & 7;
  int b = blk >> 8;
  int tid = threadIdx.x;
  int t0 = it * 64;

  {
    int r = tid >> 2;
    int cg = (tid & 3) * 16;
    const uint16_t* src = vst + ((size_t)(b * T_ + t0 + r)) * 512 + kvh * 64 + cg;
    uint4 v0 = *reinterpret_cast<const uint4*>(src);
    uint4 v1 = *reinterpret_cast<const uint4*>(src + 8);
    *reinterpret_cast<uint4*>(&tile[r][cg]) = v0;
    *reinterpret_cast<uint4*>(&tile[r][cg + 8]) = v1;
  }
  __syncthreads();

  int d = tid & 63;
  int wv = tid >> 6;
  int dn = d >> 4, l16 = d & 15;
  size_t base = (size_t)(b * KVH_ + kvh) * (T_ * HD_);
#pragma unroll
  for (int j = 0; j < 2; ++j) {
    int oct = wv * 2 + j;
    int k2 = oct >> 2, lq = oct & 3;
    uint16_t tmp[8];
#pragma unroll
    for (int e = 0; e < 8; ++e) tmp[e] = tile[oct * 8 + e][d];
    uint4 v;
    v.x = (uint32_t)tmp[0] | ((uint32_t)tmp[1] << 16);
    v.y = (uint32_t)tmp[2] | ((uint32_t)tmp[3] << 16);
    v.z = (uint32_t)tmp[4] | ((uint32_t)tmp[5] << 16);
    v.w = (uint32_t)tmp[6] | ((uint32_t)tmp[7] << 16);
    *reinterpret_cast<uint4*>(vt + base + ((size_t)(it * 2 + k2) * 4 + dn) * 512 +
                              (lq * 16 + l16) * 8) = v;
  }
}

// ---------------- flash attention (causal, GQA), swapped QK^T ----------------
__global__ __launch_bounds__(256, 2)
void flash_attn_k(const uint16_t* __restrict__ qb, const uint16_t* __restrict__ kb,
                  const uint16_t* __restrict__ vt, uint16_t* __restrict__ ob) {
  __shared__ __align__(16) uint16_t P_lds[4][32 * 72];
  const int lane = threadIdx.x & 63;
  const int w = threadIdx.x >> 6;
  const int l16 = lane & 15, lq = lane >> 4;
  const int bh = (blockIdx.x & 15) * 4 + w;
  const int rank = blockIdx.x >> 4;
  const int pair = rank & 31;
  const int tile = (rank & 32) ? (63 - pair) : pair;
  const int b = bh >> 5, h = bh & 31;
  const int kvh = h >> 2;
  uint16_t* P = P_lds[w];

  const uint16_t* Qp = qb + ((size_t)(b * H_ + h) * 64 + tile) * 2048;
  const uint16_t* Kp = kb + (size_t)(b * KVH_ + kvh) * (T_ * HD_);
  const uint16_t* Vp = vt + (size_t)(b * KVH_ + kvh) * (T_ * HD_);
  const int lofs = lane * 8;

  const int q0 = tile * 32;
  u32x4 ones_u = {0x3F803F80u, 0x3F803F80u, 0x3F803F80u, 0x3F803F80u};
  bf16x8 ones = __builtin_bit_cast(bf16x8, ones_u);

  bf16x8 aq[2][2];
#pragma unroll
  for (int mf = 0; mf < 2; ++mf)
#pragma unroll
    for (int ks = 0; ks < 2; ++ks)
      aq[mf][ks] = *reinterpret_cast<const bf16x8*>(Qp + (ks * 2 + mf) * 512 + lofs);

  f32x4 acc[2][4] = {};
  f32x4 acc_l[2] = {};

  const int nt = (tile >> 1) + 1;

  bf16x8 kA[2][4], kB[2][4];
#pragma unroll
  for (int ks = 0; ks < 2; ++ks)
#pragma unroll
    for (int nf = 0; nf < 4; ++nf)
      kA[ks][nf] = *reinterpret_cast<const bf16x8*>(Kp + (ks * 4 + nf) * 512 + lofs);

#define FLASH_STEP(KCUR, KNXT, IT)                                                     \
  do {                                                                                 \
    const int kv0 = (IT) * 64;                                                         \
    f32x4 sacc[4][2] = {};                                                             \
    _Pragma("unroll")                                                                  \
    for (int ks = 0; ks < 2; ++ks)                                                     \
      _Pragma("unroll")                                                                \
      for (int nf = 0; nf < 4; ++nf)                                                   \
        _Pragma("unroll")                                                              \
        for (int mf = 0; mf < 2; ++mf)                                                 \
          sacc[nf][mf] = __builtin_amdgcn_mfma_f32_16x16x32_bf16(                      \
              KCUR[ks][nf], aq[mf][ks], sacc[nf][mf], 0, 0, 0);                        \
    const int itn = ((IT) + 1 < nt) ? (IT) + 1 : (IT);                                 \
    _Pragma("unroll")                                                                  \
    for (int ks = 0; ks < 2; ++ks)                                                     \
      _Pragma("unroll")                                                                \
      for (int nf = 0; nf < 4; ++nf)                                                   \
        KNXT[ks][nf] = *reinterpret_cast<const bf16x8*>(                               \
            Kp + ((size_t)(itn * 2 + ks) * 4 + nf) * 512 + lofs);                      \
    bf16x8 vv[2][4];                                                                   \
    _Pragma("unroll")                                                                  \
    for (int k2 = 0; k2 < 2; ++k2)                                                     \
      _Pragma("unroll")                                                                \
      for (int dn = 0; dn < 4; ++dn)                                                   \
        vv[k2][dn] = *reinterpret_cast<const bf16x8*>(                                 \
            Vp + ((size_t)((IT) * 2 + k2) * 4 + dn) * 512 + lofs);                     \
    if ((IT) == nt - 1) {                                                              \
      _Pragma("unroll")                                                                \
      for (int mf = 0; mf < 2; ++mf) {                                                 \
        int qg = q0 + mf * 16 + l16;                                                   \
        _Pragma("unroll")                                                              \
        for (int nf = 0; nf < 4; ++nf)                                                 \
          _Pragma("unroll")                                                            \
          for (int r = 0; r < 4; ++r)                                                  \
            if (kv0 + nf * 16 + lq * 4 + r > qg) sacc[nf][mf][r] = -1e30f;             \
      }                                                                                \
    }                                                                                  \
    _Pragma("unroll")                                                                  \
    for (int mf = 0; mf < 2; ++mf) {                                                   \
      uint16_t* rowp = P + (mf * 16 + l16) * 72;                                       \
      _Pragma("unroll")                                                                \
      for (int nf = 0; nf < 4; ++nf) {                                                 \
        float p0 = __builtin_amdgcn_exp2f(sacc[nf][mf][0]);                            \
        float p1 = __builtin_amdgcn_exp2f(sacc[nf][mf][1]);                            \
        float p2 = __builtin_amdgcn_exp2f(sacc[nf][mf][2]);                            \
        float p3 = __builtin_amdgcn_exp2f(sacc[nf][mf][3]);                            \
        uint2 pk;                                                                      \
        pk.x = cvt_pk(p0, p1);                                                         \
        pk.y = cvt_pk(p2, p3);                                                         \
        *reinterpret_cast<uint2*>(rowp + nf * 16 + lq * 4) = pk;                       \
      }                                                                                \
    }                                                                                  \
    bf16x8 pa[2][2];                                                                   \
    _Pragma("unroll")                                                                  \
    for (int mf = 0; mf < 2; ++mf)                                                     \
      _Pragma("unroll")                                                                \
      for (int k2 = 0; k2 < 2; ++k2)                                                   \
        pa[mf][k2] = *reinterpret_cast<const bf16x8*>(                                 \
            P + (mf * 16 + l16) * 72 + k2 * 32 + lq * 8);                              \
    _Pragma("unroll")                                                                  \
    for (int k2 = 0; k2 < 2; ++k2)                                                     \
      _Pragma("unroll")                                                                \
      for (int mf = 0; mf < 2; ++mf) {                                                 \
        acc_l[mf] = __builtin_amdgcn_mfma_f32_16x16x32_bf16(ones, pa[mf][k2],          \
                                                            acc_l[mf], 0, 0, 0);      \
        _Pragma("unroll")                                                              \
        for (int dn = 0; dn < 4; ++dn)                                                 \
          acc[mf][dn] = __builtin_amdgcn_mfma_f32_16x16x32_bf16(                       \
              vv[k2][dn], pa[mf][k2], acc[mf][dn], 0, 0, 0);                           \
      }                                                                                \
  } while (0)

  {
    int it = 0;
    for (;;) {
      FLASH_STEP(kA, kB, it);
      ++it;
      if (it == nt) break;
      FLASH_STEP(kB, kA, it);
      ++it;
      if (it == nt) break;
    }
  }
#undef FLASH_STEP

#pragma unroll
  for (int mf = 0; mf < 2; ++mf) {
    float inv = 1.0f / acc_l[mf][0];
    uint16_t* rowp = P + (mf * 16 + l16) * 72;
#pragma unroll
    for (int dn = 0; dn < 4; ++dn) {
      uint2 pk;
      pk.x = cvt_pk(acc[mf][dn][0] * inv, acc[mf][dn][1] * inv);
      pk.y = cvt_pk(acc[mf][dn][2] * inv, acc[mf][dn][3] * inv);
      *reinterpret_cast<uint2*>(rowp + dn * 16 + lq * 4) = pk;
    }
  }
  {
    int orow = lane >> 1, ohalf = (lane & 1) * 32;
    uint16_t* op = ob + (size_t)(b * T_ + q0 + orow) * D_ + h * HD_ + ohalf;
    const uint16_t* lp = P + orow * 72 + ohalf;
#pragma unroll
    for (int j = 0; j < 4; ++j)
      *reinterpret_cast<uint4*>(op + j * 8) = *reinterpret_cast<const uint4*>(lp + j * 8);
  }
}

extern "C" void kernel_launch(void* const* d_in, const int* in_sizes, int n_in,
                              void* d_out, int out_size, void* d_ws, size_t ws_size,
                              hipStream_t stream) {
  const float* x  = (const float*)d_in[0];
  const float* Wq = (const float*)d_in[1];
  const float* bq = (const float*)d_in[2];
  const float* Wk = (const float*)d_in[3];
  const float* bk = (const float*)d_in[4];
  const float* Wv = (const float*)d_in[5];
  const float* bv = (const float*)d_in[6];
  const float* Wo = (const float*)d_in[7];
  const float* bo = (const float*)d_in[8];
  float* out = (float*)d_out;

  char* ws = (char*)d_ws;
  size_t off = 0;
  auto alloc = [&](size_t bytes) {
    void* p = ws + off;
    off += (bytes + 255) & ~(size_t)255;
    return p;
  };
  uint16_t* xb    = (uint16_t*)alloc((size_t)M_ * D_ * 2);
  uint16_t* wqkv  = (uint16_t*)alloc((size_t)NQKV_ * D_ * 2);
  uint16_t* wo_b  = (uint16_t*)alloc((size_t)D_ * D_ * 2);
  float*    bqkv  = (float*)alloc(NQKV_ * 4);
  float*    cosT  = (float*)alloc(T_ * 32 * 4);
  float*    sinT  = (float*)alloc(T_ * 32 * 4);
  uint16_t* q_bf  = (uint16_t*)alloc((size_t)B_ * H_ * T_ * HD_ * 2);
  uint16_t* k_bf  = (uint16_t*)alloc((size_t)B_ * KVH_ * T_ * HD_ * 2);
  uint16_t* vt_bf = (uint16_t*)alloc((size_t)B_ * KVH_ * T_ * HD_ * 2);
  uint16_t* vst   = (uint16_t*)alloc((size_t)B_ * T_ * 512 * 2);   // 4.2 MB
  uint16_t* attn_bf = (uint16_t*)alloc((size_t)B_ * T_ * D_ * 2);  // 16.8 MB

  prep_k<<<9484, 256, 0, stream>>>(x, Wq, Wk, Wv, Wo, bq, bk, bv,
                                   xb, wqkv, wo_b, bqkv, cosT, sinT);

  gemm_bf16<1><<<dim3(NQKV_ / BN, M_ / BM), 256, 0, stream>>>(
      xb, wqkv, bqkv, nullptr, M_, NQKV_, D_, cosT, sinT, q_bf, k_bf, vst);

  cvt_v_k<<<B_ * KVH_ * (T_ / 64), 256, 0, stream>>>(vst, vt_bf);

  flash_attn_k<<<1024, 256, 0, stream>>>(q_bf, k_bf, vt_bf, attn_bf);

  gemm_bf16<0><<<dim3(D_ / BN, M_ / BM), 256, 0, stream>>>(
      attn_bf, wo_b, bo, out, M_, D_, D_, nullptr, nullptr, nullptr, nullptr, nullptr);
}